// Round 5
// baseline (3710.242 us; speedup 1.0000x reference)
//
#include <hip/hip_runtime.h>
#include <hip/hip_bf16.h>
#include <math.h>

#define N1 50000
#define N2 50000
#define E1C 800000
#define E2C 800000
#define AC 10000
#define F 128
#define NSUP 25000
#define KHOPS 10
#define NEGINF -1e30f
#define NBINS 65536
#define NBINS22 (1 << 22)

static inline int cdiv(int a, int b) { return (a + b - 1) / b; }

// clang-native vector types for __builtin_nontemporal_store (HIP float4/uint4
// are HIP_vector_type wrappers the builtin rejects)
typedef float v4f __attribute__((ext_vector_type(4)));
typedef unsigned int v4u __attribute__((ext_vector_type(4)));

// ---------------- bf16 helpers ----------------
__device__ __forceinline__ float bf2f(unsigned short u) {
  return __uint_as_float(((unsigned)u) << 16);
}
__device__ __forceinline__ unsigned short f2bf(float f) {
  unsigned x = __float_as_uint(f);
  return (unsigned short)((x + 0x7FFFu + ((x >> 16) & 1u)) >> 16);
}

// physical XCD id (HW-verified: returns 0..7 on MI355X)
__device__ __forceinline__ int xcc_id() {
  int v;
  asm volatile("s_getreg_b32 %0, hwreg(20, 0, 32)" : "=s"(v));
  return v;
}

// ---------------- CSR build ----------------
__global__ void k_count(const int* __restrict__ key, int* __restrict__ cnt, int n) {
  int e = blockIdx.x * blockDim.x + threadIdx.x;
  if (e < n) atomicAdd(&cnt[key[e]], 1);
}

// single-block scan: thread-sequential partials + shuffle scan
__global__ void k_scan(const int* __restrict__ cnt, int* __restrict__ rowptr, int n) {
  const int T = 1024;
  int t = threadIdx.x;
  int vpt = (n + T - 1) / T;
  int lo = t * vpt, hi = lo + vpt;
  if (hi > n) hi = n;
  int sum = 0;
  for (int i = lo; i < hi; ++i) sum += cnt[i];
  int lane = t & 63, wid = t >> 6;
  int v = sum;
#pragma unroll
  for (int o = 1; o < 64; o <<= 1) {
    int u = __shfl_up(v, o, 64);
    if (lane >= o) v += u;
  }
  __shared__ int wsum[16];
  if (lane == 63) wsum[wid] = v;
  __syncthreads();
  if (t < 16) {
    int w = wsum[t];
#pragma unroll
    for (int o = 1; o < 16; o <<= 1) {
      int u = __shfl_up(w, o, 64);
      if (t >= o) w += u;
    }
    wsum[t] = w;
  }
  __syncthreads();
  int base = (wid ? wsum[wid - 1] : 0) + (v - sum);
  if (t == 0) rowptr[0] = 0;
  int run = base;
  for (int i = lo; i < hi; ++i) { run += cnt[i]; rowptr[i + 1] = run; }
}

__global__ void k_fill(const int* __restrict__ key, const int* __restrict__ payload,
                       const float* __restrict__ val, const int* __restrict__ rowptr,
                       int* __restrict__ cnt, int* __restrict__ col, float* __restrict__ v,
                       int n) {
  int e = blockIdx.x * blockDim.x + threadIdx.x;
  if (e < n) {
    int k = key[e];
    int p = atomicAdd(&cnt[k], 1);
    int s = rowptr[k] + p;
    col[s] = payload[e];
    if (val) v[s] = val[e];
  }
}

// fill storing the element index itself (for cluster->member lists)
__global__ void k_fill_iota(const int* __restrict__ key, const int* __restrict__ rowptr,
                            int* __restrict__ cnt, int* __restrict__ col, int n) {
  int e = blockIdx.x * blockDim.x + threadIdx.x;
  if (e < n) {
    int k = key[e];
    int p = atomicAdd(&cnt[k], 1);
    col[rowptr[k] + p] = e;
  }
}

__global__ void k_count_coarse(const int* __restrict__ dst, const int* __restrict__ cluster,
                               int* __restrict__ cnt, int n) {
  int e = blockIdx.x * blockDim.x + threadIdx.x;
  if (e < n) atomicAdd(&cnt[cluster[dst[e]]], 1);
}

// coarse fill computing cw = w * a[src] * a[dst] inline
__global__ void k_fill_coarse(const int* __restrict__ src, const int* __restrict__ dst,
                              const int* __restrict__ cluster, const float* __restrict__ w,
                              const float* __restrict__ a, const int* __restrict__ rowptr,
                              int* __restrict__ cnt, int* __restrict__ col,
                              float* __restrict__ v, int n) {
  int e = blockIdx.x * blockDim.x + threadIdx.x;
  if (e < n) {
    int sd = dst[e];
    int k = cluster[sd];
    int p = atomicAdd(&cnt[k], 1);
    int s = rowptr[k] + p;
    int ss = src[e];
    col[s] = cluster[ss];
    v[s] = w[e] * a[ss] * a[sd];
  }
}

// ---------------- degree via CSR rowsum (32-lane slice per row) ----------------
__global__ void k_rowsum(const int* __restrict__ rowptr, const float* __restrict__ v,
                         float* __restrict__ deg, int n) {
  int row = blockIdx.x * 8 + (threadIdx.x >> 5);
  if (row >= n) return;
  int q = threadIdx.x & 31;
  int s0 = rowptr[row], s1 = rowptr[row + 1];
  float s = 0.f;
  for (int k = s0 + q; k < s1; k += 32) s += v[k];
#pragma unroll
  for (int o = 16; o; o >>= 1) s += __shfl_xor(s, o, 64);  // stays within aligned 32-group
  if (q == 0) deg[row] = s;
}

// in-place symmetric normalization of CSR values (32-lane slice per row)
__global__ void k_csrnorm(const int* __restrict__ rowptr, const int* __restrict__ col,
                          float* __restrict__ v, const float* __restrict__ deg, int n) {
  int row = blockIdx.x * 8 + (threadIdx.x >> 5);
  if (row >= n) return;
  int q = threadIdx.x & 31;
  int s0 = rowptr[row], s1 = rowptr[row + 1];
  float di = deg[row] + 1.f;
  for (int s = s0 + q; s < s1; s += 32) {
    float dc = deg[col[s]] + 1.f;
    v[s] = v[s] / sqrtf(dc * di);
  }
}

// ---------------- propagation fp32 (pull, 32 threads/node) -- coarse graph only -------
__global__ void k_prop(const float4* __restrict__ hin, float4* __restrict__ hout,
                       float4* __restrict__ relu_out, const int* __restrict__ rowptr,
                       const int* __restrict__ col, const float* __restrict__ val, int n) {
  int node = blockIdx.x * 8 + (threadIdx.x >> 5);
  if (node >= n) return;
  int q = threadIdx.x & 31;
  int s0 = rowptr[node], s1 = rowptr[node + 1];
  float4 acc = make_float4(0.f, 0.f, 0.f, 0.f);
  for (int s = s0; s < s1; s += 8) {
    int c[8]; float v[8];
#pragma unroll
    for (int j = 0; j < 8; ++j) {
      int ss = s + j;
      int sc = (ss < s1) ? ss : (s1 - 1);
      c[j] = col[sc];
      v[j] = (ss < s1) ? val[sc] : 0.f;
    }
    float4 h[8];
#pragma unroll
    for (int j = 0; j < 8; ++j) h[j] = hin[(size_t)c[j] * 32 + q];
#pragma unroll
    for (int j = 0; j < 8; ++j) {
      acc.x = fmaf(v[j], h[j].x, acc.x);
      acc.y = fmaf(v[j], h[j].y, acc.y);
      acc.z = fmaf(v[j], h[j].z, acc.z);
      acc.w = fmaf(v[j], h[j].w, acc.w);
    }
  }
  hout[(size_t)node * 32 + q] = acc;
  if (relu_out) {
    float4 r;
    r.x = fmaxf(acc.x, 0.f); r.y = fmaxf(acc.y, 0.f);
    r.z = fmaxf(acc.z, 0.f); r.w = fmaxf(acc.w, 0.f);
    relu_out[(size_t)node * 32 + q] = r;
  }
}

// ---------------- XCD-PINNED chunked fp32 propagation (graph 1) ----------------
// 8 feature-chunks of 16 floats; chunk ownership decided by PHYSICAL XCD id
// (s_getreg HW_REG_XCC_ID) + atomic work-claim, so each XCD's L2 only ever
// gathers from its own 3.2 MB slice (<= 4 MB L2). col/val nontemporal-streamed;
// h' nontemporal-stored so the resident slice isn't evicted.
// Claim scheme: item = (chunk, 64-node range). Each block claims exactly one
// item, preferring its own XCD's chunk, cyclic fallback. With grid == #items,
// every item is claimed exactly once (a block can only exit idle if all items
// are already claimed, which is impossible with #blocks == #items).
__global__ void k_prop_c8(const float* __restrict__ hin, float* __restrict__ hout,
                          float4* __restrict__ outx_std, float4* __restrict__ xr_std,
                          const int* __restrict__ rowptr, const int* __restrict__ col,
                          const float* __restrict__ val, int* __restrict__ wctr, int n) {
  const int M = (N1 + 63) >> 6;  // node-blocks per chunk
  __shared__ int s_item;
  if (threadIdx.x == 0) {
    int xcc = xcc_id();
    int item = -1;
    for (int t = 0; t < 8; ++t) {
      int c = (xcc + t) & 7;
      int i = atomicAdd(&wctr[c], 1);
      if (i < M) { item = c * M + i; break; }
    }
    s_item = item;
  }
  __syncthreads();
  int item = s_item;
  if (item < 0) return;
  int chunk = item / M;
  int node = (item % M) * 64 + (threadIdx.x >> 2);
  if (node >= n) return;
  int sub = threadIdx.x & 3;
  const float4* hc = (const float4*)hin + (size_t)chunk * n * 4;  // 4 float4/node
  int s0 = rowptr[node], s1 = rowptr[node + 1];
  float4 acc = make_float4(0.f, 0.f, 0.f, 0.f);
  for (int s = s0; s < s1; s += 8) {
    int c[8]; float v[8];
#pragma unroll
    for (int j = 0; j < 8; ++j) {
      int ss = s + j;
      int sc = (ss < s1) ? ss : (s1 - 1);
      c[j] = __builtin_nontemporal_load(col + sc);
      float vv = __builtin_nontemporal_load(val + sc);
      v[j] = (ss < s1) ? vv : 0.f;
    }
    float4 h[8];
#pragma unroll
    for (int j = 0; j < 8; ++j) h[j] = hc[(size_t)c[j] * 4 + sub];
#pragma unroll
    for (int j = 0; j < 8; ++j) {
      acc.x = fmaf(v[j], h[j].x, acc.x);
      acc.y = fmaf(v[j], h[j].y, acc.y);
      acc.z = fmaf(v[j], h[j].z, acc.z);
      acc.w = fmaf(v[j], h[j].w, acc.w);
    }
  }
  if (outx_std) {
    size_t o = (size_t)node * 32 + chunk * 4 + sub;
    outx_std[o] = acc;
    float4 r;
    r.x = fmaxf(acc.x, 0.f); r.y = fmaxf(acc.y, 0.f);
    r.z = fmaxf(acc.z, 0.f); r.w = fmaxf(acc.w, 0.f);
    xr_std[o] = r;
  } else {
    v4f av = { acc.x, acc.y, acc.z, acc.w };
    __builtin_nontemporal_store(av,
        (v4f*)hout + ((size_t)chunk * n + node) * 4 + sub);
  }
}

// ---------------- XCD-pair-pinned chunked bf16 propagation (graph 2) ----------------
// 4 chunks of 32 bf16 (64 B/node, 3.2 MB/chunk); XCD pair (xcc>>1) owns a chunk.
__global__ void k_prop_cb4(const unsigned short* __restrict__ hin,
                           unsigned short* __restrict__ hout,
                           float4* __restrict__ outy_std,
                           const int* __restrict__ rowptr, const int* __restrict__ col,
                           const float* __restrict__ val, int* __restrict__ wctr, int n) {
  const int M = (N2 + 63) >> 6;
  __shared__ int s_item;
  if (threadIdx.x == 0) {
    int xcc = xcc_id();
    int item = -1;
    for (int t = 0; t < 4; ++t) {
      int c = ((xcc >> 1) + t) & 3;
      int i = atomicAdd(&wctr[c], 1);
      if (i < M) { item = c * M + i; break; }
    }
    s_item = item;
  }
  __syncthreads();
  int item = s_item;
  if (item < 0) return;
  int chunk = item / M;
  int node = (item % M) * 64 + (threadIdx.x >> 2);
  if (node >= n) return;
  int sub = threadIdx.x & 3;
  const uint4* hc = (const uint4*)hin + (size_t)chunk * n * 4;  // 4 uint4/node
  int s0 = rowptr[node], s1 = rowptr[node + 1];
  float acc[8];
#pragma unroll
  for (int i = 0; i < 8; ++i) acc[i] = 0.f;
  for (int s = s0; s < s1; s += 8) {
    int c[8]; float v[8];
#pragma unroll
    for (int j = 0; j < 8; ++j) {
      int ss = s + j;
      int sc = (ss < s1) ? ss : (s1 - 1);
      c[j] = __builtin_nontemporal_load(col + sc);
      float vv = __builtin_nontemporal_load(val + sc);
      v[j] = (ss < s1) ? vv : 0.f;
    }
    uint4 h[8];
#pragma unroll
    for (int j = 0; j < 8; ++j) h[j] = hc[(size_t)c[j] * 4 + sub];
#pragma unroll
    for (int j = 0; j < 8; ++j) {
      unsigned u;
      u = h[j].x;
      acc[0] = fmaf(v[j], bf2f((unsigned short)u), acc[0]);
      acc[1] = fmaf(v[j], bf2f((unsigned short)(u >> 16)), acc[1]);
      u = h[j].y;
      acc[2] = fmaf(v[j], bf2f((unsigned short)u), acc[2]);
      acc[3] = fmaf(v[j], bf2f((unsigned short)(u >> 16)), acc[3]);
      u = h[j].z;
      acc[4] = fmaf(v[j], bf2f((unsigned short)u), acc[4]);
      acc[5] = fmaf(v[j], bf2f((unsigned short)(u >> 16)), acc[5]);
      u = h[j].w;
      acc[6] = fmaf(v[j], bf2f((unsigned short)u), acc[6]);
      acc[7] = fmaf(v[j], bf2f((unsigned short)(u >> 16)), acc[7]);
    }
  }
  if (outy_std) {
    size_t o = (size_t)node * 32 + chunk * 8 + sub * 2;
    outy_std[o] = make_float4(acc[0], acc[1], acc[2], acc[3]);
    outy_std[o + 1] = make_float4(acc[4], acc[5], acc[6], acc[7]);
  } else {
    v4u p;
    p.x = (unsigned)f2bf(acc[0]) | ((unsigned)f2bf(acc[1]) << 16);
    p.y = (unsigned)f2bf(acc[2]) | ((unsigned)f2bf(acc[3]) << 16);
    p.z = (unsigned)f2bf(acc[4]) | ((unsigned)f2bf(acc[5]) << 16);
    p.w = (unsigned)f2bf(acc[6]) | ((unsigned)f2bf(acc[7]) << 16);
    __builtin_nontemporal_store(p,
        (v4u*)hout + ((size_t)chunk * n + node) * 4 + sub);
  }
}

// ---------------- dense matmul out = relu?(X @ W + b), W given transposed ----------------
__global__ void k_transpose(const float* __restrict__ W, float* __restrict__ WT) {
  int i = blockIdx.x * blockDim.x + threadIdx.x;
  if (i < F * F) { int k = i >> 7, c = i & 127; WT[c * F + k] = W[i]; }
}

__global__ void k_mm128(const float* __restrict__ X, const float* __restrict__ WT,
                        const float* __restrict__ bias, float* __restrict__ out,
                        int M, int relu, int chunked) {
  __shared__ float4 xs[16][32];
  int tid = threadIdx.x;
  int c = tid & 127;
  int half = tid >> 7;
  int row0 = blockIdx.x * 16;
  for (int t = tid; t < 512; t += 256) {
    int r = t >> 5, k4 = t & 31;
    int gr = row0 + r;
    float4 v = make_float4(0.f, 0.f, 0.f, 0.f);
    if (gr < M) v = ((const float4*)X)[(size_t)gr * 32 + k4];
    xs[r][k4] = v;
  }
  __syncthreads();
  float acc[8];
#pragma unroll
  for (int r = 0; r < 8; ++r) acc[r] = 0.f;
  const float4* wrow = (const float4*)WT + (size_t)c * 32;
  for (int k4 = 0; k4 < 32; ++k4) {
    float4 w = wrow[k4];
#pragma unroll
    for (int r = 0; r < 8; ++r) {
      float4 xv = xs[half * 8 + r][k4];
      acc[r] = fmaf(xv.x, w.x, acc[r]);
      acc[r] = fmaf(xv.y, w.y, acc[r]);
      acc[r] = fmaf(xv.z, w.z, acc[r]);
      acc[r] = fmaf(xv.w, w.w, acc[r]);
    }
  }
  float bb = bias ? bias[c] : 0.f;
#pragma unroll
  for (int r = 0; r < 8; ++r) {
    int gr = row0 + half * 8 + r;
    if (gr < M) {
      float v = acc[r] + bb;
      if (relu) v = fmaxf(v, 0.f);
      if (chunked)
        out[((size_t)(c >> 4) * M + gr) * 16 + (c & 15)] = v;
      else
        out[(size_t)gr * F + c] = v;
    }
  }
}

// same as k_mm128 but bf16 output in chunked [chunk][row][32] layout (graph-2 h0)
__global__ void k_mm128_bf16(const float* __restrict__ X, const float* __restrict__ WT,
                             const float* __restrict__ bias, unsigned short* __restrict__ out,
                             int M) {
  __shared__ float4 xs[16][32];
  int tid = threadIdx.x;
  int c = tid & 127;
  int half = tid >> 7;
  int row0 = blockIdx.x * 16;
  for (int t = tid; t < 512; t += 256) {
    int r = t >> 5, k4 = t & 31;
    int gr = row0 + r;
    float4 v = make_float4(0.f, 0.f, 0.f, 0.f);
    if (gr < M) v = ((const float4*)X)[(size_t)gr * 32 + k4];
    xs[r][k4] = v;
  }
  __syncthreads();
  float acc[8];
#pragma unroll
  for (int r = 0; r < 8; ++r) acc[r] = 0.f;
  const float4* wrow = (const float4*)WT + (size_t)c * 32;
  for (int k4 = 0; k4 < 32; ++k4) {
    float4 w = wrow[k4];
#pragma unroll
    for (int r = 0; r < 8; ++r) {
      float4 xv = xs[half * 8 + r][k4];
      acc[r] = fmaf(xv.x, w.x, acc[r]);
      acc[r] = fmaf(xv.y, w.y, acc[r]);
      acc[r] = fmaf(xv.z, w.z, acc[r]);
      acc[r] = fmaf(xv.w, w.w, acc[r]);
    }
  }
  float bb = bias ? bias[c] : 0.f;
#pragma unroll
  for (int r = 0; r < 8; ++r) {
    int gr = row0 + half * 8 + r;
    if (gr < M)
      out[((size_t)(c >> 5) * M + gr) * 32 + (c & 31)] = f2bf(acc[r] + bb);
  }
}

// ---------------- elementwise ----------------
__global__ void k_addrelu(const float* __restrict__ a, const float* __restrict__ b,
                          float* __restrict__ out, int n) {
  int i = blockIdx.x * blockDim.x + threadIdx.x;
  if (i < n) out[i] = fmaxf(a[i] + b[i], 0.f);
}

// ---------------- scores + ranking (top-k via 22-bit bin bucketing) ----------------
__global__ void k_score(const float* __restrict__ xr, const float* __restrict__ p,
                        float* __restrict__ s, int n) {
  int wid = (blockIdx.x * blockDim.x + threadIdx.x) >> 6;
  int lane = threadIdx.x & 63;
  if (wid >= n) return;
  const float* row = xr + (size_t)wid * F;
  float d = row[lane] * p[lane] + row[lane + 64] * p[lane + 64];
#pragma unroll
  for (int o = 32; o; o >>= 1) d += __shfl_xor(d, o, 64);
  if (lane == 0) s[wid] = d;
}

__device__ __forceinline__ unsigned sortkey(float f) {
  if (f == 0.f) f = 0.f;  // canonicalize -0 -> +0
  unsigned u = __float_as_uint(f);
  return (u & 0x80000000u) ? ~u : (u | 0x80000000u);
}

__global__ void k_key(const float* __restrict__ s, unsigned* __restrict__ key, int n) {
  int i = blockIdx.x * blockDim.x + threadIdx.x;
  if (i < n) key[i] = sortkey(s[i]);
}

__global__ void k_count_bins22(const unsigned* __restrict__ key, int* __restrict__ cnt, int n) {
  int i = blockIdx.x * blockDim.x + threadIdx.x;
  if (i < n) atomicAdd(&cnt[key[i] >> 10], 1);
}

// block sums over 1024-bin chunks (grid = NBINS22/1024 = 4096 blocks, 256 thr)
__global__ void k_hist_blocksum(const int* __restrict__ cnt, int* __restrict__ partial) {
  int t = threadIdx.x;
  int base = blockIdx.x * 1024 + t * 4;
  int s = cnt[base] + cnt[base + 1] + cnt[base + 2] + cnt[base + 3];
#pragma unroll
  for (int o = 32; o; o >>= 1) s += __shfl_down(s, o, 64);
  __shared__ int ws[4];
  int lane = t & 63, w = t >> 6;
  if (lane == 0) ws[w] = s;
  __syncthreads();
  if (t == 0) partial[blockIdx.x] = ws[0] + ws[1] + ws[2] + ws[3];
}

// apply scanned partials: binptr[b+1] = global inclusive prefix
__global__ void k_hist_apply(const int* __restrict__ cnt, const int* __restrict__ partialptr,
                             int* __restrict__ binptr) {
  int t = threadIdx.x;
  int base = blockIdx.x * 1024 + t * 4;
  int c0 = cnt[base], c1 = cnt[base + 1], c2 = cnt[base + 2], c3 = cnt[base + 3];
  int s = c0 + c1 + c2 + c3;
  int lane = t & 63, w = t >> 6;
  int v = s;
#pragma unroll
  for (int o = 1; o < 64; o <<= 1) {
    int u = __shfl_up(v, o, 64);
    if (lane >= o) v += u;
  }
  __shared__ int ws[4];
  if (lane == 63) ws[w] = v;
  __syncthreads();
  int wb = 0;
  for (int i = 0; i < w; ++i) wb += ws[i];
  int run = partialptr[blockIdx.x] + wb + (v - s);
  binptr[base + 1] = run + c0;
  binptr[base + 2] = run + c0 + c1;
  binptr[base + 3] = run + c0 + c1 + c2;
  binptr[base + 4] = run + s;
  if (blockIdx.x == 0 && t == 0) binptr[0] = 0;
}

__global__ void k_fill_bins22(const unsigned* __restrict__ key, const int* __restrict__ binptr,
                              int* __restrict__ cnt, int* __restrict__ bidx,
                              unsigned* __restrict__ bkey, int n) {
  int i = blockIdx.x * blockDim.x + threadIdx.x;
  if (i < n) {
    unsigned k = key[i];
    int b = k >> 10;
    int p = atomicAdd(&cnt[b], 1);
    int s = binptr[b] + p;
    bidx[s] = i;
    bkey[s] = k;
  }
}

// rank_i = #{j: s_j > s_i} + #{j: s_j == s_i && j < i}; supid = rank < NSUP ? rank : -1
__global__ void k_rank22(const unsigned* __restrict__ key, const int* __restrict__ binptr,
                         const int* __restrict__ bidx, const unsigned* __restrict__ bkey,
                         int* __restrict__ supid, int n) {
  int i = blockIdx.x * blockDim.x + threadIdx.x;
  if (i >= n) return;
  unsigned ki = key[i];
  int b = ki >> 10;
  int cnt = n - binptr[b + 1];  // all keys in strictly-higher bins
  int s1 = binptr[b + 1];
  for (int s = binptr[b]; s < s1; ++s) {
    unsigned kj = bkey[s];
    cnt += (kj > ki) || (kj == ki && bidx[s] < i);
  }
  supid[i] = (cnt < NSUP) ? cnt : -1;
}

// ---------------- attention / assignment ----------------
__device__ __forceinline__ float read_T(const void* p) {
  int ib = *(const int*)p;
  float fb = __int_as_float(ib);
  if (ib >= 1 && ib < (1 << 20)) return (float)ib;   // int-encoded scalar
  if (fb > 1e-6f && fb < 1e6f) return fb;            // float-encoded scalar
  return 1.0f;
}

// wave per node; 4-edge groups for gather MLP
__global__ void k_att_a(const float* __restrict__ xr, const int* __restrict__ rowptr,
                        const int* __restrict__ col, const int* __restrict__ supid,
                        const void* __restrict__ tptr, float* __restrict__ att,
                        float* __restrict__ attself, float* __restrict__ mout, int n) {
  int wid = (blockIdx.x * blockDim.x + threadIdx.x) >> 6;
  int lane = threadIdx.x & 63;
  if (wid >= n) return;
  float inv = 1.0f / (sqrtf(128.0f) * read_T(tptr));
  const float* xn = xr + (size_t)wid * F;
  float x0 = xn[lane], x1 = xn[lane + 64];
  // self candidate
  float d = x0 * x0 + x1 * x1;
#pragma unroll
  for (int o = 32; o; o >>= 1) d += __shfl_xor(d, o, 64);
  float av = (supid[wid] >= 0) ? d * inv : NEGINF;
  float m = av;
  if (lane == 0) attself[wid] = av;
  int s0 = rowptr[wid], s1 = rowptr[wid + 1];
  for (int s = s0; s < s1; s += 4) {
    int c[4]; bool ok[4];
#pragma unroll
    for (int j = 0; j < 4; ++j) {
      int ss = s + j;
      ok[j] = ss < s1;
      c[j] = col[ok[j] ? ss : (s1 - 1)];
    }
    float dd[4];
#pragma unroll
    for (int j = 0; j < 4; ++j) {
      const float* xc = xr + (size_t)c[j] * F;
      dd[j] = x0 * xc[lane] + x1 * xc[lane + 64];
    }
#pragma unroll
    for (int j = 0; j < 4; ++j) {
#pragma unroll
      for (int o = 32; o; o >>= 1) dd[j] += __shfl_xor(dd[j], o, 64);
    }
#pragma unroll
    for (int j = 0; j < 4; ++j) {
      if (ok[j]) {
        float a2 = (supid[c[j]] >= 0) ? dd[j] * inv : NEGINF;
        if (lane == 0) att[s + j] = a2;
        m = fmaxf(m, a2);
      }
    }
  }
  if (lane == 0) mout[wid] = m;
}

// 32-lane slice per node: esum = sum exp(att-m), best = max supid among argmax cands
__global__ void k_att_b(const int* __restrict__ rowptr, const int* __restrict__ col,
                        const int* __restrict__ supid, const float* __restrict__ att,
                        const float* __restrict__ attself, const float* __restrict__ mv,
                        int* __restrict__ cluster, float* __restrict__ aout, int n) {
  int i = blockIdx.x * 8 + (threadIdx.x >> 5);
  if (i >= n) return;
  int q = threadIdx.x & 31;
  float m = mv[i];
  float as = attself[i];
  float esum = 0.f;
  int best = -1;
  if (q == 0) {
    esum = expf(as - m);
    if (as >= m) best = supid[i];
  }
  int s0 = rowptr[i], s1 = rowptr[i + 1];
  for (int s = s0 + q; s < s1; s += 32) {
    float av = att[s];
    esum += expf(av - m);
    if (av >= m) {
      int sid = supid[col[s]];
      if (sid > best) best = sid;
    }
  }
#pragma unroll
  for (int o = 16; o; o >>= 1) {
    esum += __shfl_xor(esum, o, 64);
    int ob = __shfl_xor(best, o, 64);
    if (ob > best) best = ob;
  }
  if (q == 0) {
    int has = best >= 0;
    cluster[i] = has ? best : 0;
    aout[i] = has ? 1.0f / esum : 0.0f;
  }
}

// ---------------- pooling (pull over cluster->member CSR) ----------------
__global__ void k_xpool_pull(const float4* __restrict__ xr, const float* __restrict__ a,
                             const int* __restrict__ rowptrM, const int* __restrict__ memb,
                             float4* __restrict__ xpool, int n) {
  int c = blockIdx.x * 8 + (threadIdx.x >> 5);
  if (c >= n) return;
  int q = threadIdx.x & 31;
  int s0 = rowptrM[c], s1 = rowptrM[c + 1];
  float4 acc = make_float4(0.f, 0.f, 0.f, 0.f);
  for (int s = s0; s < s1; ++s) {
    int m = memb[s];
    float av = a[m];
    float4 h = xr[(size_t)m * 32 + q];
    acc.x = fmaf(av, h.x, acc.x);
    acc.y = fmaf(av, h.y, acc.y);
    acc.z = fmaf(av, h.z, acc.z);
    acc.w = fmaf(av, h.w, acc.w);
  }
  xpool[(size_t)c * 32 + q] = acc;
}

// ---------------- anchor scatters ----------------
__global__ void k_scatter_q(const int* __restrict__ a1, const int* __restrict__ a2,
                            const int* __restrict__ cluster, const float* __restrict__ aarr,
                            const float* __restrict__ t1, float* __restrict__ outy, int nA) {
  int idx = blockIdx.x * blockDim.x + threadIdx.x;
  if (idx >= nA * F) return;
  int k = idx >> 7, f = idx & 127;
  int n1 = a1[k];
  float qw = aarr[n1];
  if (qw != 0.f)
    atomicAdd(&outy[(size_t)a2[k] * F + f], qw * t1[(size_t)cluster[n1] * F + f]);
}

__global__ void k_scatter_t2(const int* __restrict__ a1, const int* __restrict__ a2,
                             const float* __restrict__ t2, float* __restrict__ outy, int nA) {
  int idx = blockIdx.x * blockDim.x + threadIdx.x;
  if (idx >= nA * F) return;
  int k = idx >> 7, f = idx & 127;
  atomicAdd(&outy[(size_t)a2[k] * F + f], t2[(size_t)a1[k] * F + f]);
}

// ================= host =================
extern "C" void kernel_launch(void* const* d_in, const int* in_sizes, int n_in,
                              void* d_out, int out_size, void* d_ws, size_t ws_size,
                              hipStream_t stream) {
  (void)in_sizes; (void)n_in; (void)out_size; (void)ws_size;
  const float* x   = (const float*)d_in[0];
  const int*   ei  = (const int*)d_in[1];     // src = ei, dst = ei+E1C
  const float* w1  = (const float*)d_in[2];
  const float* y   = (const float*)d_in[3];
  const int*   eiy = (const int*)d_in[4];
  const float* wy  = (const float*)d_in[5];
  const int*   anc = (const int*)d_in[6];     // a1 = anc, a2 = anc+AC
  const void*  tmp = d_in[7];
  const float* W_gcn = (const float*)d_in[8];
  const float* b_gcn = (const float*)d_in[9];
  const float* p_sc  = (const float*)d_in[10];
  const float* W_c1  = (const float*)d_in[11];
  const float* b_c1  = (const float*)d_in[12];
  const float* W_m1  = (const float*)d_in[13];
  const float* b_m1  = (const float*)d_in[14];
  const float* W_l1  = (const float*)d_in[15];
  const float* W_l2  = (const float*)d_in[16];
  const float* W_m2  = (const float*)d_in[17];
  const float* b_m2  = (const float*)d_in[18];

  float* out   = (float*)d_out;
  float* out_x = out;
  float* sup1  = out_x + (size_t)N1 * F;
  float* out_y = sup1 + (size_t)NSUP * F;
  float* sup2  = out_y + (size_t)N2 * F;
  float* a_out = sup2 + (size_t)NSUP * F;
  float* recon = a_out + N1;

  char* wsb = (char*)d_ws;
  size_t off = 0;
  auto alloc = [&](size_t bytes) -> void* {
    void* p = wsb + off;
    off = (off + bytes + 255) & ~(size_t)255;
    return p;
  };
  float*    f_csr1v   = (float*)alloc((size_t)E1C * 4);          // reused for graph2 CSR val
  int*      i_csr1c   = (int*)alloc((size_t)E1C * 4);            // reused for graph2 CSR col
  int*      i_rowptr1 = (int*)alloc((size_t)(N1 + 1) * 4);       // reused for graph2
  float*    f_deg     = (float*)alloc((size_t)N1 * 4);           // reused for graph2
  int*      i_cnt     = (int*)alloc((size_t)(NBINS + 1) * 4);
  float*    f_ha      = (float*)alloc((size_t)N1 * F * 4);       // g1 h / cnt22 / g2 bf16 h_a
  float*    f_hb      = (float*)alloc((size_t)N1 * F * 4);       // g1 h / binptr22 / g2 bf16 h_b
  float*    f_xr      = (float*)alloc((size_t)N1 * F * 4);       // reused for t2
  float*    f_s       = (float*)alloc((size_t)N1 * 4);
  unsigned* u_key     = (unsigned*)alloc((size_t)N1 * 4);
  int*      i_partial = (int*)alloc((size_t)4096 * 4);
  int*      i_partptr = (int*)alloc((size_t)4097 * 4);
  int*      i_bidx    = (int*)alloc((size_t)N1 * 4);
  unsigned* u_bkey    = (unsigned*)alloc((size_t)N1 * 4);
  int*      i_supid   = (int*)alloc((size_t)N1 * 4);
  int*      i_rowptrS = (int*)alloc((size_t)(N1 + 1) * 4);
  int*      i_csrSc   = (int*)alloc((size_t)E1C * 4);
  float*    f_att     = (float*)alloc((size_t)E1C * 4);
  float*    f_attself = (float*)alloc((size_t)N1 * 4);
  float*    f_m       = (float*)alloc((size_t)N1 * 4);
  int*      i_cluster = (int*)alloc((size_t)N1 * 4);
  float*    f_xpool   = (float*)alloc((size_t)NSUP * F * 4);
  float*    f_degc    = (float*)alloc((size_t)NSUP * 4);
  int*      i_rowptrC = (int*)alloc((size_t)(NSUP + 1) * 4);
  int*      i_csrCc   = (int*)alloc((size_t)E1C * 4);
  float*    f_csrCv   = (float*)alloc((size_t)E1C * 4);
  int*      i_rowptrM = (int*)alloc((size_t)(NSUP + 1) * 4);
  int*      i_memb    = (int*)alloc((size_t)N1 * 4);
  float*    f_h2      = (float*)alloc((size_t)NSUP * F * 4);
  float*    f_h2p     = (float*)alloc((size_t)NSUP * F * 4);     // reused for t1
  float*    f_wt      = (float*)alloc((size_t)6 * F * F * 4);
  int*      i_wctr    = (int*)alloc((size_t)24 * 8 * 4);         // per-hop work-claim counters

  // overlays: rank bins live between graph-1 and graph-2; bf16 h lives in graph-2 only
  int* i_cnt22    = (int*)f_ha;       // 16 MB <= 25.6 MB
  int* i_binptr22 = (int*)f_hb;       // 16 MB + 4 <= 25.6 MB
  unsigned short* h16a = (unsigned short*)f_ha;   // 12.8 MB (chunked bf16)
  unsigned short* h16b = (unsigned short*)f_hb;   // 12.8 MB (chunked bf16)

  const int* src1 = ei,  * dst1 = ei + E1C;
  const int* srcy = eiy, * dsty = eiy + E2C;
  const int* a1 = anc, * a2 = anc + AC;

  // --- transpose all weights; zero all work-claim counters once ---
  hipMemsetAsync(i_wctr, 0, (size_t)24 * 8 * 4, stream);
  const float* Ws[6] = { W_gcn, W_c1, W_m1, W_l1, W_l2, W_m2 };
  for (int i = 0; i < 6; ++i)
    k_transpose<<<cdiv(F * F, 256), 256, 0, stream>>>(Ws[i], f_wt + (size_t)i * F * F);
  float* wt_gcn = f_wt, *wt_c1 = f_wt + 16384, *wt_m1 = f_wt + 2 * 16384,
       * wt_l1 = f_wt + 3 * 16384, *wt_l2 = f_wt + 4 * 16384, *wt_m2 = f_wt + 5 * 16384;

  int gE = cdiv(E1C, 256);
  int gN = cdiv(N1, 256);
  int gN8 = cdiv(N1, 8);      // 32-lane-slice-per-row launches
  int gC8 = cdiv(NSUP, 8);
  int gP1 = 8 * cdiv(N1, 64);   // fp32 chunked prop: #items = 8 chunks x node-blocks
  int gP2 = 4 * cdiv(N2, 64);   // bf16 chunked prop: #items = 4 chunks x node-blocks

  // --- CSR graph1 by dst, with raw w; then deg=rowsum, normalize in place ---
  hipMemsetAsync(i_cnt, 0, (size_t)(NBINS + 1) * 4, stream);
  k_count<<<gE, 256, 0, stream>>>(dst1, i_cnt, E1C);
  k_scan<<<1, 1024, 0, stream>>>(i_cnt, i_rowptr1, N1);
  hipMemsetAsync(i_cnt, 0, (size_t)(NBINS + 1) * 4, stream);
  k_fill<<<gE, 256, 0, stream>>>(dst1, src1, w1, i_rowptr1, i_cnt, i_csr1c, f_csr1v, E1C);
  k_rowsum<<<gN8, 256, 0, stream>>>(i_rowptr1, f_csr1v, f_deg, N1);
  k_csrnorm<<<gN8, 256, 0, stream>>>(i_rowptr1, i_csr1c, f_csr1v, f_deg, N1);

  // --- GCN graph1: h0 = x@W + b (chunked layout); 10 hops XCD-pinned chunked fp32 ---
  k_mm128<<<cdiv(N1, 16), 256, 0, stream>>>(x, wt_gcn, b_gcn, f_ha, N1, 0, 1);
  {
    const float* cur = f_ha;
    for (int i = 0; i < KHOPS; ++i) {
      int last = (i == KHOPS - 1);
      float* dst = (i & 1) ? f_ha : f_hb;
      k_prop_c8<<<gP1, 256, 0, stream>>>(cur, dst,
                                         last ? (float4*)out_x : nullptr,
                                         last ? (float4*)f_xr : nullptr,
                                         i_rowptr1, i_csr1c, f_csr1v,
                                         i_wctr + i * 8, N1);
      cur = dst;
    }
  }

  // --- scores + top-k ranks (22-bit bins) ---
  k_score<<<cdiv(N1, 4), 256, 0, stream>>>(f_xr, p_sc, f_s, N1);
  k_key<<<gN, 256, 0, stream>>>(f_s, u_key, N1);
  hipMemsetAsync(i_cnt22, 0, (size_t)NBINS22 * 4, stream);
  k_count_bins22<<<gN, 256, 0, stream>>>(u_key, i_cnt22, N1);
  k_hist_blocksum<<<NBINS22 / 1024, 256, 0, stream>>>(i_cnt22, i_partial);
  k_scan<<<1, 1024, 0, stream>>>(i_partial, i_partptr, 4096);
  k_hist_apply<<<NBINS22 / 1024, 256, 0, stream>>>(i_cnt22, i_partptr, i_binptr22);
  hipMemsetAsync(i_cnt22, 0, (size_t)NBINS22 * 4, stream);
  k_fill_bins22<<<gN, 256, 0, stream>>>(u_key, i_binptr22, i_cnt22, i_bidx, u_bkey, N1);
  k_rank22<<<gN, 256, 0, stream>>>(u_key, i_binptr22, i_bidx, u_bkey, i_supid, N1);

  // --- CSR graph1 by src (attention candidates) ---
  hipMemsetAsync(i_cnt, 0, (size_t)(NBINS + 1) * 4, stream);
  k_count<<<gE, 256, 0, stream>>>(src1, i_cnt, E1C);
  k_scan<<<1, 1024, 0, stream>>>(i_cnt, i_rowptrS, N1);
  hipMemsetAsync(i_cnt, 0, (size_t)(NBINS + 1) * 4, stream);
  k_fill<<<gE, 256, 0, stream>>>(src1, dst1, (const float*)nullptr, i_rowptrS, i_cnt, i_csrSc,
                                 (float*)nullptr, E1C);

  // --- attention passes ---
  k_att_a<<<cdiv(N1, 4), 256, 0, stream>>>(f_xr, i_rowptrS, i_csrSc, i_supid, tmp,
                                           f_att, f_attself, f_m, N1);
  k_att_b<<<gN8, 256, 0, stream>>>(i_rowptrS, i_csrSc, i_supid, f_att, f_attself,
                                   f_m, i_cluster, a_out, N1);

  // --- coarsen: cluster->member CSR + pull pooling (no fp32 atomics) ---
  hipMemsetAsync(i_cnt, 0, (size_t)(NBINS + 1) * 4, stream);
  k_count<<<gN, 256, 0, stream>>>(i_cluster, i_cnt, N1);
  k_scan<<<1, 1024, 0, stream>>>(i_cnt, i_rowptrM, NSUP);
  hipMemsetAsync(i_cnt, 0, (size_t)(NBINS + 1) * 4, stream);
  k_fill_iota<<<gN, 256, 0, stream>>>(i_cluster, i_rowptrM, i_cnt, i_memb, N1);
  k_xpool_pull<<<gC8, 256, 0, stream>>>((const float4*)f_xr, a_out, i_rowptrM,
                                        i_memb, (float4*)f_xpool, NSUP);

  // --- coarse CSR with cw values; degc=rowsum; normalize in place ---
  hipMemsetAsync(i_cnt, 0, (size_t)(NBINS + 1) * 4, stream);
  k_count_coarse<<<gE, 256, 0, stream>>>(dst1, i_cluster, i_cnt, E1C);
  k_scan<<<1, 1024, 0, stream>>>(i_cnt, i_rowptrC, NSUP);
  hipMemsetAsync(i_cnt, 0, (size_t)(NBINS + 1) * 4, stream);
  k_fill_coarse<<<gE, 256, 0, stream>>>(src1, dst1, i_cluster, w1, a_out, i_rowptrC, i_cnt,
                                        i_csrCc, f_csrCv, E1C);
  k_rowsum<<<gC8, 256, 0, stream>>>(i_rowptrC, f_csrCv, f_degc, NSUP);
  k_csrnorm<<<gC8, 256, 0, stream>>>(i_rowptrC, i_csrCc, f_csrCv, f_degc, NSUP);

  // --- coarse conv + MLP1 ---
  k_mm128<<<cdiv(NSUP, 16), 256, 0, stream>>>(f_xpool, wt_c1, b_c1, f_h2, NSUP, 0, 0);
  k_prop<<<gC8, 256, 0, stream>>>((const float4*)f_h2, (float4*)f_h2p, nullptr,
                                  i_rowptrC, i_csrCc, f_csrCv, NSUP);
  k_addrelu<<<cdiv(NSUP * F, 256), 256, 0, stream>>>(f_h2p, f_h2, sup1, NSUP * F);
  k_mm128<<<cdiv(NSUP, 16), 256, 0, stream>>>(sup1, wt_m1, b_m1, sup2, NSUP, 1, 0);

  // --- graph2: CSR + rowsum-norm + GCN in bf16, XCD-pair-pinned chunked ---
  hipMemsetAsync(i_cnt, 0, (size_t)(NBINS + 1) * 4, stream);
  k_count<<<gE, 256, 0, stream>>>(dsty, i_cnt, E2C);
  k_scan<<<1, 1024, 0, stream>>>(i_cnt, i_rowptr1, N2);
  hipMemsetAsync(i_cnt, 0, (size_t)(NBINS + 1) * 4, stream);
  k_fill<<<gE, 256, 0, stream>>>(dsty, srcy, wy, i_rowptr1, i_cnt, i_csr1c, f_csr1v, E2C);
  k_rowsum<<<gN8, 256, 0, stream>>>(i_rowptr1, f_csr1v, f_deg, N2);
  k_csrnorm<<<gN8, 256, 0, stream>>>(i_rowptr1, i_csr1c, f_csr1v, f_deg, N2);
  k_mm128_bf16<<<cdiv(N2, 16), 256, 0, stream>>>(y, wt_gcn, b_gcn, h16a, N2);
  {
    const unsigned short* cur = h16a;
    for (int i = 0; i < KHOPS; ++i) {
      int last = (i == KHOPS - 1);
      unsigned short* dst = (i & 1) ? h16a : h16b;
      k_prop_cb4<<<gP2, 256, 0, stream>>>(cur, dst,
                                          last ? (float4*)out_y : nullptr,
                                          i_rowptr1, i_csr1c, f_csr1v,
                                          i_wctr + (12 + i) * 8, N2);
      cur = dst;
    }
  }

  // --- LastLayer ---
  float* f_t1 = f_h2p;  // reuse
  float* f_t2 = f_xr;   // reuse
  k_mm128<<<cdiv(NSUP, 16), 256, 0, stream>>>(sup2, wt_l1, (const float*)nullptr, f_t1, NSUP, 0, 0);
  k_scatter_q<<<cdiv(AC * F, 256), 256, 0, stream>>>(a1, a2, i_cluster, a_out, f_t1, out_y, AC);
  k_mm128<<<cdiv(N1, 16), 256, 0, stream>>>(out_x, wt_l2, (const float*)nullptr, f_t2, N1, 0, 0);
  k_scatter_t2<<<cdiv(AC * F, 256), 256, 0, stream>>>(a1, a2, f_t2, out_y, AC);

  // --- recon ---
  k_mm128<<<cdiv(N2, 16), 256, 0, stream>>>(out_y, wt_m2, b_m2, recon, N2, 0, 0);
}

// Round 6
// 3592.265 us; speedup vs baseline: 1.0328x; 1.0328x over previous
//
#include <hip/hip_runtime.h>
#include <hip/hip_bf16.h>
#include <math.h>

#define N1 50000
#define N2 50000
#define E1C 800000
#define E2C 800000
#define AC 10000
#define F 128
#define NSUP 25000
#define KHOPS 10
#define NEGINF -1e30f
#define NBINS 65536
#define NBINS22 (1 << 22)

static inline int cdiv(int a, int b) { return (a + b - 1) / b; }

// clang-native vector types for __builtin_nontemporal_store
typedef float v2f __attribute__((ext_vector_type(2)));

// ---------------- bf16 helpers ----------------
__device__ __forceinline__ float bf2f(unsigned short u) {
  return __uint_as_float(((unsigned)u) << 16);
}
__device__ __forceinline__ unsigned short f2bf(float f) {
  unsigned x = __float_as_uint(f);
  return (unsigned short)((x + 0x7FFFu + ((x >> 16) & 1u)) >> 16);
}

// physical XCD id (HW-verified: returns 0..7 on MI355X; validated R5 by FETCH drop)
__device__ __forceinline__ int xcc_id() {
  int v;
  asm volatile("s_getreg_b32 %0, hwreg(20, 0, 32)" : "=s"(v));
  return v;
}

// ---------------- CSR build ----------------
__global__ void k_count(const int* __restrict__ key, int* __restrict__ cnt, int n) {
  int e = blockIdx.x * blockDim.x + threadIdx.x;
  if (e < n) atomicAdd(&cnt[key[e]], 1);
}

// single-block scan: thread-sequential partials + shuffle scan
__global__ void k_scan(const int* __restrict__ cnt, int* __restrict__ rowptr, int n) {
  const int T = 1024;
  int t = threadIdx.x;
  int vpt = (n + T - 1) / T;
  int lo = t * vpt, hi = lo + vpt;
  if (hi > n) hi = n;
  int sum = 0;
  for (int i = lo; i < hi; ++i) sum += cnt[i];
  int lane = t & 63, wid = t >> 6;
  int v = sum;
#pragma unroll
  for (int o = 1; o < 64; o <<= 1) {
    int u = __shfl_up(v, o, 64);
    if (lane >= o) v += u;
  }
  __shared__ int wsum[16];
  if (lane == 63) wsum[wid] = v;
  __syncthreads();
  if (t < 16) {
    int w = wsum[t];
#pragma unroll
    for (int o = 1; o < 16; o <<= 1) {
      int u = __shfl_up(w, o, 64);
      if (t >= o) w += u;
    }
    wsum[t] = w;
  }
  __syncthreads();
  int base = (wid ? wsum[wid - 1] : 0) + (v - sum);
  if (t == 0) rowptr[0] = 0;
  int run = base;
  for (int i = lo; i < hi; ++i) { run += cnt[i]; rowptr[i + 1] = run; }
}

__global__ void k_fill(const int* __restrict__ key, const int* __restrict__ payload,
                       const float* __restrict__ val, const int* __restrict__ rowptr,
                       int* __restrict__ cnt, int* __restrict__ col, float* __restrict__ v,
                       int n) {
  int e = blockIdx.x * blockDim.x + threadIdx.x;
  if (e < n) {
    int k = key[e];
    int p = atomicAdd(&cnt[k], 1);
    int s = rowptr[k] + p;
    col[s] = payload[e];
    if (val) v[s] = val[e];
  }
}

// fill storing the element index itself (for cluster->member lists)
__global__ void k_fill_iota(const int* __restrict__ key, const int* __restrict__ rowptr,
                            int* __restrict__ cnt, int* __restrict__ col, int n) {
  int e = blockIdx.x * blockDim.x + threadIdx.x;
  if (e < n) {
    int k = key[e];
    int p = atomicAdd(&cnt[k], 1);
    col[rowptr[k] + p] = e;
  }
}

__global__ void k_count_coarse(const int* __restrict__ dst, const int* __restrict__ cluster,
                               int* __restrict__ cnt, int n) {
  int e = blockIdx.x * blockDim.x + threadIdx.x;
  if (e < n) atomicAdd(&cnt[cluster[dst[e]]], 1);
}

// coarse fill computing cw = w * a[src] * a[dst] inline
__global__ void k_fill_coarse(const int* __restrict__ src, const int* __restrict__ dst,
                              const int* __restrict__ cluster, const float* __restrict__ w,
                              const float* __restrict__ a, const int* __restrict__ rowptr,
                              int* __restrict__ cnt, int* __restrict__ col,
                              float* __restrict__ v, int n) {
  int e = blockIdx.x * blockDim.x + threadIdx.x;
  if (e < n) {
    int sd = dst[e];
    int k = cluster[sd];
    int p = atomicAdd(&cnt[k], 1);
    int s = rowptr[k] + p;
    int ss = src[e];
    col[s] = cluster[ss];
    v[s] = w[e] * a[ss] * a[sd];
  }
}

// ---------------- degree via CSR rowsum (32-lane slice per row) ----------------
__global__ void k_rowsum(const int* __restrict__ rowptr, const float* __restrict__ v,
                         float* __restrict__ deg, int n) {
  int row = blockIdx.x * 8 + (threadIdx.x >> 5);
  if (row >= n) return;
  int q = threadIdx.x & 31;
  int s0 = rowptr[row], s1 = rowptr[row + 1];
  float s = 0.f;
  for (int k = s0 + q; k < s1; k += 32) s += v[k];
#pragma unroll
  for (int o = 16; o; o >>= 1) s += __shfl_xor(s, o, 64);  // stays within aligned 32-group
  if (q == 0) deg[row] = s;
}

// in-place symmetric normalization of CSR values (32-lane slice per row)
__global__ void k_csrnorm(const int* __restrict__ rowptr, const int* __restrict__ col,
                          float* __restrict__ v, const float* __restrict__ deg, int n) {
  int row = blockIdx.x * 8 + (threadIdx.x >> 5);
  if (row >= n) return;
  int q = threadIdx.x & 31;
  int s0 = rowptr[row], s1 = rowptr[row + 1];
  float di = deg[row] + 1.f;
  for (int s = s0 + q; s < s1; s += 32) {
    float dc = deg[col[s]] + 1.f;
    v[s] = v[s] / sqrtf(dc * di);
  }
}

// ---------------- propagation fp32 baseline (32 lanes/node, 8-edge groups) ------------
// used for the coarse-graph conv
__global__ void k_prop(const float4* __restrict__ hin, float4* __restrict__ hout,
                       float4* __restrict__ relu_out, const int* __restrict__ rowptr,
                       const int* __restrict__ col, const float* __restrict__ val, int n) {
  int node = blockIdx.x * 8 + (threadIdx.x >> 5);
  if (node >= n) return;
  int q = threadIdx.x & 31;
  int s0 = rowptr[node], s1 = rowptr[node + 1];
  float4 acc = make_float4(0.f, 0.f, 0.f, 0.f);
  for (int s = s0; s < s1; s += 8) {
    int c[8]; float v[8];
#pragma unroll
    for (int j = 0; j < 8; ++j) {
      int ss = s + j;
      int sc = (ss < s1) ? ss : (s1 - 1);
      c[j] = col[sc];
      v[j] = (ss < s1) ? val[sc] : 0.f;
    }
    float4 h[8];
#pragma unroll
    for (int j = 0; j < 8; ++j) h[j] = hin[(size_t)c[j] * 32 + q];
#pragma unroll
    for (int j = 0; j < 8; ++j) {
      acc.x = fmaf(v[j], h[j].x, acc.x);
      acc.y = fmaf(v[j], h[j].y, acc.y);
      acc.z = fmaf(v[j], h[j].z, acc.z);
      acc.w = fmaf(v[j], h[j].w, acc.w);
    }
  }
  hout[(size_t)node * 32 + q] = acc;
  if (relu_out) {
    float4 r;
    r.x = fmaxf(acc.x, 0.f); r.y = fmaxf(acc.y, 0.f);
    r.z = fmaxf(acc.z, 0.f); r.w = fmaxf(acc.w, 0.f);
    relu_out[(size_t)node * 32 + q] = r;
  }
}

// ---------------- XCD-pinned chunked fp32 propagation, 8 lanes/node (graph 1) --------
// 8 chunks x 16 floats (64 B/node/chunk = 8 lanes x float2). Strict one-XCD-per-chunk
// via s_getreg XCC_ID + atomic work-claim (mechanism validated R5: FETCH 185->129 MB).
// vs R5's failed 4-lane version: 8 nodes/wave (divergence ~1.15x not 1.3x), 8
// outstanding 8B gathers/lane (= baseline hiding depth), col/val at 8 addrs/inst.
// Per-feature FMA order over edges identical to k_prop -> bit-identical output.
__global__ void k_prop_c16(const float* __restrict__ hin, float* __restrict__ hout,
                           float* __restrict__ outx_std, float* __restrict__ xr_std,
                           const int* __restrict__ rowptr, const int* __restrict__ col,
                           const float* __restrict__ val, int* __restrict__ wctr, int n) {
  const int M = (N1 + 31) >> 5;  // 32-node ranges per chunk
  __shared__ int s_item;
  if (threadIdx.x == 0) {
    int xcc = xcc_id();
    int item = -1;
    for (int t = 0; t < 8; ++t) {
      int c = (xcc + t) & 7;
      int i = atomicAdd(&wctr[c], 1);
      if (i < M) { item = c * M + i; break; }
    }
    s_item = item;
  }
  __syncthreads();
  int item = s_item;
  if (item < 0) return;
  int chunk = item / M;
  int node = (item % M) * 32 + (threadIdx.x >> 3);
  if (node >= n) return;
  int sub = threadIdx.x & 7;  // 8 lanes/node, float2 each
  const float2* hc = (const float2*)hin + (size_t)chunk * n * 8;  // 8 float2/node
  int s0 = rowptr[node], s1 = rowptr[node + 1];
  float2 acc = make_float2(0.f, 0.f);
  for (int s = s0; s < s1; s += 8) {
    int c[8]; float v[8];
#pragma unroll
    for (int j = 0; j < 8; ++j) {
      int ss = s + j;
      int sc = (ss < s1) ? ss : (s1 - 1);
      c[j] = __builtin_nontemporal_load(col + sc);
      float vv = __builtin_nontemporal_load(val + sc);
      v[j] = (ss < s1) ? vv : 0.f;
    }
    float2 h[8];
#pragma unroll
    for (int j = 0; j < 8; ++j) h[j] = hc[(size_t)c[j] * 8 + sub];
#pragma unroll
    for (int j = 0; j < 8; ++j) {
      acc.x = fmaf(v[j], h[j].x, acc.x);
      acc.y = fmaf(v[j], h[j].y, acc.y);
    }
  }
  if (outx_std) {
    // final hop: emit standard [node][128] layout for out_x and relu(x)
    size_t o = (size_t)node * 64 + chunk * 8 + sub;  // float2 index
    ((float2*)outx_std)[o] = acc;
    float2 r = make_float2(fmaxf(acc.x, 0.f), fmaxf(acc.y, 0.f));
    ((float2*)xr_std)[o] = r;
  } else {
    v2f a2 = { acc.x, acc.y };
    __builtin_nontemporal_store(a2,
        (v2f*)hout + (size_t)chunk * n * 8 + (size_t)node * 8 + sub);
  }
}

// ---------------- propagation bf16 baseline (graph-2, 32 lanes/node) ----------------
__global__ void k_prop_bf16(const ushort4* __restrict__ hin, ushort4* __restrict__ hout,
                            float4* __restrict__ fout, const int* __restrict__ rowptr,
                            const int* __restrict__ col, const float* __restrict__ val, int n) {
  int node = blockIdx.x * 8 + (threadIdx.x >> 5);
  if (node >= n) return;
  int q = threadIdx.x & 31;
  int s0 = rowptr[node], s1 = rowptr[node + 1];
  float4 acc = make_float4(0.f, 0.f, 0.f, 0.f);
  for (int s = s0; s < s1; s += 8) {
    int c[8]; float v[8];
#pragma unroll
    for (int j = 0; j < 8; ++j) {
      int ss = s + j;
      int sc = (ss < s1) ? ss : (s1 - 1);
      c[j] = col[sc];
      v[j] = (ss < s1) ? val[sc] : 0.f;
    }
    ushort4 h[8];
#pragma unroll
    for (int j = 0; j < 8; ++j) h[j] = hin[(size_t)c[j] * 32 + q];
#pragma unroll
    for (int j = 0; j < 8; ++j) {
      acc.x = fmaf(v[j], bf2f(h[j].x), acc.x);
      acc.y = fmaf(v[j], bf2f(h[j].y), acc.y);
      acc.z = fmaf(v[j], bf2f(h[j].z), acc.z);
      acc.w = fmaf(v[j], bf2f(h[j].w), acc.w);
    }
  }
  if (fout) {
    fout[(size_t)node * 32 + q] = acc;
  } else {
    ushort4 o;
    o.x = f2bf(acc.x); o.y = f2bf(acc.y); o.z = f2bf(acc.z); o.w = f2bf(acc.w);
    hout[(size_t)node * 32 + q] = o;
  }
}

// ---------------- dense matmul out = relu?(X @ W + b), W given transposed ----------------
__global__ void k_transpose(const float* __restrict__ W, float* __restrict__ WT) {
  int i = blockIdx.x * blockDim.x + threadIdx.x;
  if (i < F * F) { int k = i >> 7, c = i & 127; WT[c * F + k] = W[i]; }
}

// chunked=1 writes [chunk(8)][row][16] fp32 layout for k_prop_c16
__global__ void k_mm128(const float* __restrict__ X, const float* __restrict__ WT,
                        const float* __restrict__ bias, float* __restrict__ out,
                        int M, int relu, int chunked) {
  __shared__ float4 xs[16][32];
  int tid = threadIdx.x;
  int c = tid & 127;
  int half = tid >> 7;
  int row0 = blockIdx.x * 16;
  for (int t = tid; t < 512; t += 256) {
    int r = t >> 5, k4 = t & 31;
    int gr = row0 + r;
    float4 v = make_float4(0.f, 0.f, 0.f, 0.f);
    if (gr < M) v = ((const float4*)X)[(size_t)gr * 32 + k4];
    xs[r][k4] = v;
  }
  __syncthreads();
  float acc[8];
#pragma unroll
  for (int r = 0; r < 8; ++r) acc[r] = 0.f;
  const float4* wrow = (const float4*)WT + (size_t)c * 32;
  for (int k4 = 0; k4 < 32; ++k4) {
    float4 w = wrow[k4];
#pragma unroll
    for (int r = 0; r < 8; ++r) {
      float4 xv = xs[half * 8 + r][k4];
      acc[r] = fmaf(xv.x, w.x, acc[r]);
      acc[r] = fmaf(xv.y, w.y, acc[r]);
      acc[r] = fmaf(xv.z, w.z, acc[r]);
      acc[r] = fmaf(xv.w, w.w, acc[r]);
    }
  }
  float bb = bias ? bias[c] : 0.f;
#pragma unroll
  for (int r = 0; r < 8; ++r) {
    int gr = row0 + half * 8 + r;
    if (gr < M) {
      float v = acc[r] + bb;
      if (relu) v = fmaxf(v, 0.f);
      if (chunked)
        out[((size_t)(c >> 4) * M + gr) * 16 + (c & 15)] = v;
      else
        out[(size_t)gr * F + c] = v;
    }
  }
}

// same as k_mm128 but bf16 output, plain [row][128] layout (graph-2 h0)
__global__ void k_mm128_bf16(const float* __restrict__ X, const float* __restrict__ WT,
                             const float* __restrict__ bias, unsigned short* __restrict__ out,
                             int M) {
  __shared__ float4 xs[16][32];
  int tid = threadIdx.x;
  int c = tid & 127;
  int half = tid >> 7;
  int row0 = blockIdx.x * 16;
  for (int t = tid; t < 512; t += 256) {
    int r = t >> 5, k4 = t & 31;
    int gr = row0 + r;
    float4 v = make_float4(0.f, 0.f, 0.f, 0.f);
    if (gr < M) v = ((const float4*)X)[(size_t)gr * 32 + k4];
    xs[r][k4] = v;
  }
  __syncthreads();
  float acc[8];
#pragma unroll
  for (int r = 0; r < 8; ++r) acc[r] = 0.f;
  const float4* wrow = (const float4*)WT + (size_t)c * 32;
  for (int k4 = 0; k4 < 32; ++k4) {
    float4 w = wrow[k4];
#pragma unroll
    for (int r = 0; r < 8; ++r) {
      float4 xv = xs[half * 8 + r][k4];
      acc[r] = fmaf(xv.x, w.x, acc[r]);
      acc[r] = fmaf(xv.y, w.y, acc[r]);
      acc[r] = fmaf(xv.z, w.z, acc[r]);
      acc[r] = fmaf(xv.w, w.w, acc[r]);
    }
  }
  float bb = bias ? bias[c] : 0.f;
#pragma unroll
  for (int r = 0; r < 8; ++r) {
    int gr = row0 + half * 8 + r;
    if (gr < M) out[(size_t)gr * F + c] = f2bf(acc[r] + bb);
  }
}

// ---------------- elementwise ----------------
__global__ void k_addrelu(const float* __restrict__ a, const float* __restrict__ b,
                          float* __restrict__ out, int n) {
  int i = blockIdx.x * blockDim.x + threadIdx.x;
  if (i < n) out[i] = fmaxf(a[i] + b[i], 0.f);
}

// ---------------- scores + ranking (top-k via 22-bit bin bucketing) ----------------
__global__ void k_score(const float* __restrict__ xr, const float* __restrict__ p,
                        float* __restrict__ s, int n) {
  int wid = (blockIdx.x * blockDim.x + threadIdx.x) >> 6;
  int lane = threadIdx.x & 63;
  if (wid >= n) return;
  const float* row = xr + (size_t)wid * F;
  float d = row[lane] * p[lane] + row[lane + 64] * p[lane + 64];
#pragma unroll
  for (int o = 32; o; o >>= 1) d += __shfl_xor(d, o, 64);
  if (lane == 0) s[wid] = d;
}

__device__ __forceinline__ unsigned sortkey(float f) {
  if (f == 0.f) f = 0.f;  // canonicalize -0 -> +0
  unsigned u = __float_as_uint(f);
  return (u & 0x80000000u) ? ~u : (u | 0x80000000u);
}

__global__ void k_key(const float* __restrict__ s, unsigned* __restrict__ key, int n) {
  int i = blockIdx.x * blockDim.x + threadIdx.x;
  if (i < n) key[i] = sortkey(s[i]);
}

__global__ void k_count_bins22(const unsigned* __restrict__ key, int* __restrict__ cnt, int n) {
  int i = blockIdx.x * blockDim.x + threadIdx.x;
  if (i < n) atomicAdd(&cnt[key[i] >> 10], 1);
}

// block sums over 1024-bin chunks (grid = NBINS22/1024 = 4096 blocks, 256 thr)
__global__ void k_hist_blocksum(const int* __restrict__ cnt, int* __restrict__ partial) {
  int t = threadIdx.x;
  int base = blockIdx.x * 1024 + t * 4;
  int s = cnt[base] + cnt[base + 1] + cnt[base + 2] + cnt[base + 3];
#pragma unroll
  for (int o = 32; o; o >>= 1) s += __shfl_down(s, o, 64);
  __shared__ int ws[4];
  int lane = t & 63, w = t >> 6;
  if (lane == 0) ws[w] = s;
  __syncthreads();
  if (t == 0) partial[blockIdx.x] = ws[0] + ws[1] + ws[2] + ws[3];
}

// apply scanned partials: binptr[b+1] = global inclusive prefix
__global__ void k_hist_apply(const int* __restrict__ cnt, const int* __restrict__ partialptr,
                             int* __restrict__ binptr) {
  int t = threadIdx.x;
  int base = blockIdx.x * 1024 + t * 4;
  int c0 = cnt[base], c1 = cnt[base + 1], c2 = cnt[base + 2], c3 = cnt[base + 3];
  int s = c0 + c1 + c2 + c3;
  int lane = t & 63, w = t >> 6;
  int v = s;
#pragma unroll
  for (int o = 1; o < 64; o <<= 1) {
    int u = __shfl_up(v, o, 64);
    if (lane >= o) v += u;
  }
  __shared__ int ws[4];
  if (lane == 63) ws[w] = v;
  __syncthreads();
  int wb = 0;
  for (int i = 0; i < w; ++i) wb += ws[i];
  int run = partialptr[blockIdx.x] + wb + (v - s);
  binptr[base + 1] = run + c0;
  binptr[base + 2] = run + c0 + c1;
  binptr[base + 3] = run + c0 + c1 + c2;
  binptr[base + 4] = run + s;
  if (blockIdx.x == 0 && t == 0) binptr[0] = 0;
}

__global__ void k_fill_bins22(const unsigned* __restrict__ key, const int* __restrict__ binptr,
                              int* __restrict__ cnt, int* __restrict__ bidx,
                              unsigned* __restrict__ bkey, int n) {
  int i = blockIdx.x * blockDim.x + threadIdx.x;
  if (i < n) {
    unsigned k = key[i];
    int b = k >> 10;
    int p = atomicAdd(&cnt[b], 1);
    int s = binptr[b] + p;
    bidx[s] = i;
    bkey[s] = k;
  }
}

// rank_i = #{j: s_j > s_i} + #{j: s_j == s_i && j < i}; supid = rank < NSUP ? rank : -1
__global__ void k_rank22(const unsigned* __restrict__ key, const int* __restrict__ binptr,
                         const int* __restrict__ bidx, const unsigned* __restrict__ bkey,
                         int* __restrict__ supid, int n) {
  int i = blockIdx.x * blockDim.x + threadIdx.x;
  if (i >= n) return;
  unsigned ki = key[i];
  int b = ki >> 10;
  int cnt = n - binptr[b + 1];  // all keys in strictly-higher bins
  int s1 = binptr[b + 1];
  for (int s = binptr[b]; s < s1; ++s) {
    unsigned kj = bkey[s];
    cnt += (kj > ki) || (kj == ki && bidx[s] < i);
  }
  supid[i] = (cnt < NSUP) ? cnt : -1;
}

// ---------------- attention / assignment ----------------
__device__ __forceinline__ float read_T(const void* p) {
  int ib = *(const int*)p;
  float fb = __int_as_float(ib);
  if (ib >= 1 && ib < (1 << 20)) return (float)ib;   // int-encoded scalar
  if (fb > 1e-6f && fb < 1e6f) return fb;            // float-encoded scalar
  return 1.0f;
}

// wave per node; 4-edge groups for gather MLP
__global__ void k_att_a(const float* __restrict__ xr, const int* __restrict__ rowptr,
                        const int* __restrict__ col, const int* __restrict__ supid,
                        const void* __restrict__ tptr, float* __restrict__ att,
                        float* __restrict__ attself, float* __restrict__ mout, int n) {
  int wid = (blockIdx.x * blockDim.x + threadIdx.x) >> 6;
  int lane = threadIdx.x & 63;
  if (wid >= n) return;
  float inv = 1.0f / (sqrtf(128.0f) * read_T(tptr));
  const float* xn = xr + (size_t)wid * F;
  float x0 = xn[lane], x1 = xn[lane + 64];
  // self candidate
  float d = x0 * x0 + x1 * x1;
#pragma unroll
  for (int o = 32; o; o >>= 1) d += __shfl_xor(d, o, 64);
  float av = (supid[wid] >= 0) ? d * inv : NEGINF;
  float m = av;
  if (lane == 0) attself[wid] = av;
  int s0 = rowptr[wid], s1 = rowptr[wid + 1];
  for (int s = s0; s < s1; s += 4) {
    int c[4]; bool ok[4];
#pragma unroll
    for (int j = 0; j < 4; ++j) {
      int ss = s + j;
      ok[j] = ss < s1;
      c[j] = col[ok[j] ? ss : (s1 - 1)];
    }
    float dd[4];
#pragma unroll
    for (int j = 0; j < 4; ++j) {
      const float* xc = xr + (size_t)c[j] * F;
      dd[j] = x0 * xc[lane] + x1 * xc[lane + 64];
    }
#pragma unroll
    for (int j = 0; j < 4; ++j) {
#pragma unroll
      for (int o = 32; o; o >>= 1) dd[j] += __shfl_xor(dd[j], o, 64);
    }
#pragma unroll
    for (int j = 0; j < 4; ++j) {
      if (ok[j]) {
        float a2 = (supid[c[j]] >= 0) ? dd[j] * inv : NEGINF;
        if (lane == 0) att[s + j] = a2;
        m = fmaxf(m, a2);
      }
    }
  }
  if (lane == 0) mout[wid] = m;
}

// 32-lane slice per node: esum = sum exp(att-m), best = max supid among argmax cands
__global__ void k_att_b(const int* __restrict__ rowptr, const int* __restrict__ col,
                        const int* __restrict__ supid, const float* __restrict__ att,
                        const float* __restrict__ attself, const float* __restrict__ mv,
                        int* __restrict__ cluster, float* __restrict__ aout, int n) {
  int i = blockIdx.x * 8 + (threadIdx.x >> 5);
  if (i >= n) return;
  int q = threadIdx.x & 31;
  float m = mv[i];
  float as = attself[i];
  float esum = 0.f;
  int best = -1;
  if (q == 0) {
    esum = expf(as - m);
    if (as >= m) best = supid[i];
  }
  int s0 = rowptr[i], s1 = rowptr[i + 1];
  for (int s = s0 + q; s < s1; s += 32) {
    float av = att[s];
    esum += expf(av - m);
    if (av >= m) {
      int sid = supid[col[s]];
      if (sid > best) best = sid;
    }
  }
#pragma unroll
  for (int o = 16; o; o >>= 1) {
    esum += __shfl_xor(esum, o, 64);
    int ob = __shfl_xor(best, o, 64);
    if (ob > best) best = ob;
  }
  if (q == 0) {
    int has = best >= 0;
    cluster[i] = has ? best : 0;
    aout[i] = has ? 1.0f / esum : 0.0f;
  }
}

// ---------------- pooling (pull over cluster->member CSR) ----------------
__global__ void k_xpool_pull(const float4* __restrict__ xr, const float* __restrict__ a,
                             const int* __restrict__ rowptrM, const int* __restrict__ memb,
                             float4* __restrict__ xpool, int n) {
  int c = blockIdx.x * 8 + (threadIdx.x >> 5);
  if (c >= n) return;
  int q = threadIdx.x & 31;
  int s0 = rowptrM[c], s1 = rowptrM[c + 1];
  float4 acc = make_float4(0.f, 0.f, 0.f, 0.f);
  for (int s = s0; s < s1; ++s) {
    int m = memb[s];
    float av = a[m];
    float4 h = xr[(size_t)m * 32 + q];
    acc.x = fmaf(av, h.x, acc.x);
    acc.y = fmaf(av, h.y, acc.y);
    acc.z = fmaf(av, h.z, acc.z);
    acc.w = fmaf(av, h.w, acc.w);
  }
  xpool[(size_t)c * 32 + q] = acc;
}

// ---------------- anchor scatters ----------------
__global__ void k_scatter_q(const int* __restrict__ a1, const int* __restrict__ a2,
                            const int* __restrict__ cluster, const float* __restrict__ aarr,
                            const float* __restrict__ t1, float* __restrict__ outy, int nA) {
  int idx = blockIdx.x * blockDim.x + threadIdx.x;
  if (idx >= nA * F) return;
  int k = idx >> 7, f = idx & 127;
  int n1 = a1[k];
  float qw = aarr[n1];
  if (qw != 0.f)
    atomicAdd(&outy[(size_t)a2[k] * F + f], qw * t1[(size_t)cluster[n1] * F + f]);
}

__global__ void k_scatter_t2(const int* __restrict__ a1, const int* __restrict__ a2,
                             const float* __restrict__ t2, float* __restrict__ outy, int nA) {
  int idx = blockIdx.x * blockDim.x + threadIdx.x;
  if (idx >= nA * F) return;
  int k = idx >> 7, f = idx & 127;
  atomicAdd(&outy[(size_t)a2[k] * F + f], t2[(size_t)a1[k] * F + f]);
}

// ================= host =================
extern "C" void kernel_launch(void* const* d_in, const int* in_sizes, int n_in,
                              void* d_out, int out_size, void* d_ws, size_t ws_size,
                              hipStream_t stream) {
  (void)in_sizes; (void)n_in; (void)out_size; (void)ws_size;
  const float* x   = (const float*)d_in[0];
  const int*   ei  = (const int*)d_in[1];     // src = ei, dst = ei+E1C
  const float* w1  = (const float*)d_in[2];
  const float* y   = (const float*)d_in[3];
  const int*   eiy = (const int*)d_in[4];
  const float* wy  = (const float*)d_in[5];
  const int*   anc = (const int*)d_in[6];     // a1 = anc, a2 = anc+AC
  const void*  tmp = d_in[7];
  const float* W_gcn = (const float*)d_in[8];
  const float* b_gcn = (const float*)d_in[9];
  const float* p_sc  = (const float*)d_in[10];
  const float* W_c1  = (const float*)d_in[11];
  const float* b_c1  = (const float*)d_in[12];
  const float* W_m1  = (const float*)d_in[13];
  const float* b_m1  = (const float*)d_in[14];
  const float* W_l1  = (const float*)d_in[15];
  const float* W_l2  = (const float*)d_in[16];
  const float* W_m2  = (const float*)d_in[17];
  const float* b_m2  = (const float*)d_in[18];

  float* out   = (float*)d_out;
  float* out_x = out;
  float* sup1  = out_x + (size_t)N1 * F;
  float* out_y = sup1 + (size_t)NSUP * F;
  float* sup2  = out_y + (size_t)N2 * F;
  float* a_out = sup2 + (size_t)NSUP * F;
  float* recon = a_out + N1;

  char* wsb = (char*)d_ws;
  size_t off = 0;
  auto alloc = [&](size_t bytes) -> void* {
    void* p = wsb + off;
    off = (off + bytes + 255) & ~(size_t)255;
    return p;
  };
  float*    f_csr1v   = (float*)alloc((size_t)E1C * 4);          // reused for graph2 CSR val
  int*      i_csr1c   = (int*)alloc((size_t)E1C * 4);            // reused for graph2 CSR col
  int*      i_rowptr1 = (int*)alloc((size_t)(N1 + 1) * 4);       // reused for graph2
  float*    f_deg     = (float*)alloc((size_t)N1 * 4);           // reused for graph2
  int*      i_cnt     = (int*)alloc((size_t)(NBINS + 1) * 4);
  float*    f_ha      = (float*)alloc((size_t)N1 * F * 4);       // g1 h / cnt22 / g2 bf16 h_a
  float*    f_hb      = (float*)alloc((size_t)N1 * F * 4);       // g1 h / binptr22 / g2 bf16 h_b
  float*    f_xr      = (float*)alloc((size_t)N1 * F * 4);       // reused for t2
  float*    f_s       = (float*)alloc((size_t)N1 * 4);
  unsigned* u_key     = (unsigned*)alloc((size_t)N1 * 4);
  int*      i_partial = (int*)alloc((size_t)4096 * 4);
  int*      i_partptr = (int*)alloc((size_t)4097 * 4);
  int*      i_bidx    = (int*)alloc((size_t)N1 * 4);
  unsigned* u_bkey    = (unsigned*)alloc((size_t)N1 * 4);
  int*      i_supid   = (int*)alloc((size_t)N1 * 4);
  int*      i_rowptrS = (int*)alloc((size_t)(N1 + 1) * 4);
  int*      i_csrSc   = (int*)alloc((size_t)E1C * 4);
  float*    f_att     = (float*)alloc((size_t)E1C * 4);
  float*    f_attself = (float*)alloc((size_t)N1 * 4);
  float*    f_m       = (float*)alloc((size_t)N1 * 4);
  int*      i_cluster = (int*)alloc((size_t)N1 * 4);
  float*    f_xpool   = (float*)alloc((size_t)NSUP * F * 4);
  float*    f_degc    = (float*)alloc((size_t)NSUP * 4);
  int*      i_rowptrC = (int*)alloc((size_t)(NSUP + 1) * 4);
  int*      i_csrCc   = (int*)alloc((size_t)E1C * 4);
  float*    f_csrCv   = (float*)alloc((size_t)E1C * 4);
  int*      i_rowptrM = (int*)alloc((size_t)(NSUP + 1) * 4);
  int*      i_memb    = (int*)alloc((size_t)N1 * 4);
  float*    f_h2      = (float*)alloc((size_t)NSUP * F * 4);
  float*    f_h2p     = (float*)alloc((size_t)NSUP * F * 4);     // reused for t1
  float*    f_wt      = (float*)alloc((size_t)6 * F * F * 4);
  int*      i_wctr    = (int*)alloc((size_t)16 * 8 * 4);         // per-hop work-claim counters

  // overlays: rank bins live between graph-1 and graph-2; bf16 h lives in graph-2 only
  int* i_cnt22    = (int*)f_ha;       // 16 MB <= 25.6 MB
  int* i_binptr22 = (int*)f_hb;       // 16 MB + 4 <= 25.6 MB
  unsigned short* h16a = (unsigned short*)f_ha;   // 12.8 MB
  unsigned short* h16b = (unsigned short*)f_hb;   // 12.8 MB

  const int* src1 = ei,  * dst1 = ei + E1C;
  const int* srcy = eiy, * dsty = eiy + E2C;
  const int* a1 = anc, * a2 = anc + AC;

  // --- transpose all weights; zero work-claim counters ---
  hipMemsetAsync(i_wctr, 0, (size_t)16 * 8 * 4, stream);
  const float* Ws[6] = { W_gcn, W_c1, W_m1, W_l1, W_l2, W_m2 };
  for (int i = 0; i < 6; ++i)
    k_transpose<<<cdiv(F * F, 256), 256, 0, stream>>>(Ws[i], f_wt + (size_t)i * F * F);
  float* wt_gcn = f_wt, *wt_c1 = f_wt + 16384, *wt_m1 = f_wt + 2 * 16384,
       * wt_l1 = f_wt + 3 * 16384, *wt_l2 = f_wt + 4 * 16384, *wt_m2 = f_wt + 5 * 16384;

  int gE = cdiv(E1C, 256);
  int gN = cdiv(N1, 256);
  int gN8 = cdiv(N1, 8);      // 32-lane-slice-per-row launches
  int gC8 = cdiv(NSUP, 8);
  int gP1 = 8 * cdiv(N1, 32);   // chunked fp32 prop: #items = 8 chunks x 32-node ranges

  // --- CSR graph1 by dst, with raw w; then deg=rowsum, normalize in place ---
  hipMemsetAsync(i_cnt, 0, (size_t)(NBINS + 1) * 4, stream);
  k_count<<<gE, 256, 0, stream>>>(dst1, i_cnt, E1C);
  k_scan<<<1, 1024, 0, stream>>>(i_cnt, i_rowptr1, N1);
  hipMemsetAsync(i_cnt, 0, (size_t)(NBINS + 1) * 4, stream);
  k_fill<<<gE, 256, 0, stream>>>(dst1, src1, w1, i_rowptr1, i_cnt, i_csr1c, f_csr1v, E1C);
  k_rowsum<<<gN8, 256, 0, stream>>>(i_rowptr1, f_csr1v, f_deg, N1);
  k_csrnorm<<<gN8, 256, 0, stream>>>(i_rowptr1, i_csr1c, f_csr1v, f_deg, N1);

  // --- GCN graph1: h0 = x@W + b (chunked layout); 10 hops XCD-pinned 8-lane chunked ---
  k_mm128<<<cdiv(N1, 16), 256, 0, stream>>>(x, wt_gcn, b_gcn, f_ha, N1, 0, 1);
  {
    const float* cur = f_ha;
    for (int i = 0; i < KHOPS; ++i) {
      int last = (i == KHOPS - 1);
      float* dst = (i & 1) ? f_ha : f_hb;
      k_prop_c16<<<gP1, 256, 0, stream>>>(cur, dst,
                                          last ? out_x : nullptr,
                                          last ? f_xr : nullptr,
                                          i_rowptr1, i_csr1c, f_csr1v,
                                          i_wctr + i * 8, N1);
      cur = dst;
    }
  }

  // --- scores + top-k ranks (22-bit bins) ---
  k_score<<<cdiv(N1, 4), 256, 0, stream>>>(f_xr, p_sc, f_s, N1);
  k_key<<<gN, 256, 0, stream>>>(f_s, u_key, N1);
  hipMemsetAsync(i_cnt22, 0, (size_t)NBINS22 * 4, stream);
  k_count_bins22<<<gN, 256, 0, stream>>>(u_key, i_cnt22, N1);
  k_hist_blocksum<<<NBINS22 / 1024, 256, 0, stream>>>(i_cnt22, i_partial);
  k_scan<<<1, 1024, 0, stream>>>(i_partial, i_partptr, 4096);
  k_hist_apply<<<NBINS22 / 1024, 256, 0, stream>>>(i_cnt22, i_partptr, i_binptr22);
  hipMemsetAsync(i_cnt22, 0, (size_t)NBINS22 * 4, stream);
  k_fill_bins22<<<gN, 256, 0, stream>>>(u_key, i_binptr22, i_cnt22, i_bidx, u_bkey, N1);
  k_rank22<<<gN, 256, 0, stream>>>(u_key, i_binptr22, i_bidx, u_bkey, i_supid, N1);

  // --- CSR graph1 by src (attention candidates) ---
  hipMemsetAsync(i_cnt, 0, (size_t)(NBINS + 1) * 4, stream);
  k_count<<<gE, 256, 0, stream>>>(src1, i_cnt, E1C);
  k_scan<<<1, 1024, 0, stream>>>(i_cnt, i_rowptrS, N1);
  hipMemsetAsync(i_cnt, 0, (size_t)(NBINS + 1) * 4, stream);
  k_fill<<<gE, 256, 0, stream>>>(src1, dst1, (const float*)nullptr, i_rowptrS, i_cnt, i_csrSc,
                                 (float*)nullptr, E1C);

  // --- attention passes ---
  k_att_a<<<cdiv(N1, 4), 256, 0, stream>>>(f_xr, i_rowptrS, i_csrSc, i_supid, tmp,
                                           f_att, f_attself, f_m, N1);
  k_att_b<<<gN8, 256, 0, stream>>>(i_rowptrS, i_csrSc, i_supid, f_att, f_attself,
                                   f_m, i_cluster, a_out, N1);

  // --- coarsen: cluster->member CSR + pull pooling (no fp32 atomics) ---
  hipMemsetAsync(i_cnt, 0, (size_t)(NBINS + 1) * 4, stream);
  k_count<<<gN, 256, 0, stream>>>(i_cluster, i_cnt, N1);
  k_scan<<<1, 1024, 0, stream>>>(i_cnt, i_rowptrM, NSUP);
  hipMemsetAsync(i_cnt, 0, (size_t)(NBINS + 1) * 4, stream);
  k_fill_iota<<<gN, 256, 0, stream>>>(i_cluster, i_rowptrM, i_cnt, i_memb, N1);
  k_xpool_pull<<<gC8, 256, 0, stream>>>((const float4*)f_xr, a_out, i_rowptrM,
                                        i_memb, (float4*)f_xpool, NSUP);

  // --- coarse CSR with cw values; degc=rowsum; normalize in place ---
  hipMemsetAsync(i_cnt, 0, (size_t)(NBINS + 1) * 4, stream);
  k_count_coarse<<<gE, 256, 0, stream>>>(dst1, i_cluster, i_cnt, E1C);
  k_scan<<<1, 1024, 0, stream>>>(i_cnt, i_rowptrC, NSUP);
  hipMemsetAsync(i_cnt, 0, (size_t)(NBINS + 1) * 4, stream);
  k_fill_coarse<<<gE, 256, 0, stream>>>(src1, dst1, i_cluster, w1, a_out, i_rowptrC, i_cnt,
                                        i_csrCc, f_csrCv, E1C);
  k_rowsum<<<gC8, 256, 0, stream>>>(i_rowptrC, f_csrCv, f_degc, NSUP);
  k_csrnorm<<<gC8, 256, 0, stream>>>(i_rowptrC, i_csrCc, f_csrCv, f_degc, NSUP);

  // --- coarse conv + MLP1 ---
  k_mm128<<<cdiv(NSUP, 16), 256, 0, stream>>>(f_xpool, wt_c1, b_c1, f_h2, NSUP, 0, 0);
  k_prop<<<gC8, 256, 0, stream>>>((const float4*)f_h2, (float4*)f_h2p, nullptr,
                                  i_rowptrC, i_csrCc, f_csrCv, NSUP);
  k_addrelu<<<cdiv(NSUP * F, 256), 256, 0, stream>>>(f_h2p, f_h2, sup1, NSUP * F);
  k_mm128<<<cdiv(NSUP, 16), 256, 0, stream>>>(sup1, wt_m1, b_m1, sup2, NSUP, 1, 0);

  // --- graph2: CSR + rowsum-norm + GCN in bf16 (baseline structure) ---
  hipMemsetAsync(i_cnt, 0, (size_t)(NBINS + 1) * 4, stream);
  k_count<<<gE, 256, 0, stream>>>(dsty, i_cnt, E2C);
  k_scan<<<1, 1024, 0, stream>>>(i_cnt, i_rowptr1, N2);
  hipMemsetAsync(i_cnt, 0, (size_t)(NBINS + 1) * 4, stream);
  k_fill<<<gE, 256, 0, stream>>>(dsty, srcy, wy, i_rowptr1, i_cnt, i_csr1c, f_csr1v, E2C);
  k_rowsum<<<gN8, 256, 0, stream>>>(i_rowptr1, f_csr1v, f_deg, N2);
  k_csrnorm<<<gN8, 256, 0, stream>>>(i_rowptr1, i_csr1c, f_csr1v, f_deg, N2);
  k_mm128_bf16<<<cdiv(N2, 16), 256, 0, stream>>>(y, wt_gcn, b_gcn, h16a, N2);
  {
    const unsigned short* cur = h16a;
    for (int i = 0; i < KHOPS; ++i) {
      int last = (i == KHOPS - 1);
      unsigned short* dst = (i & 1) ? h16a : h16b;
      k_prop_bf16<<<gN8, 256, 0, stream>>>(
          (const ushort4*)cur, last ? nullptr : (ushort4*)dst,
          last ? (float4*)out_y : nullptr, i_rowptr1, i_csr1c, f_csr1v, N2);
      cur = dst;
    }
  }

  // --- LastLayer ---
  float* f_t1 = f_h2p;  // reuse
  float* f_t2 = f_xr;   // reuse
  k_mm128<<<cdiv(NSUP, 16), 256, 0, stream>>>(sup2, wt_l1, (const float*)nullptr, f_t1, NSUP, 0, 0);
  k_scatter_q<<<cdiv(AC * F, 256), 256, 0, stream>>>(a1, a2, i_cluster, a_out, f_t1, out_y, AC);
  k_mm128<<<cdiv(N1, 16), 256, 0, stream>>>(out_x, wt_l2, (const float*)nullptr, f_t2, N1, 0, 0);
  k_scatter_t2<<<cdiv(AC * F, 256), 256, 0, stream>>>(a1, a2, f_t2, out_y, AC);

  // --- recon ---
  k_mm128<<<cdiv(N2, 16), 256, 0, stream>>>(out_y, wt_m2, b_m2, recon, N2, 0, 0);
}

// Round 7
// 2363.247 us; speedup vs baseline: 1.5700x; 1.5201x over previous
//
#include <hip/hip_runtime.h>
#include <hip/hip_bf16.h>
#include <math.h>

#define N1 50000
#define N2 50000
#define E1C 800000
#define E2C 800000
#define AC 10000
#define F 128
#define NSUP 25000
#define KHOPS 10
#define NEGINF -1e30f
#define NBINS 65536
#define NBINS22 (1 << 22)

static inline int cdiv(int a, int b) { return (a + b - 1) / b; }

// ---------------- bf16 helpers ----------------
__device__ __forceinline__ float bf2f(unsigned short u) {
  return __uint_as_float(((unsigned)u) << 16);
}
__device__ __forceinline__ unsigned short f2bf(float f) {
  unsigned x = __float_as_uint(f);
  return (unsigned short)((x + 0x7FFFu + ((x >> 16) & 1u)) >> 16);
}

// ---------------- CSR build ----------------
__global__ void k_count(const int* __restrict__ key, int* __restrict__ cnt, int n) {
  int e = blockIdx.x * blockDim.x + threadIdx.x;
  if (e < n) atomicAdd(&cnt[key[e]], 1);
}

// single-block scan: thread-sequential partials + shuffle scan
__global__ void k_scan(const int* __restrict__ cnt, int* __restrict__ rowptr, int n) {
  const int T = 1024;
  int t = threadIdx.x;
  int vpt = (n + T - 1) / T;
  int lo = t * vpt, hi = lo + vpt;
  if (hi > n) hi = n;
  int sum = 0;
  for (int i = lo; i < hi; ++i) sum += cnt[i];
  int lane = t & 63, wid = t >> 6;
  int v = sum;
#pragma unroll
  for (int o = 1; o < 64; o <<= 1) {
    int u = __shfl_up(v, o, 64);
    if (lane >= o) v += u;
  }
  __shared__ int wsum[16];
  if (lane == 63) wsum[wid] = v;
  __syncthreads();
  if (t < 16) {
    int w = wsum[t];
#pragma unroll
    for (int o = 1; o < 16; o <<= 1) {
      int u = __shfl_up(w, o, 64);
      if (t >= o) w += u;
    }
    wsum[t] = w;
  }
  __syncthreads();
  int base = (wid ? wsum[wid - 1] : 0) + (v - sum);
  if (t == 0) rowptr[0] = 0;
  int run = base;
  for (int i = lo; i < hi; ++i) { run += cnt[i]; rowptr[i + 1] = run; }
}

__global__ void k_fill(const int* __restrict__ key, const int* __restrict__ payload,
                       const float* __restrict__ val, const int* __restrict__ rowptr,
                       int* __restrict__ cnt, int* __restrict__ col, float* __restrict__ v,
                       int n) {
  int e = blockIdx.x * blockDim.x + threadIdx.x;
  if (e < n) {
    int k = key[e];
    int p = atomicAdd(&cnt[k], 1);
    int s = rowptr[k] + p;
    col[s] = payload[e];
    if (val) v[s] = val[e];
  }
}

// fill storing the element index itself (for cluster->member lists)
__global__ void k_fill_iota(const int* __restrict__ key, const int* __restrict__ rowptr,
                            int* __restrict__ cnt, int* __restrict__ col, int n) {
  int e = blockIdx.x * blockDim.x + threadIdx.x;
  if (e < n) {
    int k = key[e];
    int p = atomicAdd(&cnt[k], 1);
    col[rowptr[k] + p] = e;
  }
}

__global__ void k_count_coarse(const int* __restrict__ dst, const int* __restrict__ cluster,
                               int* __restrict__ cnt, int n) {
  int e = blockIdx.x * blockDim.x + threadIdx.x;
  if (e < n) atomicAdd(&cnt[cluster[dst[e]]], 1);
}

// coarse fill computing cw = w * a[src] * a[dst] inline
__global__ void k_fill_coarse(const int* __restrict__ src, const int* __restrict__ dst,
                              const int* __restrict__ cluster, const float* __restrict__ w,
                              const float* __restrict__ a, const int* __restrict__ rowptr,
                              int* __restrict__ cnt, int* __restrict__ col,
                              float* __restrict__ v, int n) {
  int e = blockIdx.x * blockDim.x + threadIdx.x;
  if (e < n) {
    int sd = dst[e];
    int k = cluster[sd];
    int p = atomicAdd(&cnt[k], 1);
    int s = rowptr[k] + p;
    int ss = src[e];
    col[s] = cluster[ss];
    v[s] = w[e] * a[ss] * a[sd];
  }
}

// ---------------- degree via CSR rowsum (32-lane slice per row) ----------------
__global__ void k_rowsum(const int* __restrict__ rowptr, const float* __restrict__ v,
                         float* __restrict__ deg, int n) {
  int row = blockIdx.x * 8 + (threadIdx.x >> 5);
  if (row >= n) return;
  int q = threadIdx.x & 31;
  int s0 = rowptr[row], s1 = rowptr[row + 1];
  float s = 0.f;
  for (int k = s0 + q; k < s1; k += 32) s += v[k];
#pragma unroll
  for (int o = 16; o; o >>= 1) s += __shfl_xor(s, o, 64);  // stays within aligned 32-group
  if (q == 0) deg[row] = s;
}

// in-place symmetric normalization of CSR values (32-lane slice per row)
__global__ void k_csrnorm(const int* __restrict__ rowptr, const int* __restrict__ col,
                          float* __restrict__ v, const float* __restrict__ deg, int n) {
  int row = blockIdx.x * 8 + (threadIdx.x >> 5);
  if (row >= n) return;
  int q = threadIdx.x & 31;
  int s0 = rowptr[row], s1 = rowptr[row + 1];
  float di = deg[row] + 1.f;
  for (int s = s0 + q; s < s1; s += 32) {
    float dc = deg[col[s]] + 1.f;
    v[s] = v[s] / sqrtf(dc * di);
  }
}

// ---------------- propagation fp32 (pull, 32 threads/node, shfl edge broadcast) -------
// Each 32-lane group coalesced-loads 32 consecutive col/val entries (2 vmem
// instructions per 32 edges, replacing 64 uniform broadcast loads), then
// broadcasts per-edge values via __shfl (LDS pipe). Gathers remain 8-edge
// padded batches; per-feature FMA order over edges is ascending -> bit-identical
// to the original 8-edge-batch kernel.
__global__ void k_prop(const float4* __restrict__ hin, float4* __restrict__ hout,
                       float4* __restrict__ relu_out, const int* __restrict__ rowptr,
                       const int* __restrict__ col, const float* __restrict__ val, int n) {
  int node = blockIdx.x * 8 + (threadIdx.x >> 5);
  if (node >= n) return;
  int q = threadIdx.x & 31;
  int grp = threadIdx.x & 32;  // lane-group base within the 64-wide wave
  int s0 = rowptr[node], s1 = rowptr[node + 1];
  float4 acc = make_float4(0.f, 0.f, 0.f, 0.f);
  for (int s = s0; s < s1; s += 32) {
    int es = s + q;
    int ok = es < s1;
    int sc = ok ? es : (s1 - 1);
    int cme = col[sc];                    // coalesced: 32 consecutive edges
    float vme = ok ? val[sc] : 0.f;
    int nb = s1 - s; if (nb > 32) nb = 32;
    for (int j = 0; j < nb; j += 8) {
      int c8[8]; float v8[8];
#pragma unroll
      for (int t = 0; t < 8; ++t) {
        c8[t] = __shfl(cme, grp + j + t, 64);
        v8[t] = __shfl(vme, grp + j + t, 64);
      }
      float4 h[8];
#pragma unroll
      for (int t = 0; t < 8; ++t) h[t] = hin[(size_t)c8[t] * 32 + q];
#pragma unroll
      for (int t = 0; t < 8; ++t) {
        acc.x = fmaf(v8[t], h[t].x, acc.x);
        acc.y = fmaf(v8[t], h[t].y, acc.y);
        acc.z = fmaf(v8[t], h[t].z, acc.z);
        acc.w = fmaf(v8[t], h[t].w, acc.w);
      }
    }
  }
  hout[(size_t)node * 32 + q] = acc;
  if (relu_out) {
    float4 r;
    r.x = fmaxf(acc.x, 0.f); r.y = fmaxf(acc.y, 0.f);
    r.z = fmaxf(acc.z, 0.f); r.w = fmaxf(acc.w, 0.f);
    relu_out[(size_t)node * 32 + q] = r;
  }
}

// ---------------- propagation bf16 (graph-2, same shfl edge-broadcast scheme) ---------
__global__ void k_prop_bf16(const ushort4* __restrict__ hin, ushort4* __restrict__ hout,
                            float4* __restrict__ fout, const int* __restrict__ rowptr,
                            const int* __restrict__ col, const float* __restrict__ val, int n) {
  int node = blockIdx.x * 8 + (threadIdx.x >> 5);
  if (node >= n) return;
  int q = threadIdx.x & 31;
  int grp = threadIdx.x & 32;
  int s0 = rowptr[node], s1 = rowptr[node + 1];
  float4 acc = make_float4(0.f, 0.f, 0.f, 0.f);
  for (int s = s0; s < s1; s += 32) {
    int es = s + q;
    int ok = es < s1;
    int sc = ok ? es : (s1 - 1);
    int cme = col[sc];
    float vme = ok ? val[sc] : 0.f;
    int nb = s1 - s; if (nb > 32) nb = 32;
    for (int j = 0; j < nb; j += 8) {
      int c8[8]; float v8[8];
#pragma unroll
      for (int t = 0; t < 8; ++t) {
        c8[t] = __shfl(cme, grp + j + t, 64);
        v8[t] = __shfl(vme, grp + j + t, 64);
      }
      ushort4 h[8];
#pragma unroll
      for (int t = 0; t < 8; ++t) h[t] = hin[(size_t)c8[t] * 32 + q];
#pragma unroll
      for (int t = 0; t < 8; ++t) {
        acc.x = fmaf(v8[t], bf2f(h[t].x), acc.x);
        acc.y = fmaf(v8[t], bf2f(h[t].y), acc.y);
        acc.z = fmaf(v8[t], bf2f(h[t].z), acc.z);
        acc.w = fmaf(v8[t], bf2f(h[t].w), acc.w);
      }
    }
  }
  if (fout) {
    fout[(size_t)node * 32 + q] = acc;
  } else {
    ushort4 o;
    o.x = f2bf(acc.x); o.y = f2bf(acc.y); o.z = f2bf(acc.z); o.w = f2bf(acc.w);
    hout[(size_t)node * 32 + q] = o;
  }
}

// ---------------- dense matmul out = relu?(X @ W + b), W given transposed ----------------
__global__ void k_transpose(const float* __restrict__ W, float* __restrict__ WT) {
  int i = blockIdx.x * blockDim.x + threadIdx.x;
  if (i < F * F) { int k = i >> 7, c = i & 127; WT[c * F + k] = W[i]; }
}

__global__ void k_mm128(const float* __restrict__ X, const float* __restrict__ WT,
                        const float* __restrict__ bias, float* __restrict__ out,
                        int M, int relu) {
  __shared__ float4 xs[16][32];
  int tid = threadIdx.x;
  int c = tid & 127;
  int half = tid >> 7;
  int row0 = blockIdx.x * 16;
  for (int t = tid; t < 512; t += 256) {
    int r = t >> 5, k4 = t & 31;
    int gr = row0 + r;
    float4 v = make_float4(0.f, 0.f, 0.f, 0.f);
    if (gr < M) v = ((const float4*)X)[(size_t)gr * 32 + k4];
    xs[r][k4] = v;
  }
  __syncthreads();
  float acc[8];
#pragma unroll
  for (int r = 0; r < 8; ++r) acc[r] = 0.f;
  const float4* wrow = (const float4*)WT + (size_t)c * 32;
  for (int k4 = 0; k4 < 32; ++k4) {
    float4 w = wrow[k4];
#pragma unroll
    for (int r = 0; r < 8; ++r) {
      float4 xv = xs[half * 8 + r][k4];
      acc[r] = fmaf(xv.x, w.x, acc[r]);
      acc[r] = fmaf(xv.y, w.y, acc[r]);
      acc[r] = fmaf(xv.z, w.z, acc[r]);
      acc[r] = fmaf(xv.w, w.w, acc[r]);
    }
  }
  float bb = bias ? bias[c] : 0.f;
#pragma unroll
  for (int r = 0; r < 8; ++r) {
    int gr = row0 + half * 8 + r;
    if (gr < M) {
      float v = acc[r] + bb;
      if (relu) v = fmaxf(v, 0.f);
      out[(size_t)gr * F + c] = v;
    }
  }
}

// same as k_mm128 but bf16 output
__global__ void k_mm128_bf16(const float* __restrict__ X, const float* __restrict__ WT,
                             const float* __restrict__ bias, unsigned short* __restrict__ out,
                             int M) {
  __shared__ float4 xs[16][32];
  int tid = threadIdx.x;
  int c = tid & 127;
  int half = tid >> 7;
  int row0 = blockIdx.x * 16;
  for (int t = tid; t < 512; t += 256) {
    int r = t >> 5, k4 = t & 31;
    int gr = row0 + r;
    float4 v = make_float4(0.f, 0.f, 0.f, 0.f);
    if (gr < M) v = ((const float4*)X)[(size_t)gr * 32 + k4];
    xs[r][k4] = v;
  }
  __syncthreads();
  float acc[8];
#pragma unroll
  for (int r = 0; r < 8; ++r) acc[r] = 0.f;
  const float4* wrow = (const float4*)WT + (size_t)c * 32;
  for (int k4 = 0; k4 < 32; ++k4) {
    float4 w = wrow[k4];
#pragma unroll
    for (int r = 0; r < 8; ++r) {
      float4 xv = xs[half * 8 + r][k4];
      acc[r] = fmaf(xv.x, w.x, acc[r]);
      acc[r] = fmaf(xv.y, w.y, acc[r]);
      acc[r] = fmaf(xv.z, w.z, acc[r]);
      acc[r] = fmaf(xv.w, w.w, acc[r]);
    }
  }
  float bb = bias ? bias[c] : 0.f;
#pragma unroll
  for (int r = 0; r < 8; ++r) {
    int gr = row0 + half * 8 + r;
    if (gr < M) out[(size_t)gr * F + c] = f2bf(acc[r] + bb);
  }
}

// ---------------- elementwise ----------------
__global__ void k_addrelu(const float* __restrict__ a, const float* __restrict__ b,
                          float* __restrict__ out, int n) {
  int i = blockIdx.x * blockDim.x + threadIdx.x;
  if (i < n) out[i] = fmaxf(a[i] + b[i], 0.f);
}

// ---------------- scores + ranking (top-k via 22-bit bin bucketing) ----------------
__global__ void k_score(const float* __restrict__ xr, const float* __restrict__ p,
                        float* __restrict__ s, int n) {
  int wid = (blockIdx.x * blockDim.x + threadIdx.x) >> 6;
  int lane = threadIdx.x & 63;
  if (wid >= n) return;
  const float* row = xr + (size_t)wid * F;
  float d = row[lane] * p[lane] + row[lane + 64] * p[lane + 64];
#pragma unroll
  for (int o = 32; o; o >>= 1) d += __shfl_xor(d, o, 64);
  if (lane == 0) s[wid] = d;
}

__device__ __forceinline__ unsigned sortkey(float f) {
  if (f == 0.f) f = 0.f;  // canonicalize -0 -> +0
  unsigned u = __float_as_uint(f);
  return (u & 0x80000000u) ? ~u : (u | 0x80000000u);
}

__global__ void k_key(const float* __restrict__ s, unsigned* __restrict__ key, int n) {
  int i = blockIdx.x * blockDim.x + threadIdx.x;
  if (i < n) key[i] = sortkey(s[i]);
}

__global__ void k_count_bins22(const unsigned* __restrict__ key, int* __restrict__ cnt, int n) {
  int i = blockIdx.x * blockDim.x + threadIdx.x;
  if (i < n) atomicAdd(&cnt[key[i] >> 10], 1);
}

// block sums over 1024-bin chunks (grid = NBINS22/1024 = 4096 blocks, 256 thr)
__global__ void k_hist_blocksum(const int* __restrict__ cnt, int* __restrict__ partial) {
  int t = threadIdx.x;
  int base = blockIdx.x * 1024 + t * 4;
  int s = cnt[base] + cnt[base + 1] + cnt[base + 2] + cnt[base + 3];
#pragma unroll
  for (int o = 32; o; o >>= 1) s += __shfl_down(s, o, 64);
  __shared__ int ws[4];
  int lane = t & 63, w = t >> 6;
  if (lane == 0) ws[w] = s;
  __syncthreads();
  if (t == 0) partial[blockIdx.x] = ws[0] + ws[1] + ws[2] + ws[3];
}

// apply scanned partials: binptr[b+1] = global inclusive prefix
__global__ void k_hist_apply(const int* __restrict__ cnt, const int* __restrict__ partialptr,
                             int* __restrict__ binptr) {
  int t = threadIdx.x;
  int base = blockIdx.x * 1024 + t * 4;
  int c0 = cnt[base], c1 = cnt[base + 1], c2 = cnt[base + 2], c3 = cnt[base + 3];
  int s = c0 + c1 + c2 + c3;
  int lane = t & 63, w = t >> 6;
  int v = s;
#pragma unroll
  for (int o = 1; o < 64; o <<= 1) {
    int u = __shfl_up(v, o, 64);
    if (lane >= o) v += u;
  }
  __shared__ int ws[4];
  if (lane == 63) ws[w] = v;
  __syncthreads();
  int wb = 0;
  for (int i = 0; i < w; ++i) wb += ws[i];
  int run = partialptr[blockIdx.x] + wb + (v - s);
  binptr[base + 1] = run + c0;
  binptr[base + 2] = run + c0 + c1;
  binptr[base + 3] = run + c0 + c1 + c2;
  binptr[base + 4] = run + s;
  if (blockIdx.x == 0 && t == 0) binptr[0] = 0;
}

__global__ void k_fill_bins22(const unsigned* __restrict__ key, const int* __restrict__ binptr,
                              int* __restrict__ cnt, int* __restrict__ bidx,
                              unsigned* __restrict__ bkey, int n) {
  int i = blockIdx.x * blockDim.x + threadIdx.x;
  if (i < n) {
    unsigned k = key[i];
    int b = k >> 10;
    int p = atomicAdd(&cnt[b], 1);
    int s = binptr[b] + p;
    bidx[s] = i;
    bkey[s] = k;
  }
}

// rank_i = #{j: s_j > s_i} + #{j: s_j == s_i && j < i}; supid = rank < NSUP ? rank : -1
__global__ void k_rank22(const unsigned* __restrict__ key, const int* __restrict__ binptr,
                         const int* __restrict__ bidx, const unsigned* __restrict__ bkey,
                         int* __restrict__ supid, int n) {
  int i = blockIdx.x * blockDim.x + threadIdx.x;
  if (i >= n) return;
  unsigned ki = key[i];
  int b = ki >> 10;
  int cnt = n - binptr[b + 1];  // all keys in strictly-higher bins
  int s1 = binptr[b + 1];
  for (int s = binptr[b]; s < s1; ++s) {
    unsigned kj = bkey[s];
    cnt += (kj > ki) || (kj == ki && bidx[s] < i);
  }
  supid[i] = (cnt < NSUP) ? cnt : -1;
}

// ---------------- attention / assignment ----------------
__device__ __forceinline__ float read_T(const void* p) {
  int ib = *(const int*)p;
  float fb = __int_as_float(ib);
  if (ib >= 1 && ib < (1 << 20)) return (float)ib;   // int-encoded scalar
  if (fb > 1e-6f && fb < 1e6f) return fb;            // float-encoded scalar
  return 1.0f;
}

// wave per node; 4-edge groups for gather MLP
__global__ void k_att_a(const float* __restrict__ xr, const int* __restrict__ rowptr,
                        const int* __restrict__ col, const int* __restrict__ supid,
                        const void* __restrict__ tptr, float* __restrict__ att,
                        float* __restrict__ attself, float* __restrict__ mout, int n) {
  int wid = (blockIdx.x * blockDim.x + threadIdx.x) >> 6;
  int lane = threadIdx.x & 63;
  if (wid >= n) return;
  float inv = 1.0f / (sqrtf(128.0f) * read_T(tptr));
  const float* xn = xr + (size_t)wid * F;
  float x0 = xn[lane], x1 = xn[lane + 64];
  // self candidate
  float d = x0 * x0 + x1 * x1;
#pragma unroll
  for (int o = 32; o; o >>= 1) d += __shfl_xor(d, o, 64);
  float av = (supid[wid] >= 0) ? d * inv : NEGINF;
  float m = av;
  if (lane == 0) attself[wid] = av;
  int s0 = rowptr[wid], s1 = rowptr[wid + 1];
  for (int s = s0; s < s1; s += 4) {
    int c[4]; bool ok[4];
#pragma unroll
    for (int j = 0; j < 4; ++j) {
      int ss = s + j;
      ok[j] = ss < s1;
      c[j] = col[ok[j] ? ss : (s1 - 1)];
    }
    float dd[4];
#pragma unroll
    for (int j = 0; j < 4; ++j) {
      const float* xc = xr + (size_t)c[j] * F;
      dd[j] = x0 * xc[lane] + x1 * xc[lane + 64];
    }
#pragma unroll
    for (int j = 0; j < 4; ++j) {
#pragma unroll
      for (int o = 32; o; o >>= 1) dd[j] += __shfl_xor(dd[j], o, 64);
    }
#pragma unroll
    for (int j = 0; j < 4; ++j) {
      if (ok[j]) {
        float a2 = (supid[c[j]] >= 0) ? dd[j] * inv : NEGINF;
        if (lane == 0) att[s + j] = a2;
        m = fmaxf(m, a2);
      }
    }
  }
  if (lane == 0) mout[wid] = m;
}

// 32-lane slice per node: esum = sum exp(att-m), best = max supid among argmax cands
__global__ void k_att_b(const int* __restrict__ rowptr, const int* __restrict__ col,
                        const int* __restrict__ supid, const float* __restrict__ att,
                        const float* __restrict__ attself, const float* __restrict__ mv,
                        int* __restrict__ cluster, float* __restrict__ aout, int n) {
  int i = blockIdx.x * 8 + (threadIdx.x >> 5);
  if (i >= n) return;
  int q = threadIdx.x & 31;
  float m = mv[i];
  float as = attself[i];
  float esum = 0.f;
  int best = -1;
  if (q == 0) {
    esum = expf(as - m);
    if (as >= m) best = supid[i];
  }
  int s0 = rowptr[i], s1 = rowptr[i + 1];
  for (int s = s0 + q; s < s1; s += 32) {
    float av = att[s];
    esum += expf(av - m);
    if (av >= m) {
      int sid = supid[col[s]];
      if (sid > best) best = sid;
    }
  }
#pragma unroll
  for (int o = 16; o; o >>= 1) {
    esum += __shfl_xor(esum, o, 64);
    int ob = __shfl_xor(best, o, 64);
    if (ob > best) best = ob;
  }
  if (q == 0) {
    int has = best >= 0;
    cluster[i] = has ? best : 0;
    aout[i] = has ? 1.0f / esum : 0.0f;
  }
}

// ---------------- pooling (pull over cluster->member CSR) ----------------
__global__ void k_xpool_pull(const float4* __restrict__ xr, const float* __restrict__ a,
                             const int* __restrict__ rowptrM, const int* __restrict__ memb,
                             float4* __restrict__ xpool, int n) {
  int c = blockIdx.x * 8 + (threadIdx.x >> 5);
  if (c >= n) return;
  int q = threadIdx.x & 31;
  int s0 = rowptrM[c], s1 = rowptrM[c + 1];
  float4 acc = make_float4(0.f, 0.f, 0.f, 0.f);
  for (int s = s0; s < s1; ++s) {
    int m = memb[s];
    float av = a[m];
    float4 h = xr[(size_t)m * 32 + q];
    acc.x = fmaf(av, h.x, acc.x);
    acc.y = fmaf(av, h.y, acc.y);
    acc.z = fmaf(av, h.z, acc.z);
    acc.w = fmaf(av, h.w, acc.w);
  }
  xpool[(size_t)c * 32 + q] = acc;
}

// ---------------- anchor scatters ----------------
__global__ void k_scatter_q(const int* __restrict__ a1, const int* __restrict__ a2,
                            const int* __restrict__ cluster, const float* __restrict__ aarr,
                            const float* __restrict__ t1, float* __restrict__ outy, int nA) {
  int idx = blockIdx.x * blockDim.x + threadIdx.x;
  if (idx >= nA * F) return;
  int k = idx >> 7, f = idx & 127;
  int n1 = a1[k];
  float qw = aarr[n1];
  if (qw != 0.f)
    atomicAdd(&outy[(size_t)a2[k] * F + f], qw * t1[(size_t)cluster[n1] * F + f]);
}

__global__ void k_scatter_t2(const int* __restrict__ a1, const int* __restrict__ a2,
                             const float* __restrict__ t2, float* __restrict__ outy, int nA) {
  int idx = blockIdx.x * blockDim.x + threadIdx.x;
  if (idx >= nA * F) return;
  int k = idx >> 7, f = idx & 127;
  atomicAdd(&outy[(size_t)a2[k] * F + f], t2[(size_t)a1[k] * F + f]);
}

// ================= host =================
extern "C" void kernel_launch(void* const* d_in, const int* in_sizes, int n_in,
                              void* d_out, int out_size, void* d_ws, size_t ws_size,
                              hipStream_t stream) {
  (void)in_sizes; (void)n_in; (void)out_size; (void)ws_size;
  const float* x   = (const float*)d_in[0];
  const int*   ei  = (const int*)d_in[1];     // src = ei, dst = ei+E1C
  const float* w1  = (const float*)d_in[2];
  const float* y   = (const float*)d_in[3];
  const int*   eiy = (const int*)d_in[4];
  const float* wy  = (const float*)d_in[5];
  const int*   anc = (const int*)d_in[6];     // a1 = anc, a2 = anc+AC
  const void*  tmp = d_in[7];
  const float* W_gcn = (const float*)d_in[8];
  const float* b_gcn = (const float*)d_in[9];
  const float* p_sc  = (const float*)d_in[10];
  const float* W_c1  = (const float*)d_in[11];
  const float* b_c1  = (const float*)d_in[12];
  const float* W_m1  = (const float*)d_in[13];
  const float* b_m1  = (const float*)d_in[14];
  const float* W_l1  = (const float*)d_in[15];
  const float* W_l2  = (const float*)d_in[16];
  const float* W_m2  = (const float*)d_in[17];
  const float* b_m2  = (const float*)d_in[18];

  float* out   = (float*)d_out;
  float* out_x = out;
  float* sup1  = out_x + (size_t)N1 * F;
  float* out_y = sup1 + (size_t)NSUP * F;
  float* sup2  = out_y + (size_t)N2 * F;
  float* a_out = sup2 + (size_t)NSUP * F;
  float* recon = a_out + N1;

  char* wsb = (char*)d_ws;
  size_t off = 0;
  auto alloc = [&](size_t bytes) -> void* {
    void* p = wsb + off;
    off = (off + bytes + 255) & ~(size_t)255;
    return p;
  };
  float*    f_csr1v   = (float*)alloc((size_t)E1C * 4);          // reused for graph2 CSR val
  int*      i_csr1c   = (int*)alloc((size_t)E1C * 4);            // reused for graph2 CSR col
  int*      i_rowptr1 = (int*)alloc((size_t)(N1 + 1) * 4);       // reused for graph2
  float*    f_deg     = (float*)alloc((size_t)N1 * 4);           // reused for graph2
  int*      i_cnt     = (int*)alloc((size_t)(NBINS + 1) * 4);
  float*    f_ha      = (float*)alloc((size_t)N1 * F * 4);       // g1 h / cnt22 / g2 bf16 h_a
  float*    f_hb      = (float*)alloc((size_t)N1 * F * 4);       // g1 h / binptr22 / g2 bf16 h_b
  float*    f_xr      = (float*)alloc((size_t)N1 * F * 4);       // reused for t2
  float*    f_s       = (float*)alloc((size_t)N1 * 4);
  unsigned* u_key     = (unsigned*)alloc((size_t)N1 * 4);
  int*      i_partial = (int*)alloc((size_t)4096 * 4);
  int*      i_partptr = (int*)alloc((size_t)4097 * 4);
  int*      i_bidx    = (int*)alloc((size_t)N1 * 4);
  unsigned* u_bkey    = (unsigned*)alloc((size_t)N1 * 4);
  int*      i_supid   = (int*)alloc((size_t)N1 * 4);
  int*      i_rowptrS = (int*)alloc((size_t)(N1 + 1) * 4);
  int*      i_csrSc   = (int*)alloc((size_t)E1C * 4);
  float*    f_att     = (float*)alloc((size_t)E1C * 4);
  float*    f_attself = (float*)alloc((size_t)N1 * 4);
  float*    f_m       = (float*)alloc((size_t)N1 * 4);
  int*      i_cluster = (int*)alloc((size_t)N1 * 4);
  float*    f_xpool   = (float*)alloc((size_t)NSUP * F * 4);
  float*    f_degc    = (float*)alloc((size_t)NSUP * 4);
  int*      i_rowptrC = (int*)alloc((size_t)(NSUP + 1) * 4);
  int*      i_csrCc   = (int*)alloc((size_t)E1C * 4);
  float*    f_csrCv   = (float*)alloc((size_t)E1C * 4);
  int*      i_rowptrM = (int*)alloc((size_t)(NSUP + 1) * 4);
  int*      i_memb    = (int*)alloc((size_t)N1 * 4);
  float*    f_h2      = (float*)alloc((size_t)NSUP * F * 4);
  float*    f_h2p     = (float*)alloc((size_t)NSUP * F * 4);     // reused for t1
  float*    f_wt      = (float*)alloc((size_t)6 * F * F * 4);

  // overlays: rank bins live between graph-1 and graph-2; bf16 h lives in graph-2 only
  int* i_cnt22    = (int*)f_ha;       // 16 MB <= 25.6 MB
  int* i_binptr22 = (int*)f_hb;       // 16 MB + 4 <= 25.6 MB
  unsigned short* h16a = (unsigned short*)f_ha;   // 12.8 MB
  unsigned short* h16b = (unsigned short*)f_hb;   // 12.8 MB

  const int* src1 = ei,  * dst1 = ei + E1C;
  const int* srcy = eiy, * dsty = eiy + E2C;
  const int* a1 = anc, * a2 = anc + AC;

  // --- transpose all weights ---
  const float* Ws[6] = { W_gcn, W_c1, W_m1, W_l1, W_l2, W_m2 };
  for (int i = 0; i < 6; ++i)
    k_transpose<<<cdiv(F * F, 256), 256, 0, stream>>>(Ws[i], f_wt + (size_t)i * F * F);
  float* wt_gcn = f_wt, *wt_c1 = f_wt + 16384, *wt_m1 = f_wt + 2 * 16384,
       * wt_l1 = f_wt + 3 * 16384, *wt_l2 = f_wt + 4 * 16384, *wt_m2 = f_wt + 5 * 16384;

  int gE = cdiv(E1C, 256);
  int gN = cdiv(N1, 256);
  int gN8 = cdiv(N1, 8);      // 32-lane-slice-per-row launches
  int gC8 = cdiv(NSUP, 8);

  // --- CSR graph1 by dst, with raw w; then deg=rowsum, normalize in place ---
  hipMemsetAsync(i_cnt, 0, (size_t)(NBINS + 1) * 4, stream);
  k_count<<<gE, 256, 0, stream>>>(dst1, i_cnt, E1C);
  k_scan<<<1, 1024, 0, stream>>>(i_cnt, i_rowptr1, N1);
  hipMemsetAsync(i_cnt, 0, (size_t)(NBINS + 1) * 4, stream);
  k_fill<<<gE, 256, 0, stream>>>(dst1, src1, w1, i_rowptr1, i_cnt, i_csr1c, f_csr1v, E1C);
  k_rowsum<<<gN8, 256, 0, stream>>>(i_rowptr1, f_csr1v, f_deg, N1);
  k_csrnorm<<<gN8, 256, 0, stream>>>(i_rowptr1, i_csr1c, f_csr1v, f_deg, N1);

  // --- GCN graph1: h0 = x@W + b; 10 hops (fp32 — feeds top-k/argmax decisions) ---
  k_mm128<<<cdiv(N1, 16), 256, 0, stream>>>(x, wt_gcn, b_gcn, f_ha, N1, 0);
  {
    const float* cur = f_ha;
    for (int i = 0; i < KHOPS; ++i) {
      int last = (i == KHOPS - 1);
      float* dst = last ? out_x : ((i & 1) ? f_ha : f_hb);
      k_prop<<<gN8, 256, 0, stream>>>((const float4*)cur, (float4*)dst,
                                      last ? (float4*)f_xr : nullptr,
                                      i_rowptr1, i_csr1c, f_csr1v, N1);
      cur = dst;
    }
  }

  // --- scores + top-k ranks (22-bit bins) ---
  k_score<<<cdiv(N1, 4), 256, 0, stream>>>(f_xr, p_sc, f_s, N1);
  k_key<<<gN, 256, 0, stream>>>(f_s, u_key, N1);
  hipMemsetAsync(i_cnt22, 0, (size_t)NBINS22 * 4, stream);
  k_count_bins22<<<gN, 256, 0, stream>>>(u_key, i_cnt22, N1);
  k_hist_blocksum<<<NBINS22 / 1024, 256, 0, stream>>>(i_cnt22, i_partial);
  k_scan<<<1, 1024, 0, stream>>>(i_partial, i_partptr, 4096);
  k_hist_apply<<<NBINS22 / 1024, 256, 0, stream>>>(i_cnt22, i_partptr, i_binptr22);
  hipMemsetAsync(i_cnt22, 0, (size_t)NBINS22 * 4, stream);
  k_fill_bins22<<<gN, 256, 0, stream>>>(u_key, i_binptr22, i_cnt22, i_bidx, u_bkey, N1);
  k_rank22<<<gN, 256, 0, stream>>>(u_key, i_binptr22, i_bidx, u_bkey, i_supid, N1);

  // --- CSR graph1 by src (attention candidates) ---
  hipMemsetAsync(i_cnt, 0, (size_t)(NBINS + 1) * 4, stream);
  k_count<<<gE, 256, 0, stream>>>(src1, i_cnt, E1C);
  k_scan<<<1, 1024, 0, stream>>>(i_cnt, i_rowptrS, N1);
  hipMemsetAsync(i_cnt, 0, (size_t)(NBINS + 1) * 4, stream);
  k_fill<<<gE, 256, 0, stream>>>(src1, dst1, (const float*)nullptr, i_rowptrS, i_cnt, i_csrSc,
                                 (float*)nullptr, E1C);

  // --- attention passes ---
  k_att_a<<<cdiv(N1, 4), 256, 0, stream>>>(f_xr, i_rowptrS, i_csrSc, i_supid, tmp,
                                           f_att, f_attself, f_m, N1);
  k_att_b<<<gN8, 256, 0, stream>>>(i_rowptrS, i_csrSc, i_supid, f_att, f_attself,
                                   f_m, i_cluster, a_out, N1);

  // --- coarsen: cluster->member CSR + pull pooling (no fp32 atomics) ---
  hipMemsetAsync(i_cnt, 0, (size_t)(NBINS + 1) * 4, stream);
  k_count<<<gN, 256, 0, stream>>>(i_cluster, i_cnt, N1);
  k_scan<<<1, 1024, 0, stream>>>(i_cnt, i_rowptrM, NSUP);
  hipMemsetAsync(i_cnt, 0, (size_t)(NBINS + 1) * 4, stream);
  k_fill_iota<<<gN, 256, 0, stream>>>(i_cluster, i_rowptrM, i_cnt, i_memb, N1);
  k_xpool_pull<<<gC8, 256, 0, stream>>>((const float4*)f_xr, a_out, i_rowptrM,
                                        i_memb, (float4*)f_xpool, NSUP);

  // --- coarse CSR with cw values; degc=rowsum; normalize in place ---
  hipMemsetAsync(i_cnt, 0, (size_t)(NBINS + 1) * 4, stream);
  k_count_coarse<<<gE, 256, 0, stream>>>(dst1, i_cluster, i_cnt, E1C);
  k_scan<<<1, 1024, 0, stream>>>(i_cnt, i_rowptrC, NSUP);
  hipMemsetAsync(i_cnt, 0, (size_t)(NBINS + 1) * 4, stream);
  k_fill_coarse<<<gE, 256, 0, stream>>>(src1, dst1, i_cluster, w1, a_out, i_rowptrC, i_cnt,
                                        i_csrCc, f_csrCv, E1C);
  k_rowsum<<<gC8, 256, 0, stream>>>(i_rowptrC, f_csrCv, f_degc, NSUP);
  k_csrnorm<<<gC8, 256, 0, stream>>>(i_rowptrC, i_csrCc, f_csrCv, f_degc, NSUP);

  // --- coarse conv + MLP1 ---
  k_mm128<<<cdiv(NSUP, 16), 256, 0, stream>>>(f_xpool, wt_c1, b_c1, f_h2, NSUP, 0);
  k_prop<<<gC8, 256, 0, stream>>>((const float4*)f_h2, (float4*)f_h2p, nullptr,
                                  i_rowptrC, i_csrCc, f_csrCv, NSUP);
  k_addrelu<<<cdiv(NSUP * F, 256), 256, 0, stream>>>(f_h2p, f_h2, sup1, NSUP * F);
  k_mm128<<<cdiv(NSUP, 16), 256, 0, stream>>>(sup1, wt_m1, b_m1, sup2, NSUP, 1);

  // --- graph2: CSR + rowsum-norm + GCN in bf16 (decision-free value path) ---
  hipMemsetAsync(i_cnt, 0, (size_t)(NBINS + 1) * 4, stream);
  k_count<<<gE, 256, 0, stream>>>(dsty, i_cnt, E2C);
  k_scan<<<1, 1024, 0, stream>>>(i_cnt, i_rowptr1, N2);
  hipMemsetAsync(i_cnt, 0, (size_t)(NBINS + 1) * 4, stream);
  k_fill<<<gE, 256, 0, stream>>>(dsty, srcy, wy, i_rowptr1, i_cnt, i_csr1c, f_csr1v, E2C);
  k_rowsum<<<gN8, 256, 0, stream>>>(i_rowptr1, f_csr1v, f_deg, N2);
  k_csrnorm<<<gN8, 256, 0, stream>>>(i_rowptr1, i_csr1c, f_csr1v, f_deg, N2);
  k_mm128_bf16<<<cdiv(N2, 16), 256, 0, stream>>>(y, wt_gcn, b_gcn, h16a, N2);
  {
    const unsigned short* cur = h16a;
    for (int i = 0; i < KHOPS; ++i) {
      int last = (i == KHOPS - 1);
      unsigned short* dst = (i & 1) ? h16a : h16b;
      k_prop_bf16<<<gN8, 256, 0, stream>>>(
          (const ushort4*)cur, last ? nullptr : (ushort4*)dst,
          last ? (float4*)out_y : nullptr, i_rowptr1, i_csr1c, f_csr1v, N2);
      cur = dst;
    }
  }

  // --- LastLayer ---
  float* f_t1 = f_h2p;  // reuse
  float* f_t2 = f_xr;   // reuse
  k_mm128<<<cdiv(NSUP, 16), 256, 0, stream>>>(sup2, wt_l1, (const float*)nullptr, f_t1, NSUP, 0);
  k_scatter_q<<<cdiv(AC * F, 256), 256, 0, stream>>>(a1, a2, i_cluster, a_out, f_t1, out_y, AC);
  k_mm128<<<cdiv(N1, 16), 256, 0, stream>>>(out_x, wt_l2, (const float*)nullptr, f_t2, N1, 0);
  k_scatter_t2<<<cdiv(AC * F, 256), 256, 0, stream>>>(a1, a2, f_t2, out_y, AC);

  // --- recon ---
  k_mm128<<<cdiv(N2, 16), 256, 0, stream>>>(out_y, wt_m2, b_m2, recon, N2, 0);
}

// Round 8
// 2356.607 us; speedup vs baseline: 1.5744x; 1.0028x over previous
//
#include <hip/hip_runtime.h>
#include <hip/hip_bf16.h>
#include <math.h>

#define N1 50000
#define N2 50000
#define E1C 800000
#define E2C 800000
#define AC 10000
#define F 128
#define NSUP 25000
#define KHOPS 10
#define NEGINF -1e30f
#define NBINS 65536
#define NBINS22 (1 << 22)

static inline int cdiv(int a, int b) { return (a + b - 1) / b; }

// ---------------- bf16 helpers ----------------
__device__ __forceinline__ float bf2f(unsigned short u) {
  return __uint_as_float(((unsigned)u) << 16);
}
__device__ __forceinline__ unsigned short f2bf(float f) {
  unsigned x = __float_as_uint(f);
  return (unsigned short)((x + 0x7FFFu + ((x >> 16) & 1u)) >> 16);
}

// ---------------- CSR build ----------------
__global__ void k_count(const int* __restrict__ key, int* __restrict__ cnt, int n) {
  int e = blockIdx.x * blockDim.x + threadIdx.x;
  if (e < n) atomicAdd(&cnt[key[e]], 1);
}

// single-block scan: thread-sequential partials + shuffle scan
__global__ void k_scan(const int* __restrict__ cnt, int* __restrict__ rowptr, int n) {
  const int T = 1024;
  int t = threadIdx.x;
  int vpt = (n + T - 1) / T;
  int lo = t * vpt, hi = lo + vpt;
  if (hi > n) hi = n;
  int sum = 0;
  for (int i = lo; i < hi; ++i) sum += cnt[i];
  int lane = t & 63, wid = t >> 6;
  int v = sum;
#pragma unroll
  for (int o = 1; o < 64; o <<= 1) {
    int u = __shfl_up(v, o, 64);
    if (lane >= o) v += u;
  }
  __shared__ int wsum[16];
  if (lane == 63) wsum[wid] = v;
  __syncthreads();
  if (t < 16) {
    int w = wsum[t];
#pragma unroll
    for (int o = 1; o < 16; o <<= 1) {
      int u = __shfl_up(w, o, 64);
      if (t >= o) w += u;
    }
    wsum[t] = w;
  }
  __syncthreads();
  int base = (wid ? wsum[wid - 1] : 0) + (v - sum);
  if (t == 0) rowptr[0] = 0;
  int run = base;
  for (int i = lo; i < hi; ++i) { run += cnt[i]; rowptr[i + 1] = run; }
}

__global__ void k_fill(const int* __restrict__ key, const int* __restrict__ payload,
                       const float* __restrict__ val, const int* __restrict__ rowptr,
                       int* __restrict__ cnt, int* __restrict__ col, float* __restrict__ v,
                       int n) {
  int e = blockIdx.x * blockDim.x + threadIdx.x;
  if (e < n) {
    int k = key[e];
    int p = atomicAdd(&cnt[k], 1);
    int s = rowptr[k] + p;
    col[s] = payload[e];
    if (val) v[s] = val[e];
  }
}

// fill storing the element index itself (for cluster->member lists)
__global__ void k_fill_iota(const int* __restrict__ key, const int* __restrict__ rowptr,
                            int* __restrict__ cnt, int* __restrict__ col, int n) {
  int e = blockIdx.x * blockDim.x + threadIdx.x;
  if (e < n) {
    int k = key[e];
    int p = atomicAdd(&cnt[k], 1);
    col[rowptr[k] + p] = e;
  }
}

__global__ void k_count_coarse(const int* __restrict__ dst, const int* __restrict__ cluster,
                               int* __restrict__ cnt, int n) {
  int e = blockIdx.x * blockDim.x + threadIdx.x;
  if (e < n) atomicAdd(&cnt[cluster[dst[e]]], 1);
}

// coarse fill computing cw = w * a[src] * a[dst] inline
__global__ void k_fill_coarse(const int* __restrict__ src, const int* __restrict__ dst,
                              const int* __restrict__ cluster, const float* __restrict__ w,
                              const float* __restrict__ a, const int* __restrict__ rowptr,
                              int* __restrict__ cnt, int* __restrict__ col,
                              float* __restrict__ v, int n) {
  int e = blockIdx.x * blockDim.x + threadIdx.x;
  if (e < n) {
    int sd = dst[e];
    int k = cluster[sd];
    int p = atomicAdd(&cnt[k], 1);
    int s = rowptr[k] + p;
    int ss = src[e];
    col[s] = cluster[ss];
    v[s] = w[e] * a[ss] * a[sd];
  }
}

// ---------------- degree via CSR rowsum (32-lane slice per row) ----------------
__global__ void k_rowsum(const int* __restrict__ rowptr, const float* __restrict__ v,
                         float* __restrict__ deg, int n) {
  int row = blockIdx.x * 8 + (threadIdx.x >> 5);
  if (row >= n) return;
  int q = threadIdx.x & 31;
  int s0 = rowptr[row], s1 = rowptr[row + 1];
  float s = 0.f;
  for (int k = s0 + q; k < s1; k += 32) s += v[k];
#pragma unroll
  for (int o = 16; o; o >>= 1) s += __shfl_xor(s, o, 64);  // stays within aligned 32-group
  if (q == 0) deg[row] = s;
}

// in-place symmetric normalization of CSR values (32-lane slice per row)
__global__ void k_csrnorm(const int* __restrict__ rowptr, const int* __restrict__ col,
                          float* __restrict__ v, const float* __restrict__ deg, int n) {
  int row = blockIdx.x * 8 + (threadIdx.x >> 5);
  if (row >= n) return;
  int q = threadIdx.x & 31;
  int s0 = rowptr[row], s1 = rowptr[row + 1];
  float di = deg[row] + 1.f;
  for (int s = s0 + q; s < s1; s += 32) {
    float dc = deg[col[s]] + 1.f;
    v[s] = v[s] / sqrtf(dc * di);
  }
}

// ---------------- propagation fp32 (pull, 32 threads/node, shfl edge broadcast) -------
// used standalone for the coarse-graph conv
__global__ void k_prop(const float4* __restrict__ hin, float4* __restrict__ hout,
                       float4* __restrict__ relu_out, const int* __restrict__ rowptr,
                       const int* __restrict__ col, const float* __restrict__ val, int n) {
  int node = blockIdx.x * 8 + (threadIdx.x >> 5);
  if (node >= n) return;
  int q = threadIdx.x & 31;
  int grp = threadIdx.x & 32;  // lane-group base within the 64-wide wave
  int s0 = rowptr[node], s1 = rowptr[node + 1];
  float4 acc = make_float4(0.f, 0.f, 0.f, 0.f);
  for (int s = s0; s < s1; s += 32) {
    int es = s + q;
    int ok = es < s1;
    int sc = ok ? es : (s1 - 1);
    int cme = col[sc];                    // coalesced: 32 consecutive edges
    float vme = ok ? val[sc] : 0.f;
    int nb = s1 - s; if (nb > 32) nb = 32;
    for (int j = 0; j < nb; j += 8) {
      int c8[8]; float v8[8];
#pragma unroll
      for (int t = 0; t < 8; ++t) {
        c8[t] = __shfl(cme, grp + j + t, 64);
        v8[t] = __shfl(vme, grp + j + t, 64);
      }
      float4 h[8];
#pragma unroll
      for (int t = 0; t < 8; ++t) h[t] = hin[(size_t)c8[t] * 32 + q];
#pragma unroll
      for (int t = 0; t < 8; ++t) {
        acc.x = fmaf(v8[t], h[t].x, acc.x);
        acc.y = fmaf(v8[t], h[t].y, acc.y);
        acc.z = fmaf(v8[t], h[t].z, acc.z);
        acc.w = fmaf(v8[t], h[t].w, acc.w);
      }
    }
  }
  hout[(size_t)node * 32 + q] = acc;
  if (relu_out) {
    float4 r;
    r.x = fmaxf(acc.x, 0.f); r.y = fmaxf(acc.y, 0.f);
    r.z = fmaxf(acc.z, 0.f); r.w = fmaxf(acc.w, 0.f);
    relu_out[(size_t)node * 32 + q] = r;
  }
}

// ---------------- FUSED dual propagation: g1 fp32 hop + g2 bf16 hop in one dispatch ---
// The two GCN chains are data-independent until LastLayer; co-scheduling them doubles
// outstanding gather requests chip-wide (both standalone kernels sit at the same
// ~2.2 TB/s effective gather rate with HBM at 27% and VALU at 43% -> latency-bound,
// not chip-BW-bound). Even blocks run the fp32 body on graph-1's CSR; odd blocks run
// the bf16 body on graph-2's CSR. Bodies are verbatim R7 kernels -> numerics identical.
__global__ void k_prop_dual(const float4* __restrict__ hin1, float4* __restrict__ hout1,
                            float4* __restrict__ xr_out,
                            const int* __restrict__ rp1, const int* __restrict__ col1,
                            const float* __restrict__ val1,
                            const ushort4* __restrict__ hin2, ushort4* __restrict__ hout2,
                            float4* __restrict__ fout2,
                            const int* __restrict__ rp2, const int* __restrict__ col2,
                            const float* __restrict__ val2, int n) {
  int node = (blockIdx.x >> 1) * 8 + (threadIdx.x >> 5);
  if (node >= n) return;
  int q = threadIdx.x & 31;
  int grp = threadIdx.x & 32;
  if ((blockIdx.x & 1) == 0) {
    // ---- fp32 path (graph 1) ----
    int s0 = rp1[node], s1 = rp1[node + 1];
    float4 acc = make_float4(0.f, 0.f, 0.f, 0.f);
    for (int s = s0; s < s1; s += 32) {
      int es = s + q;
      int ok = es < s1;
      int sc = ok ? es : (s1 - 1);
      int cme = col1[sc];
      float vme = ok ? val1[sc] : 0.f;
      int nb = s1 - s; if (nb > 32) nb = 32;
      for (int j = 0; j < nb; j += 8) {
        int c8[8]; float v8[8];
#pragma unroll
        for (int t = 0; t < 8; ++t) {
          c8[t] = __shfl(cme, grp + j + t, 64);
          v8[t] = __shfl(vme, grp + j + t, 64);
        }
        float4 h[8];
#pragma unroll
        for (int t = 0; t < 8; ++t) h[t] = hin1[(size_t)c8[t] * 32 + q];
#pragma unroll
        for (int t = 0; t < 8; ++t) {
          acc.x = fmaf(v8[t], h[t].x, acc.x);
          acc.y = fmaf(v8[t], h[t].y, acc.y);
          acc.z = fmaf(v8[t], h[t].z, acc.z);
          acc.w = fmaf(v8[t], h[t].w, acc.w);
        }
      }
    }
    hout1[(size_t)node * 32 + q] = acc;
    if (xr_out) {
      float4 r;
      r.x = fmaxf(acc.x, 0.f); r.y = fmaxf(acc.y, 0.f);
      r.z = fmaxf(acc.z, 0.f); r.w = fmaxf(acc.w, 0.f);
      xr_out[(size_t)node * 32 + q] = r;
    }
  } else {
    // ---- bf16 path (graph 2) ----
    int s0 = rp2[node], s1 = rp2[node + 1];
    float4 acc = make_float4(0.f, 0.f, 0.f, 0.f);
    for (int s = s0; s < s1; s += 32) {
      int es = s + q;
      int ok = es < s1;
      int sc = ok ? es : (s1 - 1);
      int cme = col2[sc];
      float vme = ok ? val2[sc] : 0.f;
      int nb = s1 - s; if (nb > 32) nb = 32;
      for (int j = 0; j < nb; j += 8) {
        int c8[8]; float v8[8];
#pragma unroll
        for (int t = 0; t < 8; ++t) {
          c8[t] = __shfl(cme, grp + j + t, 64);
          v8[t] = __shfl(vme, grp + j + t, 64);
        }
        ushort4 h[8];
#pragma unroll
        for (int t = 0; t < 8; ++t) h[t] = hin2[(size_t)c8[t] * 32 + q];
#pragma unroll
        for (int t = 0; t < 8; ++t) {
          acc.x = fmaf(v8[t], bf2f(h[t].x), acc.x);
          acc.y = fmaf(v8[t], bf2f(h[t].y), acc.y);
          acc.z = fmaf(v8[t], bf2f(h[t].z), acc.z);
          acc.w = fmaf(v8[t], bf2f(h[t].w), acc.w);
        }
      }
    }
    if (fout2) {
      fout2[(size_t)node * 32 + q] = acc;
    } else {
      ushort4 o;
      o.x = f2bf(acc.x); o.y = f2bf(acc.y); o.z = f2bf(acc.z); o.w = f2bf(acc.w);
      hout2[(size_t)node * 32 + q] = o;
    }
  }
}

// ---------------- dense matmul out = relu?(X @ W + b), W given transposed ----------------
__global__ void k_transpose(const float* __restrict__ W, float* __restrict__ WT) {
  int i = blockIdx.x * blockDim.x + threadIdx.x;
  if (i < F * F) { int k = i >> 7, c = i & 127; WT[c * F + k] = W[i]; }
}

__global__ void k_mm128(const float* __restrict__ X, const float* __restrict__ WT,
                        const float* __restrict__ bias, float* __restrict__ out,
                        int M, int relu) {
  __shared__ float4 xs[16][32];
  int tid = threadIdx.x;
  int c = tid & 127;
  int half = tid >> 7;
  int row0 = blockIdx.x * 16;
  for (int t = tid; t < 512; t += 256) {
    int r = t >> 5, k4 = t & 31;
    int gr = row0 + r;
    float4 v = make_float4(0.f, 0.f, 0.f, 0.f);
    if (gr < M) v = ((const float4*)X)[(size_t)gr * 32 + k4];
    xs[r][k4] = v;
  }
  __syncthreads();
  float acc[8];
#pragma unroll
  for (int r = 0; r < 8; ++r) acc[r] = 0.f;
  const float4* wrow = (const float4*)WT + (size_t)c * 32;
  for (int k4 = 0; k4 < 32; ++k4) {
    float4 w = wrow[k4];
#pragma unroll
    for (int r = 0; r < 8; ++r) {
      float4 xv = xs[half * 8 + r][k4];
      acc[r] = fmaf(xv.x, w.x, acc[r]);
      acc[r] = fmaf(xv.y, w.y, acc[r]);
      acc[r] = fmaf(xv.z, w.z, acc[r]);
      acc[r] = fmaf(xv.w, w.w, acc[r]);
    }
  }
  float bb = bias ? bias[c] : 0.f;
#pragma unroll
  for (int r = 0; r < 8; ++r) {
    int gr = row0 + half * 8 + r;
    if (gr < M) {
      float v = acc[r] + bb;
      if (relu) v = fmaxf(v, 0.f);
      out[(size_t)gr * F + c] = v;
    }
  }
}

// same as k_mm128 but bf16 output
__global__ void k_mm128_bf16(const float* __restrict__ X, const float* __restrict__ WT,
                             const float* __restrict__ bias, unsigned short* __restrict__ out,
                             int M) {
  __shared__ float4 xs[16][32];
  int tid = threadIdx.x;
  int c = tid & 127;
  int half = tid >> 7;
  int row0 = blockIdx.x * 16;
  for (int t = tid; t < 512; t += 256) {
    int r = t >> 5, k4 = t & 31;
    int gr = row0 + r;
    float4 v = make_float4(0.f, 0.f, 0.f, 0.f);
    if (gr < M) v = ((const float4*)X)[(size_t)gr * 32 + k4];
    xs[r][k4] = v;
  }
  __syncthreads();
  float acc[8];
#pragma unroll
  for (int r = 0; r < 8; ++r) acc[r] = 0.f;
  const float4* wrow = (const float4*)WT + (size_t)c * 32;
  for (int k4 = 0; k4 < 32; ++k4) {
    float4 w = wrow[k4];
#pragma unroll
    for (int r = 0; r < 8; ++r) {
      float4 xv = xs[half * 8 + r][k4];
      acc[r] = fmaf(xv.x, w.x, acc[r]);
      acc[r] = fmaf(xv.y, w.y, acc[r]);
      acc[r] = fmaf(xv.z, w.z, acc[r]);
      acc[r] = fmaf(xv.w, w.w, acc[r]);
    }
  }
  float bb = bias ? bias[c] : 0.f;
#pragma unroll
  for (int r = 0; r < 8; ++r) {
    int gr = row0 + half * 8 + r;
    if (gr < M) out[(size_t)gr * F + c] = f2bf(acc[r] + bb);
  }
}

// ---------------- elementwise ----------------
__global__ void k_addrelu(const float* __restrict__ a, const float* __restrict__ b,
                          float* __restrict__ out, int n) {
  int i = blockIdx.x * blockDim.x + threadIdx.x;
  if (i < n) out[i] = fmaxf(a[i] + b[i], 0.f);
}

// ---------------- scores + ranking (top-k via 22-bit bin bucketing) ----------------
__global__ void k_score(const float* __restrict__ xr, const float* __restrict__ p,
                        float* __restrict__ s, int n) {
  int wid = (blockIdx.x * blockDim.x + threadIdx.x) >> 6;
  int lane = threadIdx.x & 63;
  if (wid >= n) return;
  const float* row = xr + (size_t)wid * F;
  float d = row[lane] * p[lane] + row[lane + 64] * p[lane + 64];
#pragma unroll
  for (int o = 32; o; o >>= 1) d += __shfl_xor(d, o, 64);
  if (lane == 0) s[wid] = d;
}

__device__ __forceinline__ unsigned sortkey(float f) {
  if (f == 0.f) f = 0.f;  // canonicalize -0 -> +0
  unsigned u = __float_as_uint(f);
  return (u & 0x80000000u) ? ~u : (u | 0x80000000u);
}

__global__ void k_key(const float* __restrict__ s, unsigned* __restrict__ key, int n) {
  int i = blockIdx.x * blockDim.x + threadIdx.x;
  if (i < n) key[i] = sortkey(s[i]);
}

__global__ void k_count_bins22(const unsigned* __restrict__ key, int* __restrict__ cnt, int n) {
  int i = blockIdx.x * blockDim.x + threadIdx.x;
  if (i < n) atomicAdd(&cnt[key[i] >> 10], 1);
}

// block sums over 1024-bin chunks (grid = NBINS22/1024 = 4096 blocks, 256 thr)
__global__ void k_hist_blocksum(const int* __restrict__ cnt, int* __restrict__ partial) {
  int t = threadIdx.x;
  int base = blockIdx.x * 1024 + t * 4;
  int s = cnt[base] + cnt[base + 1] + cnt[base + 2] + cnt[base + 3];
#pragma unroll
  for (int o = 32; o; o >>= 1) s += __shfl_down(s, o, 64);
  __shared__ int ws[4];
  int lane = t & 63, w = t >> 6;
  if (lane == 0) ws[w] = s;
  __syncthreads();
  if (t == 0) partial[blockIdx.x] = ws[0] + ws[1] + ws[2] + ws[3];
}

// apply scanned partials: binptr[b+1] = global inclusive prefix
__global__ void k_hist_apply(const int* __restrict__ cnt, const int* __restrict__ partialptr,
                             int* __restrict__ binptr) {
  int t = threadIdx.x;
  int base = blockIdx.x * 1024 + t * 4;
  int c0 = cnt[base], c1 = cnt[base + 1], c2 = cnt[base + 2], c3 = cnt[base + 3];
  int s = c0 + c1 + c2 + c3;
  int lane = t & 63, w = t >> 6;
  int v = s;
#pragma unroll
  for (int o = 1; o < 64; o <<= 1) {
    int u = __shfl_up(v, o, 64);
    if (lane >= o) v += u;
  }
  __shared__ int ws[4];
  if (lane == 63) ws[w] = v;
  __syncthreads();
  int wb = 0;
  for (int i = 0; i < w; ++i) wb += ws[i];
  int run = partialptr[blockIdx.x] + wb + (v - s);
  binptr[base + 1] = run + c0;
  binptr[base + 2] = run + c0 + c1;
  binptr[base + 3] = run + c0 + c1 + c2;
  binptr[base + 4] = run + s;
  if (blockIdx.x == 0 && t == 0) binptr[0] = 0;
}

__global__ void k_fill_bins22(const unsigned* __restrict__ key, const int* __restrict__ binptr,
                              int* __restrict__ cnt, int* __restrict__ bidx,
                              unsigned* __restrict__ bkey, int n) {
  int i = blockIdx.x * blockDim.x + threadIdx.x;
  if (i < n) {
    unsigned k = key[i];
    int b = k >> 10;
    int p = atomicAdd(&cnt[b], 1);
    int s = binptr[b] + p;
    bidx[s] = i;
    bkey[s] = k;
  }
}

// rank_i = #{j: s_j > s_i} + #{j: s_j == s_i && j < i}; supid = rank < NSUP ? rank : -1
__global__ void k_rank22(const unsigned* __restrict__ key, const int* __restrict__ binptr,
                         const int* __restrict__ bidx, const unsigned* __restrict__ bkey,
                         int* __restrict__ supid, int n) {
  int i = blockIdx.x * blockDim.x + threadIdx.x;
  if (i >= n) return;
  unsigned ki = key[i];
  int b = ki >> 10;
  int cnt = n - binptr[b + 1];  // all keys in strictly-higher bins
  int s1 = binptr[b + 1];
  for (int s = binptr[b]; s < s1; ++s) {
    unsigned kj = bkey[s];
    cnt += (kj > ki) || (kj == ki && bidx[s] < i);
  }
  supid[i] = (cnt < NSUP) ? cnt : -1;
}

// ---------------- attention / assignment ----------------
__device__ __forceinline__ float read_T(const void* p) {
  int ib = *(const int*)p;
  float fb = __int_as_float(ib);
  if (ib >= 1 && ib < (1 << 20)) return (float)ib;   // int-encoded scalar
  if (fb > 1e-6f && fb < 1e6f) return fb;            // float-encoded scalar
  return 1.0f;
}

// wave per node; 4-edge groups for gather MLP
__global__ void k_att_a(const float* __restrict__ xr, const int* __restrict__ rowptr,
                        const int* __restrict__ col, const int* __restrict__ supid,
                        const void* __restrict__ tptr, float* __restrict__ att,
                        float* __restrict__ attself, float* __restrict__ mout, int n) {
  int wid = (blockIdx.x * blockDim.x + threadIdx.x) >> 6;
  int lane = threadIdx.x & 63;
  if (wid >= n) return;
  float inv = 1.0f / (sqrtf(128.0f) * read_T(tptr));
  const float* xn = xr + (size_t)wid * F;
  float x0 = xn[lane], x1 = xn[lane + 64];
  // self candidate
  float d = x0 * x0 + x1 * x1;
#pragma unroll
  for (int o = 32; o; o >>= 1) d += __shfl_xor(d, o, 64);
  float av = (supid[wid] >= 0) ? d * inv : NEGINF;
  float m = av;
  if (lane == 0) attself[wid] = av;
  int s0 = rowptr[wid], s1 = rowptr[wid + 1];
  for (int s = s0; s < s1; s += 4) {
    int c[4]; bool ok[4];
#pragma unroll
    for (int j = 0; j < 4; ++j) {
      int ss = s + j;
      ok[j] = ss < s1;
      c[j] = col[ok[j] ? ss : (s1 - 1)];
    }
    float dd[4];
#pragma unroll
    for (int j = 0; j < 4; ++j) {
      const float* xc = xr + (size_t)c[j] * F;
      dd[j] = x0 * xc[lane] + x1 * xc[lane + 64];
    }
#pragma unroll
    for (int j = 0; j < 4; ++j) {
#pragma unroll
      for (int o = 32; o; o >>= 1) dd[j] += __shfl_xor(dd[j], o, 64);
    }
#pragma unroll
    for (int j = 0; j < 4; ++j) {
      if (ok[j]) {
        float a2 = (supid[c[j]] >= 0) ? dd[j] * inv : NEGINF;
        if (lane == 0) att[s + j] = a2;
        m = fmaxf(m, a2);
      }
    }
  }
  if (lane == 0) mout[wid] = m;
}

// 32-lane slice per node: esum = sum exp(att-m), best = max supid among argmax cands
__global__ void k_att_b(const int* __restrict__ rowptr, const int* __restrict__ col,
                        const int* __restrict__ supid, const float* __restrict__ att,
                        const float* __restrict__ attself, const float* __restrict__ mv,
                        int* __restrict__ cluster, float* __restrict__ aout, int n) {
  int i = blockIdx.x * 8 + (threadIdx.x >> 5);
  if (i >= n) return;
  int q = threadIdx.x & 31;
  float m = mv[i];
  float as = attself[i];
  float esum = 0.f;
  int best = -1;
  if (q == 0) {
    esum = expf(as - m);
    if (as >= m) best = supid[i];
  }
  int s0 = rowptr[i], s1 = rowptr[i + 1];
  for (int s = s0 + q; s < s1; s += 32) {
    float av = att[s];
    esum += expf(av - m);
    if (av >= m) {
      int sid = supid[col[s]];
      if (sid > best) best = sid;
    }
  }
#pragma unroll
  for (int o = 16; o; o >>= 1) {
    esum += __shfl_xor(esum, o, 64);
    int ob = __shfl_xor(best, o, 64);
    if (ob > best) best = ob;
  }
  if (q == 0) {
    int has = best >= 0;
    cluster[i] = has ? best : 0;
    aout[i] = has ? 1.0f / esum : 0.0f;
  }
}

// ---------------- pooling (pull over cluster->member CSR) ----------------
__global__ void k_xpool_pull(const float4* __restrict__ xr, const float* __restrict__ a,
                             const int* __restrict__ rowptrM, const int* __restrict__ memb,
                             float4* __restrict__ xpool, int n) {
  int c = blockIdx.x * 8 + (threadIdx.x >> 5);
  if (c >= n) return;
  int q = threadIdx.x & 31;
  int s0 = rowptrM[c], s1 = rowptrM[c + 1];
  float4 acc = make_float4(0.f, 0.f, 0.f, 0.f);
  for (int s = s0; s < s1; ++s) {
    int m = memb[s];
    float av = a[m];
    float4 h = xr[(size_t)m * 32 + q];
    acc.x = fmaf(av, h.x, acc.x);
    acc.y = fmaf(av, h.y, acc.y);
    acc.z = fmaf(av, h.z, acc.z);
    acc.w = fmaf(av, h.w, acc.w);
  }
  xpool[(size_t)c * 32 + q] = acc;
}

// ---------------- anchor scatters ----------------
__global__ void k_scatter_q(const int* __restrict__ a1, const int* __restrict__ a2,
                            const int* __restrict__ cluster, const float* __restrict__ aarr,
                            const float* __restrict__ t1, float* __restrict__ outy, int nA) {
  int idx = blockIdx.x * blockDim.x + threadIdx.x;
  if (idx >= nA * F) return;
  int k = idx >> 7, f = idx & 127;
  int n1 = a1[k];
  float qw = aarr[n1];
  if (qw != 0.f)
    atomicAdd(&outy[(size_t)a2[k] * F + f], qw * t1[(size_t)cluster[n1] * F + f]);
}

__global__ void k_scatter_t2(const int* __restrict__ a1, const int* __restrict__ a2,
                             const float* __restrict__ t2, float* __restrict__ outy, int nA) {
  int idx = blockIdx.x * blockDim.x + threadIdx.x;
  if (idx >= nA * F) return;
  int k = idx >> 7, f = idx & 127;
  atomicAdd(&outy[(size_t)a2[k] * F + f], t2[(size_t)a1[k] * F + f]);
}

// ================= host =================
extern "C" void kernel_launch(void* const* d_in, const int* in_sizes, int n_in,
                              void* d_out, int out_size, void* d_ws, size_t ws_size,
                              hipStream_t stream) {
  (void)in_sizes; (void)n_in; (void)out_size; (void)ws_size;
  const float* x   = (const float*)d_in[0];
  const int*   ei  = (const int*)d_in[1];     // src = ei, dst = ei+E1C
  const float* w1  = (const float*)d_in[2];
  const float* y   = (const float*)d_in[3];
  const int*   eiy = (const int*)d_in[4];
  const float* wy  = (const float*)d_in[5];
  const int*   anc = (const int*)d_in[6];     // a1 = anc, a2 = anc+AC
  const void*  tmp = d_in[7];
  const float* W_gcn = (const float*)d_in[8];
  const float* b_gcn = (const float*)d_in[9];
  const float* p_sc  = (const float*)d_in[10];
  const float* W_c1  = (const float*)d_in[11];
  const float* b_c1  = (const float*)d_in[12];
  const float* W_m1  = (const float*)d_in[13];
  const float* b_m1  = (const float*)d_in[14];
  const float* W_l1  = (const float*)d_in[15];
  const float* W_l2  = (const float*)d_in[16];
  const float* W_m2  = (const float*)d_in[17];
  const float* b_m2  = (const float*)d_in[18];

  float* out   = (float*)d_out;
  float* out_x = out;
  float* sup1  = out_x + (size_t)N1 * F;
  float* out_y = sup1 + (size_t)NSUP * F;
  float* sup2  = out_y + (size_t)N2 * F;
  float* a_out = sup2 + (size_t)NSUP * F;
  float* recon = a_out + N1;

  char* wsb = (char*)d_ws;
  size_t off = 0;
  auto alloc = [&](size_t bytes) -> void* {
    void* p = wsb + off;
    off = (off + bytes + 255) & ~(size_t)255;
    return p;
  };
  float*    f_csr1v   = (float*)alloc((size_t)E1C * 4);
  int*      i_csr1c   = (int*)alloc((size_t)E1C * 4);
  int*      i_rowptr1 = (int*)alloc((size_t)(N1 + 1) * 4);
  int*      i_rowptr2 = (int*)alloc((size_t)(N2 + 1) * 4);      // graph-2 CSR rowptr (new)
  float*    f_deg     = (float*)alloc((size_t)N1 * 4);           // reused for graph2
  int*      i_cnt     = (int*)alloc((size_t)(NBINS + 1) * 4);
  float*    f_ha      = (float*)alloc((size_t)N1 * F * 4);       // g1 h ping / cnt22 overlay
  float*    f_hb      = (float*)alloc((size_t)N1 * F * 4);       // g1 h pong / binptr22 overlay
  float*    f_xr      = (float*)alloc((size_t)N1 * F * 4);       // reused for t2
  float*    f_s       = (float*)alloc((size_t)N1 * 4);
  unsigned* u_key     = (unsigned*)alloc((size_t)N1 * 4);
  int*      i_partial = (int*)alloc((size_t)4096 * 4);
  int*      i_partptr = (int*)alloc((size_t)4097 * 4);
  int*      i_bidx    = (int*)alloc((size_t)N1 * 4);
  unsigned* u_bkey    = (unsigned*)alloc((size_t)N1 * 4);
  int*      i_supid   = (int*)alloc((size_t)N1 * 4);
  int*      i_rowptrS = (int*)alloc((size_t)(N1 + 1) * 4);
  int*      i_csrSc   = (int*)alloc((size_t)E1C * 4);
  float*    f_att     = (float*)alloc((size_t)E1C * 4);
  float*    f_attself = (float*)alloc((size_t)N1 * 4);
  float*    f_m       = (float*)alloc((size_t)N1 * 4);
  int*      i_cluster = (int*)alloc((size_t)N1 * 4);
  float*    f_xpool   = (float*)alloc((size_t)NSUP * F * 4);
  float*    f_degc    = (float*)alloc((size_t)NSUP * 4);
  int*      i_rowptrC = (int*)alloc((size_t)(NSUP + 1) * 4);
  int*      i_csrCc   = (int*)alloc((size_t)E1C * 4);
  float*    f_csrCv   = (float*)alloc((size_t)E1C * 4);
  int*      i_rowptrM = (int*)alloc((size_t)(NSUP + 1) * 4);
  int*      i_memb    = (int*)alloc((size_t)N1 * 4);
  float*    f_h2      = (float*)alloc((size_t)NSUP * F * 4);
  float*    f_h2p     = (float*)alloc((size_t)NSUP * F * 4);     // reused for t1
  float*    f_wt      = (float*)alloc((size_t)6 * F * F * 4);

  // overlays (non-overlapping lifetimes):
  //   rank bins live AFTER the fused props      -> on f_ha/f_hb (g1 ping-pong, dead)
  //   g2 CSR col/val live BEFORE coarse CSR     -> on i_csrCc/f_csrCv
  //   g2 bf16 h ping-pong live BEFORE coarsen   -> on f_xpool/f_h2 (12.8 MB each, exact)
  int* i_cnt22    = (int*)f_ha;
  int* i_binptr22 = (int*)f_hb;
  int*   i_csr2c  = i_csrCc;
  float* f_csr2v  = f_csrCv;
  unsigned short* h16a = (unsigned short*)f_xpool;   // N2*F*2 = 12.8 MB = NSUP*F*4
  unsigned short* h16b = (unsigned short*)f_h2;

  const int* src1 = ei,  * dst1 = ei + E1C;
  const int* srcy = eiy, * dsty = eiy + E2C;
  const int* a1 = anc, * a2 = anc + AC;

  // --- transpose all weights ---
  const float* Ws[6] = { W_gcn, W_c1, W_m1, W_l1, W_l2, W_m2 };
  for (int i = 0; i < 6; ++i)
    k_transpose<<<cdiv(F * F, 256), 256, 0, stream>>>(Ws[i], f_wt + (size_t)i * F * F);
  float* wt_gcn = f_wt, *wt_c1 = f_wt + 16384, *wt_m1 = f_wt + 2 * 16384,
       * wt_l1 = f_wt + 3 * 16384, *wt_l2 = f_wt + 4 * 16384, *wt_m2 = f_wt + 5 * 16384;

  int gE = cdiv(E1C, 256);
  int gN = cdiv(N1, 256);
  int gN8 = cdiv(N1, 8);      // 32-lane-slice-per-row launches
  int gC8 = cdiv(NSUP, 8);
  int gD = 2 * cdiv(N1, 8);   // fused dual-prop grid (even=g1 fp32, odd=g2 bf16)

  // --- CSR graph1 by dst, with raw w; then deg=rowsum, normalize in place ---
  hipMemsetAsync(i_cnt, 0, (size_t)(NBINS + 1) * 4, stream);
  k_count<<<gE, 256, 0, stream>>>(dst1, i_cnt, E1C);
  k_scan<<<1, 1024, 0, stream>>>(i_cnt, i_rowptr1, N1);
  hipMemsetAsync(i_cnt, 0, (size_t)(NBINS + 1) * 4, stream);
  k_fill<<<gE, 256, 0, stream>>>(dst1, src1, w1, i_rowptr1, i_cnt, i_csr1c, f_csr1v, E1C);
  k_rowsum<<<gN8, 256, 0, stream>>>(i_rowptr1, f_csr1v, f_deg, N1);
  k_csrnorm<<<gN8, 256, 0, stream>>>(i_rowptr1, i_csr1c, f_csr1v, f_deg, N1);

  // --- CSR graph2 (moved early; independent of graph-1 results) ---
  hipMemsetAsync(i_cnt, 0, (size_t)(NBINS + 1) * 4, stream);
  k_count<<<gE, 256, 0, stream>>>(dsty, i_cnt, E2C);
  k_scan<<<1, 1024, 0, stream>>>(i_cnt, i_rowptr2, N2);
  hipMemsetAsync(i_cnt, 0, (size_t)(NBINS + 1) * 4, stream);
  k_fill<<<gE, 256, 0, stream>>>(dsty, srcy, wy, i_rowptr2, i_cnt, i_csr2c, f_csr2v, E2C);
  k_rowsum<<<gN8, 256, 0, stream>>>(i_rowptr2, f_csr2v, f_deg, N2);
  k_csrnorm<<<gN8, 256, 0, stream>>>(i_rowptr2, i_csr2c, f_csr2v, f_deg, N2);

  // --- h0 for both graphs ---
  k_mm128<<<cdiv(N1, 16), 256, 0, stream>>>(x, wt_gcn, b_gcn, f_ha, N1, 0);
  k_mm128_bf16<<<cdiv(N2, 16), 256, 0, stream>>>(y, wt_gcn, b_gcn, h16a, N2);

  // --- FUSED 10 hops: g1 fp32 + g2 bf16 co-scheduled per dispatch ---
  {
    const float* cur1 = f_ha;
    const unsigned short* cur2 = h16a;
    for (int i = 0; i < KHOPS; ++i) {
      int last = (i == KHOPS - 1);
      float* dst1b = last ? out_x : ((i & 1) ? f_ha : f_hb);
      unsigned short* dst2b = (i & 1) ? h16a : h16b;
      k_prop_dual<<<gD, 256, 0, stream>>>(
          (const float4*)cur1, (float4*)dst1b, last ? (float4*)f_xr : nullptr,
          i_rowptr1, i_csr1c, f_csr1v,
          (const ushort4*)cur2, (ushort4*)dst2b, last ? (float4*)out_y : nullptr,
          i_rowptr2, i_csr2c, f_csr2v, N1);
      cur1 = dst1b; cur2 = dst2b;
    }
  }

  // --- scores + top-k ranks (22-bit bins; overlays on f_ha/f_hb, now free) ---
  k_score<<<cdiv(N1, 4), 256, 0, stream>>>(f_xr, p_sc, f_s, N1);
  k_key<<<gN, 256, 0, stream>>>(f_s, u_key, N1);
  hipMemsetAsync(i_cnt22, 0, (size_t)NBINS22 * 4, stream);
  k_count_bins22<<<gN, 256, 0, stream>>>(u_key, i_cnt22, N1);
  k_hist_blocksum<<<NBINS22 / 1024, 256, 0, stream>>>(i_cnt22, i_partial);
  k_scan<<<1, 1024, 0, stream>>>(i_partial, i_partptr, 4096);
  k_hist_apply<<<NBINS22 / 1024, 256, 0, stream>>>(i_cnt22, i_partptr, i_binptr22);
  hipMemsetAsync(i_cnt22, 0, (size_t)NBINS22 * 4, stream);
  k_fill_bins22<<<gN, 256, 0, stream>>>(u_key, i_binptr22, i_cnt22, i_bidx, u_bkey, N1);
  k_rank22<<<gN, 256, 0, stream>>>(u_key, i_binptr22, i_bidx, u_bkey, i_supid, N1);

  // --- CSR graph1 by src (attention candidates) ---
  hipMemsetAsync(i_cnt, 0, (size_t)(NBINS + 1) * 4, stream);
  k_count<<<gE, 256, 0, stream>>>(src1, i_cnt, E1C);
  k_scan<<<1, 1024, 0, stream>>>(i_cnt, i_rowptrS, N1);
  hipMemsetAsync(i_cnt, 0, (size_t)(NBINS + 1) * 4, stream);
  k_fill<<<gE, 256, 0, stream>>>(src1, dst1, (const float*)nullptr, i_rowptrS, i_cnt, i_csrSc,
                                 (float*)nullptr, E1C);

  // --- attention passes ---
  k_att_a<<<cdiv(N1, 4), 256, 0, stream>>>(f_xr, i_rowptrS, i_csrSc, i_supid, tmp,
                                           f_att, f_attself, f_m, N1);
  k_att_b<<<gN8, 256, 0, stream>>>(i_rowptrS, i_csrSc, i_supid, f_att, f_attself,
                                   f_m, i_cluster, a_out, N1);

  // --- coarsen: cluster->member CSR + pull pooling (no fp32 atomics) ---
  // (f_xpool/f_h2 become live from here on; their h16 overlays are dead)
  hipMemsetAsync(i_cnt, 0, (size_t)(NBINS + 1) * 4, stream);
  k_count<<<gN, 256, 0, stream>>>(i_cluster, i_cnt, N1);
  k_scan<<<1, 1024, 0, stream>>>(i_cnt, i_rowptrM, NSUP);
  hipMemsetAsync(i_cnt, 0, (size_t)(NBINS + 1) * 4, stream);
  k_fill_iota<<<gN, 256, 0, stream>>>(i_cluster, i_rowptrM, i_cnt, i_memb, N1);
  k_xpool_pull<<<gC8, 256, 0, stream>>>((const float4*)f_xr, a_out, i_rowptrM,
                                        i_memb, (float4*)f_xpool, NSUP);

  // --- coarse CSR with cw values; degc=rowsum; normalize in place ---
  // (i_csrCc/f_csrCv become live from here; g2 CSR overlay is dead)
  hipMemsetAsync(i_cnt, 0, (size_t)(NBINS + 1) * 4, stream);
  k_count_coarse<<<gE, 256, 0, stream>>>(dst1, i_cluster, i_cnt, E1C);
  k_scan<<<1, 1024, 0, stream>>>(i_cnt, i_rowptrC, NSUP);
  hipMemsetAsync(i_cnt, 0, (size_t)(NBINS + 1) * 4, stream);
  k_fill_coarse<<<gE, 256, 0, stream>>>(src1, dst1, i_cluster, w1, a_out, i_rowptrC, i_cnt,
                                        i_csrCc, f_csrCv, E1C);
  k_rowsum<<<gC8, 256, 0, stream>>>(i_rowptrC, f_csrCv, f_degc, NSUP);
  k_csrnorm<<<gC8, 256, 0, stream>>>(i_rowptrC, i_csrCc, f_csrCv, f_degc, NSUP);

  // --- coarse conv + MLP1 ---
  k_mm128<<<cdiv(NSUP, 16), 256, 0, stream>>>(f_xpool, wt_c1, b_c1, f_h2, NSUP, 0);
  k_prop<<<gC8, 256, 0, stream>>>((const float4*)f_h2, (float4*)f_h2p, nullptr,
                                  i_rowptrC, i_csrCc, f_csrCv, NSUP);
  k_addrelu<<<cdiv(NSUP * F, 256), 256, 0, stream>>>(f_h2p, f_h2, sup1, NSUP * F);
  k_mm128<<<cdiv(NSUP, 16), 256, 0, stream>>>(sup1, wt_m1, b_m1, sup2, NSUP, 1);

  // --- LastLayer ---
  float* f_t1 = f_h2p;  // reuse
  float* f_t2 = f_xr;   // reuse
  k_mm128<<<cdiv(NSUP, 16), 256, 0, stream>>>(sup2, wt_l1, (const float*)nullptr, f_t1, NSUP, 0);
  k_scatter_q<<<cdiv(AC * F, 256), 256, 0, stream>>>(a1, a2, i_cluster, a_out, f_t1, out_y, AC);
  k_mm128<<<cdiv(N1, 16), 256, 0, stream>>>(out_x, wt_l2, (const float*)nullptr, f_t2, N1, 0);
  k_scatter_t2<<<cdiv(AC * F, 256), 256, 0, stream>>>(a1, a2, f_t2, out_y, AC);

  // --- recon ---
  k_mm128<<<cdiv(N2, 16), 256, 0, stream>>>(out_y, wt_m2, b_m2, recon, N2, 0);
}

// Round 9
// 2121.704 us; speedup vs baseline: 1.7487x; 1.1107x over previous
//
#include <hip/hip_runtime.h>
#include <hip/hip_bf16.h>
#include <math.h>

#define N1 50000
#define N2 50000
#define E1C 800000
#define E2C 800000
#define AC 10000
#define F 128
#define NSUP 25000
#define KHOPS 10
#define NEGINF -1e30f
#define NB 65536
#define NBINS22 (1 << 22)

static inline int cdiv(int a, int b) { return (a + b - 1) / b; }

// ---------------- bf16 helpers ----------------
__device__ __forceinline__ float bf2f(unsigned short u) {
  return __uint_as_float(((unsigned)u) << 16);
}
__device__ __forceinline__ unsigned short f2bf(float f) {
  unsigned x = __float_as_uint(f);
  return (unsigned short)((x + 0x7FFFu + ((x >> 16) & 1u)) >> 16);
}

// ---------------- CSR build ----------------
__global__ void k_count(const int* __restrict__ key, int* __restrict__ cnt, int n) {
  int e = blockIdx.x * blockDim.x + threadIdx.x;
  if (e < n) atomicAdd(&cnt[key[e]], 1);
}

// fused triple count: g0=dst1, g1=dsty, g2=src1 into 3 cnt regions
__global__ void k_count3(const int* __restrict__ d1, const int* __restrict__ dy,
                         const int* __restrict__ s1, int* __restrict__ cnt3) {
  int e = blockIdx.x * blockDim.x + threadIdx.x;
  if (e >= 3 * E1C) return;
  int g = e / E1C, i = e - g * E1C;
  int key = (g == 0) ? d1[i] : (g == 1) ? dy[i] : s1[i];
  atomicAdd(&cnt3[g * NB + key], 1);
}

// single-block scan body (thread-sequential partials + shuffle scan)
__device__ __forceinline__ void scan_body(const int* cnt, int* rowptr, int n) {
  const int T = 1024;
  int t = threadIdx.x;
  int vpt = (n + T - 1) / T;
  int lo = t * vpt, hi = lo + vpt;
  if (hi > n) hi = n;
  int sum = 0;
  for (int i = lo; i < hi; ++i) sum += cnt[i];
  int lane = t & 63, wid = t >> 6;
  int v = sum;
#pragma unroll
  for (int o = 1; o < 64; o <<= 1) {
    int u = __shfl_up(v, o, 64);
    if (lane >= o) v += u;
  }
  __shared__ int wsum[16];
  if (lane == 63) wsum[wid] = v;
  __syncthreads();
  if (t < 16) {
    int w = wsum[t];
#pragma unroll
    for (int o = 1; o < 16; o <<= 1) {
      int u = __shfl_up(w, o, 64);
      if (t >= o) w += u;
    }
    wsum[t] = w;
  }
  __syncthreads();
  int base = (wid ? wsum[wid - 1] : 0) + (v - sum);
  if (t == 0) rowptr[0] = 0;
  int run = base;
  for (int i = lo; i < hi; ++i) { run += cnt[i]; rowptr[i + 1] = run; }
}

__global__ void k_scan(const int* __restrict__ cnt, int* __restrict__ rowptr, int n) {
  scan_body(cnt, rowptr, n);
}

// fused triple scan: block b scans cnt3 region b into its rowptr
__global__ void k_scan3(const int* __restrict__ cnt3, int* __restrict__ rp0,
                        int* __restrict__ rp1, int* __restrict__ rp2,
                        int n0, int n1, int n2) {
  int b = blockIdx.x;
  const int* cnt = cnt3 + b * NB;
  int* rowptr = (b == 0) ? rp0 : (b == 1) ? rp1 : rp2;
  int n = (b == 0) ? n0 : (b == 1) ? n1 : n2;
  scan_body(cnt, rowptr, n);
}

// fused triple fill; atomicSub restores cnt3 to zero (no re-memset needed)
__global__ void k_fill3(const int* __restrict__ d1, const int* __restrict__ s1,
                        const float* __restrict__ w1,
                        const int* __restrict__ dy, const int* __restrict__ sy,
                        const float* __restrict__ wy,
                        const int* __restrict__ rp1, const int* __restrict__ rp2,
                        const int* __restrict__ rpS, int* __restrict__ cnt3,
                        int* __restrict__ c1, float* __restrict__ v1,
                        int* __restrict__ c2, float* __restrict__ v2,
                        int* __restrict__ cS) {
  int e = blockIdx.x * blockDim.x + threadIdx.x;
  if (e >= 3 * E1C) return;
  int g = e / E1C, i = e - g * E1C;
  if (g == 0) {
    int k = d1[i];
    int p = atomicSub(&cnt3[k], 1) - 1;
    int s = rp1[k] + p;
    c1[s] = s1[i]; v1[s] = w1[i];
  } else if (g == 1) {
    int k = dy[i];
    int p = atomicSub(&cnt3[NB + k], 1) - 1;
    int s = rp2[k] + p;
    c2[s] = sy[i]; v2[s] = wy[i];
  } else {
    int k = s1[i];
    int p = atomicSub(&cnt3[2 * NB + k], 1) - 1;
    cS[rpS[k] + p] = d1[i];
  }
}

// fill storing the element index itself; atomicSub restores cnt to zero
__global__ void k_fill_iota(const int* __restrict__ key, const int* __restrict__ rowptr,
                            int* __restrict__ cnt, int* __restrict__ col, int n) {
  int e = blockIdx.x * blockDim.x + threadIdx.x;
  if (e < n) {
    int k = key[e];
    int p = atomicSub(&cnt[k], 1) - 1;
    col[rowptr[k] + p] = e;
  }
}

__global__ void k_count_coarse(const int* __restrict__ dst, const int* __restrict__ cluster,
                               int* __restrict__ cnt, int n) {
  int e = blockIdx.x * blockDim.x + threadIdx.x;
  if (e < n) atomicAdd(&cnt[cluster[dst[e]]], 1);
}

// coarse fill computing cw = w * a[src] * a[dst] inline; atomicSub restores cnt
__global__ void k_fill_coarse(const int* __restrict__ src, const int* __restrict__ dst,
                              const int* __restrict__ cluster, const float* __restrict__ w,
                              const float* __restrict__ a, const int* __restrict__ rowptr,
                              int* __restrict__ cnt, int* __restrict__ col,
                              float* __restrict__ v, int n) {
  int e = blockIdx.x * blockDim.x + threadIdx.x;
  if (e < n) {
    int sd = dst[e];
    int k = cluster[sd];
    int p = atomicSub(&cnt[k], 1) - 1;
    int s = rowptr[k] + p;
    int ss = src[e];
    col[s] = cluster[ss];
    v[s] = w[e] * a[ss] * a[sd];
  }
}

// ---------------- degree via CSR rowsum (32-lane slice per row) ----------------
__global__ void k_rowsum(const int* __restrict__ rowptr, const float* __restrict__ v,
                         float* __restrict__ deg, int n) {
  int row = blockIdx.x * 8 + (threadIdx.x >> 5);
  if (row >= n) return;
  int q = threadIdx.x & 31;
  int s0 = rowptr[row], s1 = rowptr[row + 1];
  float s = 0.f;
  for (int k = s0 + q; k < s1; k += 32) s += v[k];
#pragma unroll
  for (int o = 16; o; o >>= 1) s += __shfl_xor(s, o, 64);
  if (q == 0) deg[row] = s;
}

__global__ void k_csrnorm(const int* __restrict__ rowptr, const int* __restrict__ col,
                          float* __restrict__ v, const float* __restrict__ deg, int n) {
  int row = blockIdx.x * 8 + (threadIdx.x >> 5);
  if (row >= n) return;
  int q = threadIdx.x & 31;
  int s0 = rowptr[row], s1 = rowptr[row + 1];
  float di = deg[row] + 1.f;
  for (int s = s0 + q; s < s1; s += 32) {
    float dc = deg[col[s]] + 1.f;
    v[s] = v[s] / sqrtf(dc * di);
  }
}

// fused two-graph rowsum (g1 rows then g2 rows)
__global__ void k_rowsum2(const int* __restrict__ rpA, const float* __restrict__ vA,
                          float* __restrict__ degA, int nA,
                          const int* __restrict__ rpB, const float* __restrict__ vB,
                          float* __restrict__ degB, int nB) {
  int row = blockIdx.x * 8 + (threadIdx.x >> 5);
  const int* rp; const float* v; float* deg; int r;
  if (row < nA) { rp = rpA; v = vA; deg = degA; r = row; }
  else { r = row - nA; if (r >= nB) return; rp = rpB; v = vB; deg = degB; }
  int q = threadIdx.x & 31;
  int s0 = rp[r], s1 = rp[r + 1];
  float s = 0.f;
  for (int k = s0 + q; k < s1; k += 32) s += v[k];
#pragma unroll
  for (int o = 16; o; o >>= 1) s += __shfl_xor(s, o, 64);
  if (q == 0) deg[r] = s;
}

__global__ void k_csrnorm2(const int* __restrict__ rpA, const int* __restrict__ colA,
                           float* __restrict__ vA, const float* __restrict__ degA, int nA,
                           const int* __restrict__ rpB, const int* __restrict__ colB,
                           float* __restrict__ vB, const float* __restrict__ degB, int nB) {
  int row = blockIdx.x * 8 + (threadIdx.x >> 5);
  const int* rp; const int* col; float* v; const float* deg; int r;
  if (row < nA) { rp = rpA; col = colA; v = vA; deg = degA; r = row; }
  else { r = row - nA; if (r >= nB) return; rp = rpB; col = colB; v = vB; deg = degB; }
  int q = threadIdx.x & 31;
  int s0 = rp[r], s1 = rp[r + 1];
  float di = deg[r] + 1.f;
  for (int s = s0 + q; s < s1; s += 32) {
    float dc = deg[col[s]] + 1.f;
    v[s] = v[s] / sqrtf(dc * di);
  }
}

// ---------------- propagation fp32 (coarse graph; optional fused add+relu) -----------
__global__ void k_prop(const float4* __restrict__ hin, float4* __restrict__ hout,
                       const float4* __restrict__ addin, const int* __restrict__ rowptr,
                       const int* __restrict__ col, const float* __restrict__ val, int n) {
  int node = blockIdx.x * 8 + (threadIdx.x >> 5);
  if (node >= n) return;
  int q = threadIdx.x & 31;
  int grp = threadIdx.x & 32;
  int s0 = rowptr[node], s1 = rowptr[node + 1];
  float4 acc = make_float4(0.f, 0.f, 0.f, 0.f);
  for (int s = s0; s < s1; s += 32) {
    int es = s + q;
    int ok = es < s1;
    int sc = ok ? es : (s1 - 1);
    int cme = col[sc];
    float vme = ok ? val[sc] : 0.f;
    int nb = s1 - s; if (nb > 32) nb = 32;
    for (int j = 0; j < nb; j += 8) {
      int c8[8]; float v8[8];
#pragma unroll
      for (int t = 0; t < 8; ++t) {
        c8[t] = __shfl(cme, grp + j + t, 64);
        v8[t] = __shfl(vme, grp + j + t, 64);
      }
      float4 h[8];
#pragma unroll
      for (int t = 0; t < 8; ++t) h[t] = hin[(size_t)c8[t] * 32 + q];
#pragma unroll
      for (int t = 0; t < 8; ++t) {
        acc.x = fmaf(v8[t], h[t].x, acc.x);
        acc.y = fmaf(v8[t], h[t].y, acc.y);
        acc.z = fmaf(v8[t], h[t].z, acc.z);
        acc.w = fmaf(v8[t], h[t].w, acc.w);
      }
    }
  }
  if (addin) {
    float4 ad = addin[(size_t)node * 32 + q];
    float4 r;
    r.x = fmaxf(acc.x + ad.x, 0.f); r.y = fmaxf(acc.y + ad.y, 0.f);
    r.z = fmaxf(acc.z + ad.z, 0.f); r.w = fmaxf(acc.w + ad.w, 0.f);
    hout[(size_t)node * 32 + q] = r;
  } else {
    hout[(size_t)node * 32 + q] = acc;
  }
}

// ---------------- FUSED dual propagation: g1 fp32 hop + g2 bf16 hop (R8, verbatim) ---
__global__ void k_prop_dual(const float4* __restrict__ hin1, float4* __restrict__ hout1,
                            float4* __restrict__ xr_out,
                            const int* __restrict__ rp1, const int* __restrict__ col1,
                            const float* __restrict__ val1,
                            const ushort4* __restrict__ hin2, ushort4* __restrict__ hout2,
                            float4* __restrict__ fout2,
                            const int* __restrict__ rp2, const int* __restrict__ col2,
                            const float* __restrict__ val2, int n) {
  int node = (blockIdx.x >> 1) * 8 + (threadIdx.x >> 5);
  if (node >= n) return;
  int q = threadIdx.x & 31;
  int grp = threadIdx.x & 32;
  if ((blockIdx.x & 1) == 0) {
    int s0 = rp1[node], s1 = rp1[node + 1];
    float4 acc = make_float4(0.f, 0.f, 0.f, 0.f);
    for (int s = s0; s < s1; s += 32) {
      int es = s + q;
      int ok = es < s1;
      int sc = ok ? es : (s1 - 1);
      int cme = col1[sc];
      float vme = ok ? val1[sc] : 0.f;
      int nb = s1 - s; if (nb > 32) nb = 32;
      for (int j = 0; j < nb; j += 8) {
        int c8[8]; float v8[8];
#pragma unroll
        for (int t = 0; t < 8; ++t) {
          c8[t] = __shfl(cme, grp + j + t, 64);
          v8[t] = __shfl(vme, grp + j + t, 64);
        }
        float4 h[8];
#pragma unroll
        for (int t = 0; t < 8; ++t) h[t] = hin1[(size_t)c8[t] * 32 + q];
#pragma unroll
        for (int t = 0; t < 8; ++t) {
          acc.x = fmaf(v8[t], h[t].x, acc.x);
          acc.y = fmaf(v8[t], h[t].y, acc.y);
          acc.z = fmaf(v8[t], h[t].z, acc.z);
          acc.w = fmaf(v8[t], h[t].w, acc.w);
        }
      }
    }
    hout1[(size_t)node * 32 + q] = acc;
    if (xr_out) {
      float4 r;
      r.x = fmaxf(acc.x, 0.f); r.y = fmaxf(acc.y, 0.f);
      r.z = fmaxf(acc.z, 0.f); r.w = fmaxf(acc.w, 0.f);
      xr_out[(size_t)node * 32 + q] = r;
    }
  } else {
    int s0 = rp2[node], s1 = rp2[node + 1];
    float4 acc = make_float4(0.f, 0.f, 0.f, 0.f);
    for (int s = s0; s < s1; s += 32) {
      int es = s + q;
      int ok = es < s1;
      int sc = ok ? es : (s1 - 1);
      int cme = col2[sc];
      float vme = ok ? val2[sc] : 0.f;
      int nb = s1 - s; if (nb > 32) nb = 32;
      for (int j = 0; j < nb; j += 8) {
        int c8[8]; float v8[8];
#pragma unroll
        for (int t = 0; t < 8; ++t) {
          c8[t] = __shfl(cme, grp + j + t, 64);
          v8[t] = __shfl(vme, grp + j + t, 64);
        }
        ushort4 h[8];
#pragma unroll
        for (int t = 0; t < 8; ++t) h[t] = hin2[(size_t)c8[t] * 32 + q];
#pragma unroll
        for (int t = 0; t < 8; ++t) {
          acc.x = fmaf(v8[t], bf2f(h[t].x), acc.x);
          acc.y = fmaf(v8[t], bf2f(h[t].y), acc.y);
          acc.z = fmaf(v8[t], bf2f(h[t].z), acc.z);
          acc.w = fmaf(v8[t], bf2f(h[t].w), acc.w);
        }
      }
    }
    if (fout2) {
      fout2[(size_t)node * 32 + q] = acc;
    } else {
      ushort4 o;
      o.x = f2bf(acc.x); o.y = f2bf(acc.y); o.z = f2bf(acc.z); o.w = f2bf(acc.w);
      hout2[(size_t)node * 32 + q] = o;
    }
  }
}

// ---------------- dense matmul out = relu?(X @ W + b), W given transposed ----------------
__global__ void k_transpose6(const float* __restrict__ W0, const float* __restrict__ W1,
                             const float* __restrict__ W2, const float* __restrict__ W3,
                             const float* __restrict__ W4, const float* __restrict__ W5,
                             float* __restrict__ WT) {
  int i = blockIdx.x * blockDim.x + threadIdx.x;
  if (i >= 6 * F * F) return;
  int w = i >> 14, r = i & 16383, k = r >> 7, c = r & 127;
  const float* W = (w == 0) ? W0 : (w == 1) ? W1 : (w == 2) ? W2
                   : (w == 3) ? W3 : (w == 4) ? W4 : W5;
  WT[(size_t)w * 16384 + c * F + k] = W[r];
}

__global__ void k_mm128(const float* __restrict__ X, const float* __restrict__ WT,
                        const float* __restrict__ bias, float* __restrict__ out,
                        int M, int relu) {
  __shared__ float4 xs[16][32];
  int tid = threadIdx.x;
  int c = tid & 127;
  int half = tid >> 7;
  int row0 = blockIdx.x * 16;
  for (int t = tid; t < 512; t += 256) {
    int r = t >> 5, k4 = t & 31;
    int gr = row0 + r;
    float4 v = make_float4(0.f, 0.f, 0.f, 0.f);
    if (gr < M) v = ((const float4*)X)[(size_t)gr * 32 + k4];
    xs[r][k4] = v;
  }
  __syncthreads();
  float acc[8];
#pragma unroll
  for (int r = 0; r < 8; ++r) acc[r] = 0.f;
  const float4* wrow = (const float4*)WT + (size_t)c * 32;
  for (int k4 = 0; k4 < 32; ++k4) {
    float4 w = wrow[k4];
#pragma unroll
    for (int r = 0; r < 8; ++r) {
      float4 xv = xs[half * 8 + r][k4];
      acc[r] = fmaf(xv.x, w.x, acc[r]);
      acc[r] = fmaf(xv.y, w.y, acc[r]);
      acc[r] = fmaf(xv.z, w.z, acc[r]);
      acc[r] = fmaf(xv.w, w.w, acc[r]);
    }
  }
  float bb = bias ? bias[c] : 0.f;
#pragma unroll
  for (int r = 0; r < 8; ++r) {
    int gr = row0 + half * 8 + r;
    if (gr < M) {
      float v = acc[r] + bb;
      if (relu) v = fmaxf(v, 0.f);
      out[(size_t)gr * F + c] = v;
    }
  }
}

__global__ void k_mm128_bf16(const float* __restrict__ X, const float* __restrict__ WT,
                             const float* __restrict__ bias, unsigned short* __restrict__ out,
                             int M) {
  __shared__ float4 xs[16][32];
  int tid = threadIdx.x;
  int c = tid & 127;
  int half = tid >> 7;
  int row0 = blockIdx.x * 16;
  for (int t = tid; t < 512; t += 256) {
    int r = t >> 5, k4 = t & 31;
    int gr = row0 + r;
    float4 v = make_float4(0.f, 0.f, 0.f, 0.f);
    if (gr < M) v = ((const float4*)X)[(size_t)gr * 32 + k4];
    xs[r][k4] = v;
  }
  __syncthreads();
  float acc[8];
#pragma unroll
  for (int r = 0; r < 8; ++r) acc[r] = 0.f;
  const float4* wrow = (const float4*)WT + (size_t)c * 32;
  for (int k4 = 0; k4 < 32; ++k4) {
    float4 w = wrow[k4];
#pragma unroll
    for (int r = 0; r < 8; ++r) {
      float4 xv = xs[half * 8 + r][k4];
      acc[r] = fmaf(xv.x, w.x, acc[r]);
      acc[r] = fmaf(xv.y, w.y, acc[r]);
      acc[r] = fmaf(xv.z, w.z, acc[r]);
      acc[r] = fmaf(xv.w, w.w, acc[r]);
    }
  }
  float bb = bias ? bias[c] : 0.f;
#pragma unroll
  for (int r = 0; r < 8; ++r) {
    int gr = row0 + half * 8 + r;
    if (gr < M) out[(size_t)gr * F + c] = f2bf(acc[r] + bb);
  }
}

// ---------------- scores + ranking (top-k via 22-bit bin bucketing) ----------------
__device__ __forceinline__ unsigned sortkey(float f) {
  if (f == 0.f) f = 0.f;  // canonicalize -0 -> +0
  unsigned u = __float_as_uint(f);
  return (u & 0x80000000u) ? ~u : (u | 0x80000000u);
}

// fused score + sortkey (f_s eliminated; key is the only consumer)
__global__ void k_score_key(const float* __restrict__ xr, const float* __restrict__ p,
                            unsigned* __restrict__ key, int n) {
  int wid = (blockIdx.x * blockDim.x + threadIdx.x) >> 6;
  int lane = threadIdx.x & 63;
  if (wid >= n) return;
  const float* row = xr + (size_t)wid * F;
  float d = row[lane] * p[lane] + row[lane + 64] * p[lane + 64];
#pragma unroll
  for (int o = 32; o; o >>= 1) d += __shfl_xor(d, o, 64);
  if (lane == 0) key[wid] = sortkey(d);
}

__global__ void k_count_bins22(const unsigned* __restrict__ key, int* __restrict__ cnt, int n) {
  int i = blockIdx.x * blockDim.x + threadIdx.x;
  if (i < n) atomicAdd(&cnt[key[i] >> 10], 1);
}

__global__ void k_hist_blocksum(const int* __restrict__ cnt, int* __restrict__ partial) {
  int t = threadIdx.x;
  int base = blockIdx.x * 1024 + t * 4;
  int s = cnt[base] + cnt[base + 1] + cnt[base + 2] + cnt[base + 3];
#pragma unroll
  for (int o = 32; o; o >>= 1) s += __shfl_down(s, o, 64);
  __shared__ int ws[4];
  int lane = t & 63, w = t >> 6;
  if (lane == 0) ws[w] = s;
  __syncthreads();
  if (t == 0) partial[blockIdx.x] = ws[0] + ws[1] + ws[2] + ws[3];
}

__global__ void k_hist_apply(const int* __restrict__ cnt, const int* __restrict__ partialptr,
                             int* __restrict__ binptr) {
  int t = threadIdx.x;
  int base = blockIdx.x * 1024 + t * 4;
  int c0 = cnt[base], c1 = cnt[base + 1], c2 = cnt[base + 2], c3 = cnt[base + 3];
  int s = c0 + c1 + c2 + c3;
  int lane = t & 63, w = t >> 6;
  int v = s;
#pragma unroll
  for (int o = 1; o < 64; o <<= 1) {
    int u = __shfl_up(v, o, 64);
    if (lane >= o) v += u;
  }
  __shared__ int ws[4];
  if (lane == 63) ws[w] = v;
  __syncthreads();
  int wb = 0;
  for (int i = 0; i < w; ++i) wb += ws[i];
  int run = partialptr[blockIdx.x] + wb + (v - s);
  binptr[base + 1] = run + c0;
  binptr[base + 2] = run + c0 + c1;
  binptr[base + 3] = run + c0 + c1 + c2;
  binptr[base + 4] = run + s;
  if (blockIdx.x == 0 && t == 0) binptr[0] = 0;
}

// atomicSub variant: cnt22 self-zeroes (second 16.8MB memset eliminated);
// within-bin order irrelevant (rank22 compares bidx values, not positions)
__global__ void k_fill_bins22(const unsigned* __restrict__ key, const int* __restrict__ binptr,
                              int* __restrict__ cnt, int* __restrict__ bidx,
                              unsigned* __restrict__ bkey, int n) {
  int i = blockIdx.x * blockDim.x + threadIdx.x;
  if (i < n) {
    unsigned k = key[i];
    int b = k >> 10;
    int p = atomicSub(&cnt[b], 1) - 1;
    int s = binptr[b] + p;
    bidx[s] = i;
    bkey[s] = k;
  }
}

__global__ void k_rank22(const unsigned* __restrict__ key, const int* __restrict__ binptr,
                         const int* __restrict__ bidx, const unsigned* __restrict__ bkey,
                         int* __restrict__ supid, int n) {
  int i = blockIdx.x * blockDim.x + threadIdx.x;
  if (i >= n) return;
  unsigned ki = key[i];
  int b = ki >> 10;
  int cnt = n - binptr[b + 1];
  int s1 = binptr[b + 1];
  for (int s = binptr[b]; s < s1; ++s) {
    unsigned kj = bkey[s];
    cnt += (kj > ki) || (kj == ki && bidx[s] < i);
  }
  supid[i] = (cnt < NSUP) ? cnt : -1;
}

// ---------------- attention / assignment (FUSED online softmax+argmax) ----------------
__device__ __forceinline__ float read_T(const void* p) {
  int ib = *(const int*)p;
  float fb = __int_as_float(ib);
  if (ib >= 1 && ib < (1 << 20)) return (float)ib;
  if (fb > 1e-6f && fb < 1e6f) return fb;
  return 1.0f;
}

// wave per node; online running (m, esum, best). Max/argmax tracking is EXACT
// (comparisons on exact f32 att values) -> cluster decisions identical to the
// two-pass version; esum rescaling differs only in rounding (value path).
// Eliminates k_att_b and the f_att/f_attself/f_m buffers entirely.
__global__ void k_att(const float* __restrict__ xr, const int* __restrict__ rowptr,
                      const int* __restrict__ col, const int* __restrict__ supid,
                      const void* __restrict__ tptr,
                      int* __restrict__ cluster, float* __restrict__ aout, int n) {
  int wid = (blockIdx.x * blockDim.x + threadIdx.x) >> 6;
  int lane = threadIdx.x & 63;
  if (wid >= n) return;
  float inv = 1.0f / (sqrtf(128.0f) * read_T(tptr));
  const float* xn = xr + (size_t)wid * F;
  float x0 = xn[lane], x1 = xn[lane + 64];
  float d = x0 * x0 + x1 * x1;
#pragma unroll
  for (int o = 32; o; o >>= 1) d += __shfl_xor(d, o, 64);
  int sid_self = supid[wid];
  float m = (sid_self >= 0) ? d * inv : NEGINF;
  float esum = 1.0f;      // exp(self - m) with m == self-att
  int best = sid_self;
  int s0 = rowptr[wid], s1 = rowptr[wid + 1];
  for (int s = s0; s < s1; s += 4) {
    int c[4]; bool ok[4];
#pragma unroll
    for (int j = 0; j < 4; ++j) {
      int ss = s + j;
      ok[j] = ss < s1;
      c[j] = col[ok[j] ? ss : (s1 - 1)];
    }
    float dd[4];
#pragma unroll
    for (int j = 0; j < 4; ++j) {
      const float* xc = xr + (size_t)c[j] * F;
      dd[j] = x0 * xc[lane] + x1 * xc[lane + 64];
    }
#pragma unroll
    for (int j = 0; j < 4; ++j) {
#pragma unroll
      for (int o = 32; o; o >>= 1) dd[j] += __shfl_xor(dd[j], o, 64);
    }
#pragma unroll
    for (int j = 0; j < 4; ++j) {
      if (ok[j]) {
        int sid = supid[c[j]];
        float a2 = (sid >= 0) ? dd[j] * inv : NEGINF;
        if (a2 > m) {
          esum = esum * expf(m - a2) + 1.0f;
          m = a2;
          best = sid;
        } else {
          esum += expf(a2 - m);
          if (a2 == m && sid > best) best = sid;
        }
      }
    }
  }
  if (lane == 0) {
    int has = best >= 0;
    cluster[wid] = has ? best : 0;
    aout[wid] = has ? 1.0f / esum : 0.0f;
  }
}

// ---------------- pooling (pull over cluster->member CSR) ----------------
__global__ void k_xpool_pull(const float4* __restrict__ xr, const float* __restrict__ a,
                             const int* __restrict__ rowptrM, const int* __restrict__ memb,
                             float4* __restrict__ xpool, int n) {
  int c = blockIdx.x * 8 + (threadIdx.x >> 5);
  if (c >= n) return;
  int q = threadIdx.x & 31;
  int s0 = rowptrM[c], s1 = rowptrM[c + 1];
  float4 acc = make_float4(0.f, 0.f, 0.f, 0.f);
  for (int s = s0; s < s1; ++s) {
    int m = memb[s];
    float av = a[m];
    float4 h = xr[(size_t)m * 32 + q];
    acc.x = fmaf(av, h.x, acc.x);
    acc.y = fmaf(av, h.y, acc.y);
    acc.z = fmaf(av, h.z, acc.z);
    acc.w = fmaf(av, h.w, acc.w);
  }
  xpool[(size_t)c * 32 + q] = acc;
}

// ---------------- fused anchor scatter (one atomic per element) ----------------
__global__ void k_scatter2(const int* __restrict__ a1, const int* __restrict__ a2,
                           const int* __restrict__ cluster, const float* __restrict__ aarr,
                           const float* __restrict__ t1, const float* __restrict__ t2,
                           float* __restrict__ outy, int nA) {
  int idx = blockIdx.x * blockDim.x + threadIdx.x;
  if (idx >= nA * F) return;
  int k = idx >> 7, f = idx & 127;
  int n1 = a1[k];
  float add = t2[(size_t)n1 * F + f];
  float qw = aarr[n1];
  if (qw != 0.f) add += qw * t1[(size_t)cluster[n1] * F + f];
  atomicAdd(&outy[(size_t)a2[k] * F + f], add);
}

// ================= host =================
extern "C" void kernel_launch(void* const* d_in, const int* in_sizes, int n_in,
                              void* d_out, int out_size, void* d_ws, size_t ws_size,
                              hipStream_t stream) {
  (void)in_sizes; (void)n_in; (void)out_size; (void)ws_size;
  const float* x   = (const float*)d_in[0];
  const int*   ei  = (const int*)d_in[1];
  const float* w1  = (const float*)d_in[2];
  const float* y   = (const float*)d_in[3];
  const int*   eiy = (const int*)d_in[4];
  const float* wy  = (const float*)d_in[5];
  const int*   anc = (const int*)d_in[6];
  const void*  tmp = d_in[7];
  const float* W_gcn = (const float*)d_in[8];
  const float* b_gcn = (const float*)d_in[9];
  const float* p_sc  = (const float*)d_in[10];
  const float* W_c1  = (const float*)d_in[11];
  const float* b_c1  = (const float*)d_in[12];
  const float* W_m1  = (const float*)d_in[13];
  const float* b_m1  = (const float*)d_in[14];
  const float* W_l1  = (const float*)d_in[15];
  const float* W_l2  = (const float*)d_in[16];
  const float* W_m2  = (const float*)d_in[17];
  const float* b_m2  = (const float*)d_in[18];

  float* out   = (float*)d_out;
  float* out_x = out;
  float* sup1  = out_x + (size_t)N1 * F;
  float* out_y = sup1 + (size_t)NSUP * F;
  float* sup2  = out_y + (size_t)N2 * F;
  float* a_out = sup2 + (size_t)NSUP * F;
  float* recon = a_out + N1;

  char* wsb = (char*)d_ws;
  size_t off = 0;
  auto alloc = [&](size_t bytes) -> void* {
    void* p = wsb + off;
    off = (off + bytes + 255) & ~(size_t)255;
    return p;
  };
  float*    f_csr1v   = (float*)alloc((size_t)E1C * 4);
  int*      i_csr1c   = (int*)alloc((size_t)E1C * 4);
  int*      i_rowptr1 = (int*)alloc((size_t)(N1 + 1) * 4);
  int*      i_rowptr2 = (int*)alloc((size_t)(N2 + 1) * 4);
  float*    f_deg     = (float*)alloc((size_t)N1 * 4);
  float*    f_deg2    = (float*)alloc((size_t)N2 * 4);
  int*      i_cnt3    = (int*)alloc((size_t)3 * NB * 4);         // self-restoring counters
  float*    f_ha      = (float*)alloc((size_t)N1 * F * 4);       // g1 h ping / cnt22 overlay
  float*    f_hb      = (float*)alloc((size_t)N1 * F * 4);       // g1 h pong / binptr22 overlay
  float*    f_xr      = (float*)alloc((size_t)N1 * F * 4);       // reused for t2
  unsigned* u_key     = (unsigned*)alloc((size_t)N1 * 4);
  int*      i_partial = (int*)alloc((size_t)4096 * 4);
  int*      i_partptr = (int*)alloc((size_t)4097 * 4);
  int*      i_bidx    = (int*)alloc((size_t)N1 * 4);
  unsigned* u_bkey    = (unsigned*)alloc((size_t)N1 * 4);
  int*      i_supid   = (int*)alloc((size_t)N1 * 4);
  int*      i_rowptrS = (int*)alloc((size_t)(N1 + 1) * 4);
  int*      i_csrSc   = (int*)alloc((size_t)E1C * 4);
  int*      i_cluster = (int*)alloc((size_t)N1 * 4);
  float*    f_xpool   = (float*)alloc((size_t)NSUP * F * 4);
  float*    f_degc    = (float*)alloc((size_t)NSUP * 4);
  int*      i_rowptrC = (int*)alloc((size_t)(NSUP + 1) * 4);
  int*      i_csrCc   = (int*)alloc((size_t)E1C * 4);
  float*    f_csrCv   = (float*)alloc((size_t)E1C * 4);
  int*      i_rowptrM = (int*)alloc((size_t)(NSUP + 1) * 4);
  int*      i_memb    = (int*)alloc((size_t)N1 * 4);
  float*    f_h2      = (float*)alloc((size_t)NSUP * F * 4);
  float*    f_h2p     = (float*)alloc((size_t)NSUP * F * 4);     // t1
  float*    f_wt      = (float*)alloc((size_t)6 * F * F * 4);

  // overlays (non-overlapping lifetimes):
  int* i_cnt22    = (int*)f_ha;       // rank bins live after props (g1 ping-pong dead)
  int* i_binptr22 = (int*)f_hb;
  int*   i_csr2c  = i_csrCc;          // g2 CSR lives before coarse CSR
  float* f_csr2v  = f_csrCv;
  unsigned short* h16a = (unsigned short*)f_xpool;   // g2 bf16 h lives before coarsen
  unsigned short* h16b = (unsigned short*)f_h2;

  const int* src1 = ei,  * dst1 = ei + E1C;
  const int* srcy = eiy, * dsty = eiy + E2C;
  const int* a1 = anc, * a2 = anc + AC;

  int gE = cdiv(E1C, 256);
  int gN = cdiv(N1, 256);
  int gC8 = cdiv(NSUP, 8);
  int gD = 2 * cdiv(N1, 8);

  // --- single upfront counter memset (counters self-restore via atomicSub fills) ---
  hipMemsetAsync(i_cnt3, 0, (size_t)3 * NB * 4, stream);
  k_transpose6<<<cdiv(6 * F * F, 256), 256, 0, stream>>>(W_gcn, W_c1, W_m1, W_l1, W_l2,
                                                         W_m2, f_wt);
  float* wt_gcn = f_wt, *wt_c1 = f_wt + 16384, *wt_m1 = f_wt + 2 * 16384,
       * wt_l1 = f_wt + 3 * 16384, *wt_l2 = f_wt + 4 * 16384, *wt_m2 = f_wt + 5 * 16384;

  // --- all three big CSRs (g1-by-dst, g2, g1-by-src) in 3 fused launches ---
  k_count3<<<cdiv(3 * E1C, 256), 256, 0, stream>>>(dst1, dsty, src1, i_cnt3);
  k_scan3<<<3, 1024, 0, stream>>>(i_cnt3, i_rowptr1, i_rowptr2, i_rowptrS, N1, N2, N1);
  k_fill3<<<cdiv(3 * E1C, 256), 256, 0, stream>>>(dst1, src1, w1, dsty, srcy, wy,
                                                  i_rowptr1, i_rowptr2, i_rowptrS, i_cnt3,
                                                  i_csr1c, f_csr1v, i_csr2c, f_csr2v,
                                                  i_csrSc);
  k_rowsum2<<<cdiv(N1 + N2, 8), 256, 0, stream>>>(i_rowptr1, f_csr1v, f_deg, N1,
                                                  i_rowptr2, f_csr2v, f_deg2, N2);
  k_csrnorm2<<<cdiv(N1 + N2, 8), 256, 0, stream>>>(i_rowptr1, i_csr1c, f_csr1v, f_deg, N1,
                                                   i_rowptr2, i_csr2c, f_csr2v, f_deg2, N2);

  // --- h0 for both graphs ---
  k_mm128<<<cdiv(N1, 16), 256, 0, stream>>>(x, wt_gcn, b_gcn, f_ha, N1, 0);
  k_mm128_bf16<<<cdiv(N2, 16), 256, 0, stream>>>(y, wt_gcn, b_gcn, h16a, N2);

  // --- FUSED 10 hops: g1 fp32 + g2 bf16 co-scheduled per dispatch ---
  {
    const float* cur1 = f_ha;
    const unsigned short* cur2 = h16a;
    for (int i = 0; i < KHOPS; ++i) {
      int last = (i == KHOPS - 1);
      float* dst1b = last ? out_x : ((i & 1) ? f_ha : f_hb);
      unsigned short* dst2b = (i & 1) ? h16a : h16b;
      k_prop_dual<<<gD, 256, 0, stream>>>(
          (const float4*)cur1, (float4*)dst1b, last ? (float4*)f_xr : nullptr,
          i_rowptr1, i_csr1c, f_csr1v,
          (const ushort4*)cur2, (ushort4*)dst2b, last ? (float4*)out_y : nullptr,
          i_rowptr2, i_csr2c, f_csr2v, N1);
      cur1 = dst1b; cur2 = dst2b;
    }
  }

  // --- scores + top-k ranks (22-bit bins; overlays on f_ha/f_hb, now free) ---
  k_score_key<<<cdiv(N1, 4), 256, 0, stream>>>(f_xr, p_sc, u_key, N1);
  hipMemsetAsync(i_cnt22, 0, (size_t)NBINS22 * 4, stream);
  k_count_bins22<<<gN, 256, 0, stream>>>(u_key, i_cnt22, N1);
  k_hist_blocksum<<<NBINS22 / 1024, 256, 0, stream>>>(i_cnt22, i_partial);
  k_scan<<<1, 1024, 0, stream>>>(i_partial, i_partptr, 4096);
  k_hist_apply<<<NBINS22 / 1024, 256, 0, stream>>>(i_cnt22, i_partptr, i_binptr22);
  k_fill_bins22<<<gN, 256, 0, stream>>>(u_key, i_binptr22, i_cnt22, i_bidx, u_bkey, N1);
  k_rank22<<<gN, 256, 0, stream>>>(u_key, i_binptr22, i_bidx, u_bkey, i_supid, N1);

  // --- fused attention: online softmax + exact argmax, one pass ---
  k_att<<<cdiv(N1, 4), 256, 0, stream>>>(f_xr, i_rowptrS, i_csrSc, i_supid, tmp,
                                         i_cluster, a_out, N1);

  // --- coarsen: cluster->member CSR + pull pooling (cnt3 region 0, self-restored) ---
  k_count<<<gN, 256, 0, stream>>>(i_cluster, i_cnt3, N1);
  k_scan<<<1, 1024, 0, stream>>>(i_cnt3, i_rowptrM, NSUP);
  k_fill_iota<<<gN, 256, 0, stream>>>(i_cluster, i_rowptrM, i_cnt3, i_memb, N1);
  k_xpool_pull<<<gC8, 256, 0, stream>>>((const float4*)f_xr, a_out, i_rowptrM,
                                        i_memb, (float4*)f_xpool, NSUP);

  // --- coarse CSR with cw values (cnt3 region 0 again) ---
  k_count_coarse<<<gE, 256, 0, stream>>>(dst1, i_cluster, i_cnt3, E1C);
  k_scan<<<1, 1024, 0, stream>>>(i_cnt3, i_rowptrC, NSUP);
  k_fill_coarse<<<gE, 256, 0, stream>>>(src1, dst1, i_cluster, w1, a_out, i_rowptrC, i_cnt3,
                                        i_csrCc, f_csrCv, E1C);
  k_rowsum<<<gC8, 256, 0, stream>>>(i_rowptrC, f_csrCv, f_degc, NSUP);
  k_csrnorm<<<gC8, 256, 0, stream>>>(i_rowptrC, i_csrCc, f_csrCv, f_degc, NSUP);

  // --- coarse conv (prop + add + relu fused) + MLP1 ---
  k_mm128<<<cdiv(NSUP, 16), 256, 0, stream>>>(f_xpool, wt_c1, b_c1, f_h2, NSUP, 0);
  k_prop<<<gC8, 256, 0, stream>>>((const float4*)f_h2, (float4*)sup1, (const float4*)f_h2,
                                  i_rowptrC, i_csrCc, f_csrCv, NSUP);
  k_mm128<<<cdiv(NSUP, 16), 256, 0, stream>>>(sup1, wt_m1, b_m1, sup2, NSUP, 1);

  // --- LastLayer: both mms, then one fused scatter ---
  float* f_t1 = f_h2p;
  float* f_t2 = f_xr;
  k_mm128<<<cdiv(NSUP, 16), 256, 0, stream>>>(sup2, wt_l1, (const float*)nullptr, f_t1,
                                              NSUP, 0);
  k_mm128<<<cdiv(N1, 16), 256, 0, stream>>>(out_x, wt_l2, (const float*)nullptr, f_t2,
                                            N1, 0);
  k_scatter2<<<cdiv(AC * F, 256), 256, 0, stream>>>(a1, a2, i_cluster, a_out, f_t1, f_t2,
                                                    out_y, AC);

  // --- recon ---
  k_mm128<<<cdiv(N2, 16), 256, 0, stream>>>(out_y, wt_m2, b_m2, recon, N2, 0);
}

// Round 10
// 2092.781 us; speedup vs baseline: 1.7729x; 1.0138x over previous
//
#include <hip/hip_runtime.h>
#include <hip/hip_bf16.h>
#include <math.h>

#define N1 50000
#define N2 50000
#define E1C 800000
#define E2C 800000
#define AC 10000
#define F 128
#define NSUP 25000
#define KHOPS 10
#define NEGINF -1e30f
#define NB 65536
#define NBINS22 (1 << 22)

static inline int cdiv(int a, int b) { return (a + b - 1) / b; }

// ---------------- bf16 helpers ----------------
__device__ __forceinline__ float bf2f(unsigned short u) {
  return __uint_as_float(((unsigned)u) << 16);
}
__device__ __forceinline__ unsigned short f2bf(float f) {
  unsigned x = __float_as_uint(f);
  return (unsigned short)((x + 0x7FFFu + ((x >> 16) & 1u)) >> 16);
}

// ---------------- CSR build (edges stored interleaved as int2 {col, val-bits}) -------
__global__ void k_count(const int* __restrict__ key, int* __restrict__ cnt, int n) {
  int e = blockIdx.x * blockDim.x + threadIdx.x;
  if (e < n) atomicAdd(&cnt[key[e]], 1);
}

// fused triple count: g0=dst1, g1=dsty, g2=src1 into 3 cnt regions
__global__ void k_count3(const int* __restrict__ d1, const int* __restrict__ dy,
                         const int* __restrict__ s1, int* __restrict__ cnt3) {
  int e = blockIdx.x * blockDim.x + threadIdx.x;
  if (e >= 3 * E1C) return;
  int g = e / E1C, i = e - g * E1C;
  int key = (g == 0) ? d1[i] : (g == 1) ? dy[i] : s1[i];
  atomicAdd(&cnt3[g * NB + key], 1);
}

// single-block scan body (thread-sequential partials + shuffle scan)
__device__ __forceinline__ void scan_body(const int* cnt, int* rowptr, int n) {
  const int T = 1024;
  int t = threadIdx.x;
  int vpt = (n + T - 1) / T;
  int lo = t * vpt, hi = lo + vpt;
  if (hi > n) hi = n;
  int sum = 0;
  for (int i = lo; i < hi; ++i) sum += cnt[i];
  int lane = t & 63, wid = t >> 6;
  int v = sum;
#pragma unroll
  for (int o = 1; o < 64; o <<= 1) {
    int u = __shfl_up(v, o, 64);
    if (lane >= o) v += u;
  }
  __shared__ int wsum[16];
  if (lane == 63) wsum[wid] = v;
  __syncthreads();
  if (t < 16) {
    int w = wsum[t];
#pragma unroll
    for (int o = 1; o < 16; o <<= 1) {
      int u = __shfl_up(w, o, 64);
      if (t >= o) w += u;
    }
    wsum[t] = w;
  }
  __syncthreads();
  int base = (wid ? wsum[wid - 1] : 0) + (v - sum);
  if (t == 0) rowptr[0] = 0;
  int run = base;
  for (int i = lo; i < hi; ++i) { run += cnt[i]; rowptr[i + 1] = run; }
}

__global__ void k_scan(const int* __restrict__ cnt, int* __restrict__ rowptr, int n) {
  scan_body(cnt, rowptr, n);
}

__global__ void k_scan3(const int* __restrict__ cnt3, int* __restrict__ rp0,
                        int* __restrict__ rp1, int* __restrict__ rp2,
                        int n0, int n1, int n2) {
  int b = blockIdx.x;
  const int* cnt = cnt3 + b * NB;
  int* rowptr = (b == 0) ? rp0 : (b == 1) ? rp1 : rp2;
  int n = (b == 0) ? n0 : (b == 1) ? n1 : n2;
  scan_body(cnt, rowptr, n);
}

// fused triple fill; atomicSub restores cnt3 to zero. Edge payload written as ONE
// 8B int2 {col, val-bits} instead of two 4B scatters 12.8MB apart -> halves the
// scattered-line count (R9: WRITE_SIZE 219MB for 16MB payload = 13x amplification).
__global__ void k_fill3(const int* __restrict__ d1, const int* __restrict__ s1,
                        const float* __restrict__ w1,
                        const int* __restrict__ dy, const int* __restrict__ sy,
                        const float* __restrict__ wy,
                        const int* __restrict__ rp1, const int* __restrict__ rp2,
                        const int* __restrict__ rpS, int* __restrict__ cnt3,
                        int2* __restrict__ e1, int2* __restrict__ e2,
                        int* __restrict__ cS) {
  int e = blockIdx.x * blockDim.x + threadIdx.x;
  if (e >= 3 * E1C) return;
  int g = e / E1C, i = e - g * E1C;
  if (g == 0) {
    int k = d1[i];
    int p = atomicSub(&cnt3[k], 1) - 1;
    e1[rp1[k] + p] = make_int2(s1[i], __float_as_int(w1[i]));
  } else if (g == 1) {
    int k = dy[i];
    int p = atomicSub(&cnt3[NB + k], 1) - 1;
    e2[rp2[k] + p] = make_int2(sy[i], __float_as_int(wy[i]));
  } else {
    int k = s1[i];
    int p = atomicSub(&cnt3[2 * NB + k], 1) - 1;
    cS[rpS[k] + p] = d1[i];
  }
}

// fill storing the element index itself; atomicSub restores cnt to zero
__global__ void k_fill_iota(const int* __restrict__ key, const int* __restrict__ rowptr,
                            int* __restrict__ cnt, int* __restrict__ col, int n) {
  int e = blockIdx.x * blockDim.x + threadIdx.x;
  if (e < n) {
    int k = key[e];
    int p = atomicSub(&cnt[k], 1) - 1;
    col[rowptr[k] + p] = e;
  }
}

__global__ void k_count_coarse(const int* __restrict__ dst, const int* __restrict__ cluster,
                               int* __restrict__ cnt, int n) {
  int e = blockIdx.x * blockDim.x + threadIdx.x;
  if (e < n) atomicAdd(&cnt[cluster[dst[e]]], 1);
}

// coarse fill computing cw inline; int2-interleaved output; atomicSub restores cnt
__global__ void k_fill_coarse(const int* __restrict__ src, const int* __restrict__ dst,
                              const int* __restrict__ cluster, const float* __restrict__ w,
                              const float* __restrict__ a, const int* __restrict__ rowptr,
                              int* __restrict__ cnt, int2* __restrict__ eC, int n) {
  int e = blockIdx.x * blockDim.x + threadIdx.x;
  if (e < n) {
    int sd = dst[e];
    int k = cluster[sd];
    int p = atomicSub(&cnt[k], 1) - 1;
    int ss = src[e];
    eC[rowptr[k] + p] = make_int2(cluster[ss],
                                  __float_as_int(w[e] * a[ss] * a[sd]));
  }
}

// ---------------- degree via CSR rowsum (32-lane slice per row, int2 edges) ----------
__global__ void k_rowsum(const int2* __restrict__ e, const int* __restrict__ rowptr,
                         float* __restrict__ deg, int n) {
  int row = blockIdx.x * 8 + (threadIdx.x >> 5);
  if (row >= n) return;
  int q = threadIdx.x & 31;
  int s0 = rowptr[row], s1 = rowptr[row + 1];
  float s = 0.f;
  for (int k = s0 + q; k < s1; k += 32) s += __int_as_float(e[k].y);
#pragma unroll
  for (int o = 16; o; o >>= 1) s += __shfl_xor(s, o, 64);
  if (q == 0) deg[row] = s;
}

__global__ void k_csrnorm(int2* __restrict__ e, const int* __restrict__ rowptr,
                          const float* __restrict__ deg, int n) {
  int row = blockIdx.x * 8 + (threadIdx.x >> 5);
  if (row >= n) return;
  int q = threadIdx.x & 31;
  int s0 = rowptr[row], s1 = rowptr[row + 1];
  float di = deg[row] + 1.f;
  for (int s = s0 + q; s < s1; s += 32) {
    int2 ee = e[s];
    float dc = deg[ee.x] + 1.f;
    ee.y = __float_as_int(__int_as_float(ee.y) / sqrtf(dc * di));
    e[s] = ee;
  }
}

// fused two-graph rowsum (g1 rows then g2 rows)
__global__ void k_rowsum2(const int2* __restrict__ eA, const int* __restrict__ rpA,
                          float* __restrict__ degA, int nA,
                          const int2* __restrict__ eB, const int* __restrict__ rpB,
                          float* __restrict__ degB, int nB) {
  int row = blockIdx.x * 8 + (threadIdx.x >> 5);
  const int2* e; const int* rp; float* deg; int r;
  if (row < nA) { e = eA; rp = rpA; deg = degA; r = row; }
  else { r = row - nA; if (r >= nB) return; e = eB; rp = rpB; deg = degB; }
  int q = threadIdx.x & 31;
  int s0 = rp[r], s1 = rp[r + 1];
  float s = 0.f;
  for (int k = s0 + q; k < s1; k += 32) s += __int_as_float(e[k].y);
#pragma unroll
  for (int o = 16; o; o >>= 1) s += __shfl_xor(s, o, 64);
  if (q == 0) deg[r] = s;
}

__global__ void k_csrnorm2(int2* __restrict__ eA, const int* __restrict__ rpA,
                           const float* __restrict__ degA, int nA,
                           int2* __restrict__ eB, const int* __restrict__ rpB,
                           const float* __restrict__ degB, int nB) {
  int row = blockIdx.x * 8 + (threadIdx.x >> 5);
  int2* e; const int* rp; const float* deg; int r;
  if (row < nA) { e = eA; rp = rpA; deg = degA; r = row; }
  else { r = row - nA; if (r >= nB) return; e = eB; rp = rpB; deg = degB; }
  int q = threadIdx.x & 31;
  int s0 = rp[r], s1 = rp[r + 1];
  float di = deg[r] + 1.f;
  for (int s = s0 + q; s < s1; s += 32) {
    int2 ee = e[s];
    float dc = deg[ee.x] + 1.f;
    ee.y = __float_as_int(__int_as_float(ee.y) / sqrtf(dc * di));
    e[s] = ee;
  }
}

// ---------------- propagation fp32 (coarse graph; optional fused add+relu) -----------
__global__ void k_prop(const float4* __restrict__ hin, float4* __restrict__ hout,
                       const float4* __restrict__ addin, const int* __restrict__ rowptr,
                       const int2* __restrict__ edg, int n) {
  int node = blockIdx.x * 8 + (threadIdx.x >> 5);
  if (node >= n) return;
  int q = threadIdx.x & 31;
  int grp = threadIdx.x & 32;
  int s0 = rowptr[node], s1 = rowptr[node + 1];
  float4 acc = make_float4(0.f, 0.f, 0.f, 0.f);
  for (int s = s0; s < s1; s += 32) {
    int es = s + q;
    int ok = es < s1;
    int sc = ok ? es : (s1 - 1);
    int2 ee = edg[sc];                    // coalesced: one 8B load per edge
    int cme = ee.x;
    float vme = ok ? __int_as_float(ee.y) : 0.f;
    int nb = s1 - s; if (nb > 32) nb = 32;
    for (int j = 0; j < nb; j += 8) {
      int c8[8]; float v8[8];
#pragma unroll
      for (int t = 0; t < 8; ++t) {
        c8[t] = __shfl(cme, grp + j + t, 64);
        v8[t] = __shfl(vme, grp + j + t, 64);
      }
      float4 h[8];
#pragma unroll
      for (int t = 0; t < 8; ++t) h[t] = hin[(size_t)c8[t] * 32 + q];
#pragma unroll
      for (int t = 0; t < 8; ++t) {
        acc.x = fmaf(v8[t], h[t].x, acc.x);
        acc.y = fmaf(v8[t], h[t].y, acc.y);
        acc.z = fmaf(v8[t], h[t].z, acc.z);
        acc.w = fmaf(v8[t], h[t].w, acc.w);
      }
    }
  }
  if (addin) {
    float4 ad = addin[(size_t)node * 32 + q];
    float4 r;
    r.x = fmaxf(acc.x + ad.x, 0.f); r.y = fmaxf(acc.y + ad.y, 0.f);
    r.z = fmaxf(acc.z + ad.z, 0.f); r.w = fmaxf(acc.w + ad.w, 0.f);
    hout[(size_t)node * 32 + q] = r;
  } else {
    hout[(size_t)node * 32 + q] = acc;
  }
}

// ---------------- FUSED dual propagation: g1 fp32 hop + g2 bf16 hop ------------------
__global__ void k_prop_dual(const float4* __restrict__ hin1, float4* __restrict__ hout1,
                            float4* __restrict__ xr_out,
                            const int* __restrict__ rp1, const int2* __restrict__ edg1,
                            const ushort4* __restrict__ hin2, ushort4* __restrict__ hout2,
                            float4* __restrict__ fout2,
                            const int* __restrict__ rp2, const int2* __restrict__ edg2,
                            int n) {
  int node = (blockIdx.x >> 1) * 8 + (threadIdx.x >> 5);
  if (node >= n) return;
  int q = threadIdx.x & 31;
  int grp = threadIdx.x & 32;
  if ((blockIdx.x & 1) == 0) {
    int s0 = rp1[node], s1 = rp1[node + 1];
    float4 acc = make_float4(0.f, 0.f, 0.f, 0.f);
    for (int s = s0; s < s1; s += 32) {
      int es = s + q;
      int ok = es < s1;
      int sc = ok ? es : (s1 - 1);
      int2 ee = edg1[sc];
      int cme = ee.x;
      float vme = ok ? __int_as_float(ee.y) : 0.f;
      int nb = s1 - s; if (nb > 32) nb = 32;
      for (int j = 0; j < nb; j += 8) {
        int c8[8]; float v8[8];
#pragma unroll
        for (int t = 0; t < 8; ++t) {
          c8[t] = __shfl(cme, grp + j + t, 64);
          v8[t] = __shfl(vme, grp + j + t, 64);
        }
        float4 h[8];
#pragma unroll
        for (int t = 0; t < 8; ++t) h[t] = hin1[(size_t)c8[t] * 32 + q];
#pragma unroll
        for (int t = 0; t < 8; ++t) {
          acc.x = fmaf(v8[t], h[t].x, acc.x);
          acc.y = fmaf(v8[t], h[t].y, acc.y);
          acc.z = fmaf(v8[t], h[t].z, acc.z);
          acc.w = fmaf(v8[t], h[t].w, acc.w);
        }
      }
    }
    hout1[(size_t)node * 32 + q] = acc;
    if (xr_out) {
      float4 r;
      r.x = fmaxf(acc.x, 0.f); r.y = fmaxf(acc.y, 0.f);
      r.z = fmaxf(acc.z, 0.f); r.w = fmaxf(acc.w, 0.f);
      xr_out[(size_t)node * 32 + q] = r;
    }
  } else {
    int s0 = rp2[node], s1 = rp2[node + 1];
    float4 acc = make_float4(0.f, 0.f, 0.f, 0.f);
    for (int s = s0; s < s1; s += 32) {
      int es = s + q;
      int ok = es < s1;
      int sc = ok ? es : (s1 - 1);
      int2 ee = edg2[sc];
      int cme = ee.x;
      float vme = ok ? __int_as_float(ee.y) : 0.f;
      int nb = s1 - s; if (nb > 32) nb = 32;
      for (int j = 0; j < nb; j += 8) {
        int c8[8]; float v8[8];
#pragma unroll
        for (int t = 0; t < 8; ++t) {
          c8[t] = __shfl(cme, grp + j + t, 64);
          v8[t] = __shfl(vme, grp + j + t, 64);
        }
        ushort4 h[8];
#pragma unroll
        for (int t = 0; t < 8; ++t) h[t] = hin2[(size_t)c8[t] * 32 + q];
#pragma unroll
        for (int t = 0; t < 8; ++t) {
          acc.x = fmaf(v8[t], bf2f(h[t].x), acc.x);
          acc.y = fmaf(v8[t], bf2f(h[t].y), acc.y);
          acc.z = fmaf(v8[t], bf2f(h[t].z), acc.z);
          acc.w = fmaf(v8[t], bf2f(h[t].w), acc.w);
        }
      }
    }
    if (fout2) {
      fout2[(size_t)node * 32 + q] = acc;
    } else {
      ushort4 o;
      o.x = f2bf(acc.x); o.y = f2bf(acc.y); o.z = f2bf(acc.z); o.w = f2bf(acc.w);
      hout2[(size_t)node * 32 + q] = o;
    }
  }
}

// ---------------- dense matmul out = relu?(X @ W + b), W given transposed ----------------
__global__ void k_transpose6(const float* __restrict__ W0, const float* __restrict__ W1,
                             const float* __restrict__ W2, const float* __restrict__ W3,
                             const float* __restrict__ W4, const float* __restrict__ W5,
                             float* __restrict__ WT) {
  int i = blockIdx.x * blockDim.x + threadIdx.x;
  if (i >= 6 * F * F) return;
  int w = i >> 14, r = i & 16383, k = r >> 7, c = r & 127;
  const float* W = (w == 0) ? W0 : (w == 1) ? W1 : (w == 2) ? W2
                   : (w == 3) ? W3 : (w == 4) ? W4 : W5;
  WT[(size_t)w * 16384 + c * F + k] = W[r];
}

__global__ void k_mm128(const float* __restrict__ X, const float* __restrict__ WT,
                        const float* __restrict__ bias, float* __restrict__ out,
                        int M, int relu) {
  __shared__ float4 xs[16][32];
  int tid = threadIdx.x;
  int c = tid & 127;
  int half = tid >> 7;
  int row0 = blockIdx.x * 16;
  for (int t = tid; t < 512; t += 256) {
    int r = t >> 5, k4 = t & 31;
    int gr = row0 + r;
    float4 v = make_float4(0.f, 0.f, 0.f, 0.f);
    if (gr < M) v = ((const float4*)X)[(size_t)gr * 32 + k4];
    xs[r][k4] = v;
  }
  __syncthreads();
  float acc[8];
#pragma unroll
  for (int r = 0; r < 8; ++r) acc[r] = 0.f;
  const float4* wrow = (const float4*)WT + (size_t)c * 32;
  for (int k4 = 0; k4 < 32; ++k4) {
    float4 w = wrow[k4];
#pragma unroll
    for (int r = 0; r < 8; ++r) {
      float4 xv = xs[half * 8 + r][k4];
      acc[r] = fmaf(xv.x, w.x, acc[r]);
      acc[r] = fmaf(xv.y, w.y, acc[r]);
      acc[r] = fmaf(xv.z, w.z, acc[r]);
      acc[r] = fmaf(xv.w, w.w, acc[r]);
    }
  }
  float bb = bias ? bias[c] : 0.f;
#pragma unroll
  for (int r = 0; r < 8; ++r) {
    int gr = row0 + half * 8 + r;
    if (gr < M) {
      float v = acc[r] + bb;
      if (relu) v = fmaxf(v, 0.f);
      out[(size_t)gr * F + c] = v;
    }
  }
}

__global__ void k_mm128_bf16(const float* __restrict__ X, const float* __restrict__ WT,
                             const float* __restrict__ bias, unsigned short* __restrict__ out,
                             int M) {
  __shared__ float4 xs[16][32];
  int tid = threadIdx.x;
  int c = tid & 127;
  int half = tid >> 7;
  int row0 = blockIdx.x * 16;
  for (int t = tid; t < 512; t += 256) {
    int r = t >> 5, k4 = t & 31;
    int gr = row0 + r;
    float4 v = make_float4(0.f, 0.f, 0.f, 0.f);
    if (gr < M) v = ((const float4*)X)[(size_t)gr * 32 + k4];
    xs[r][k4] = v;
  }
  __syncthreads();
  float acc[8];
#pragma unroll
  for (int r = 0; r < 8; ++r) acc[r] = 0.f;
  const float4* wrow = (const float4*)WT + (size_t)c * 32;
  for (int k4 = 0; k4 < 32; ++k4) {
    float4 w = wrow[k4];
#pragma unroll
    for (int r = 0; r < 8; ++r) {
      float4 xv = xs[half * 8 + r][k4];
      acc[r] = fmaf(xv.x, w.x, acc[r]);
      acc[r] = fmaf(xv.y, w.y, acc[r]);
      acc[r] = fmaf(xv.z, w.z, acc[r]);
      acc[r] = fmaf(xv.w, w.w, acc[r]);
    }
  }
  float bb = bias ? bias[c] : 0.f;
#pragma unroll
  for (int r = 0; r < 8; ++r) {
    int gr = row0 + half * 8 + r;
    if (gr < M) out[(size_t)gr * F + c] = f2bf(acc[r] + bb);
  }
}

// ---------------- scores + ranking (top-k via 22-bit bin bucketing) ----------------
__device__ __forceinline__ unsigned sortkey(float f) {
  if (f == 0.f) f = 0.f;
  unsigned u = __float_as_uint(f);
  return (u & 0x80000000u) ? ~u : (u | 0x80000000u);
}

__global__ void k_score_key(const float* __restrict__ xr, const float* __restrict__ p,
                            unsigned* __restrict__ key, int n) {
  int wid = (blockIdx.x * blockDim.x + threadIdx.x) >> 6;
  int lane = threadIdx.x & 63;
  if (wid >= n) return;
  const float* row = xr + (size_t)wid * F;
  float d = row[lane] * p[lane] + row[lane + 64] * p[lane + 64];
#pragma unroll
  for (int o = 32; o; o >>= 1) d += __shfl_xor(d, o, 64);
  if (lane == 0) key[wid] = sortkey(d);
}

__global__ void k_count_bins22(const unsigned* __restrict__ key, int* __restrict__ cnt, int n) {
  int i = blockIdx.x * blockDim.x + threadIdx.x;
  if (i < n) atomicAdd(&cnt[key[i] >> 10], 1);
}

__global__ void k_hist_blocksum(const int* __restrict__ cnt, int* __restrict__ partial) {
  int t = threadIdx.x;
  int base = blockIdx.x * 1024 + t * 4;
  int s = cnt[base] + cnt[base + 1] + cnt[base + 2] + cnt[base + 3];
#pragma unroll
  for (int o = 32; o; o >>= 1) s += __shfl_down(s, o, 64);
  __shared__ int ws[4];
  int lane = t & 63, w = t >> 6;
  if (lane == 0) ws[w] = s;
  __syncthreads();
  if (t == 0) partial[blockIdx.x] = ws[0] + ws[1] + ws[2] + ws[3];
}

__global__ void k_hist_apply(const int* __restrict__ cnt, const int* __restrict__ partialptr,
                             int* __restrict__ binptr) {
  int t = threadIdx.x;
  int base = blockIdx.x * 1024 + t * 4;
  int c0 = cnt[base], c1 = cnt[base + 1], c2 = cnt[base + 2], c3 = cnt[base + 3];
  int s = c0 + c1 + c2 + c3;
  int lane = t & 63, w = t >> 6;
  int v = s;
#pragma unroll
  for (int o = 1; o < 64; o <<= 1) {
    int u = __shfl_up(v, o, 64);
    if (lane >= o) v += u;
  }
  __shared__ int ws[4];
  if (lane == 63) ws[w] = v;
  __syncthreads();
  int wb = 0;
  for (int i = 0; i < w; ++i) wb += ws[i];
  int run = partialptr[blockIdx.x] + wb + (v - s);
  binptr[base + 1] = run + c0;
  binptr[base + 2] = run + c0 + c1;
  binptr[base + 3] = run + c0 + c1 + c2;
  binptr[base + 4] = run + s;
  if (blockIdx.x == 0 && t == 0) binptr[0] = 0;
}

// atomicSub variant: cnt22 self-zeroes; within-bin order irrelevant
__global__ void k_fill_bins22(const unsigned* __restrict__ key, const int* __restrict__ binptr,
                              int* __restrict__ cnt, int* __restrict__ bidx,
                              unsigned* __restrict__ bkey, int n) {
  int i = blockIdx.x * blockDim.x + threadIdx.x;
  if (i < n) {
    unsigned k = key[i];
    int b = k >> 10;
    int p = atomicSub(&cnt[b], 1) - 1;
    int s = binptr[b] + p;
    bidx[s] = i;
    bkey[s] = k;
  }
}

__global__ void k_rank22(const unsigned* __restrict__ key, const int* __restrict__ binptr,
                         const int* __restrict__ bidx, const unsigned* __restrict__ bkey,
                         int* __restrict__ supid, int n) {
  int i = blockIdx.x * blockDim.x + threadIdx.x;
  if (i >= n) return;
  unsigned ki = key[i];
  int b = ki >> 10;
  int cnt = n - binptr[b + 1];
  int s1 = binptr[b + 1];
  for (int s = binptr[b]; s < s1; ++s) {
    unsigned kj = bkey[s];
    cnt += (kj > ki) || (kj == ki && bidx[s] < i);
  }
  supid[i] = (cnt < NSUP) ? cnt : -1;
}

// ---------------- attention / assignment (fused online softmax+argmax) ---------------
__device__ __forceinline__ float read_T(const void* p) {
  int ib = *(const int*)p;
  float fb = __int_as_float(ib);
  if (ib >= 1 && ib < (1 << 20)) return (float)ib;
  if (fb > 1e-6f && fb < 1e6f) return fb;
  return 1.0f;
}

__global__ void k_att(const float* __restrict__ xr, const int* __restrict__ rowptr,
                      const int* __restrict__ col, const int* __restrict__ supid,
                      const void* __restrict__ tptr,
                      int* __restrict__ cluster, float* __restrict__ aout, int n) {
  int wid = (blockIdx.x * blockDim.x + threadIdx.x) >> 6;
  int lane = threadIdx.x & 63;
  if (wid >= n) return;
  float inv = 1.0f / (sqrtf(128.0f) * read_T(tptr));
  const float* xn = xr + (size_t)wid * F;
  float x0 = xn[lane], x1 = xn[lane + 64];
  float d = x0 * x0 + x1 * x1;
#pragma unroll
  for (int o = 32; o; o >>= 1) d += __shfl_xor(d, o, 64);
  int sid_self = supid[wid];
  float m = (sid_self >= 0) ? d * inv : NEGINF;
  float esum = 1.0f;
  int best = sid_self;
  int s0 = rowptr[wid], s1 = rowptr[wid + 1];
  for (int s = s0; s < s1; s += 4) {
    int c[4]; bool ok[4];
#pragma unroll
    for (int j = 0; j < 4; ++j) {
      int ss = s + j;
      ok[j] = ss < s1;
      c[j] = col[ok[j] ? ss : (s1 - 1)];
    }
    float dd[4];
#pragma unroll
    for (int j = 0; j < 4; ++j) {
      const float* xc = xr + (size_t)c[j] * F;
      dd[j] = x0 * xc[lane] + x1 * xc[lane + 64];
    }
#pragma unroll
    for (int j = 0; j < 4; ++j) {
#pragma unroll
      for (int o = 32; o; o >>= 1) dd[j] += __shfl_xor(dd[j], o, 64);
    }
#pragma unroll
    for (int j = 0; j < 4; ++j) {
      if (ok[j]) {
        int sid = supid[c[j]];
        float a2 = (sid >= 0) ? dd[j] * inv : NEGINF;
        if (a2 > m) {
          esum = esum * expf(m - a2) + 1.0f;
          m = a2;
          best = sid;
        } else {
          esum += expf(a2 - m);
          if (a2 == m && sid > best) best = sid;
        }
      }
    }
  }
  if (lane == 0) {
    int has = best >= 0;
    cluster[wid] = has ? best : 0;
    aout[wid] = has ? 1.0f / esum : 0.0f;
  }
}

// ---------------- pooling (pull over cluster->member CSR) ----------------
__global__ void k_xpool_pull(const float4* __restrict__ xr, const float* __restrict__ a,
                             const int* __restrict__ rowptrM, const int* __restrict__ memb,
                             float4* __restrict__ xpool, int n) {
  int c = blockIdx.x * 8 + (threadIdx.x >> 5);
  if (c >= n) return;
  int q = threadIdx.x & 31;
  int s0 = rowptrM[c], s1 = rowptrM[c + 1];
  float4 acc = make_float4(0.f, 0.f, 0.f, 0.f);
  for (int s = s0; s < s1; ++s) {
    int m = memb[s];
    float av = a[m];
    float4 h = xr[(size_t)m * 32 + q];
    acc.x = fmaf(av, h.x, acc.x);
    acc.y = fmaf(av, h.y, acc.y);
    acc.z = fmaf(av, h.z, acc.z);
    acc.w = fmaf(av, h.w, acc.w);
  }
  xpool[(size_t)c * 32 + q] = acc;
}

// ---------------- fused anchor scatter (one atomic per element) ----------------
__global__ void k_scatter2(const int* __restrict__ a1, const int* __restrict__ a2,
                           const int* __restrict__ cluster, const float* __restrict__ aarr,
                           const float* __restrict__ t1, const float* __restrict__ t2,
                           float* __restrict__ outy, int nA) {
  int idx = blockIdx.x * blockDim.x + threadIdx.x;
  if (idx >= nA * F) return;
  int k = idx >> 7, f = idx & 127;
  int n1 = a1[k];
  float add = t2[(size_t)n1 * F + f];
  float qw = aarr[n1];
  if (qw != 0.f) add += qw * t1[(size_t)cluster[n1] * F + f];
  atomicAdd(&outy[(size_t)a2[k] * F + f], add);
}

// ================= host =================
extern "C" void kernel_launch(void* const* d_in, const int* in_sizes, int n_in,
                              void* d_out, int out_size, void* d_ws, size_t ws_size,
                              hipStream_t stream) {
  (void)in_sizes; (void)n_in; (void)out_size; (void)ws_size;
  const float* x   = (const float*)d_in[0];
  const int*   ei  = (const int*)d_in[1];
  const float* w1  = (const float*)d_in[2];
  const float* y   = (const float*)d_in[3];
  const int*   eiy = (const int*)d_in[4];
  const float* wy  = (const float*)d_in[5];
  const int*   anc = (const int*)d_in[6];
  const void*  tmp = d_in[7];
  const float* W_gcn = (const float*)d_in[8];
  const float* b_gcn = (const float*)d_in[9];
  const float* p_sc  = (const float*)d_in[10];
  const float* W_c1  = (const float*)d_in[11];
  const float* b_c1  = (const float*)d_in[12];
  const float* W_m1  = (const float*)d_in[13];
  const float* b_m1  = (const float*)d_in[14];
  const float* W_l1  = (const float*)d_in[15];
  const float* W_l2  = (const float*)d_in[16];
  const float* W_m2  = (const float*)d_in[17];
  const float* b_m2  = (const float*)d_in[18];

  float* out   = (float*)d_out;
  float* out_x = out;
  float* sup1  = out_x + (size_t)N1 * F;
  float* out_y = sup1 + (size_t)NSUP * F;
  float* sup2  = out_y + (size_t)N2 * F;
  float* a_out = sup2 + (size_t)NSUP * F;
  float* recon = a_out + N1;

  char* wsb = (char*)d_ws;
  size_t off = 0;
  auto alloc = [&](size_t bytes) -> void* {
    void* p = wsb + off;
    off = (off + bytes + 255) & ~(size_t)255;
    return p;
  };
  int2*     e_g1      = (int2*)alloc((size_t)E1C * 8);           // g1 CSR {col,val}
  int*      i_rowptr1 = (int*)alloc((size_t)(N1 + 1) * 4);
  int*      i_rowptr2 = (int*)alloc((size_t)(N2 + 1) * 4);
  float*    f_deg     = (float*)alloc((size_t)N1 * 4);
  float*    f_deg2    = (float*)alloc((size_t)N2 * 4);
  int*      i_cnt3    = (int*)alloc((size_t)3 * NB * 4);         // self-restoring counters
  float*    f_ha      = (float*)alloc((size_t)N1 * F * 4);       // g1 h ping / cnt22 overlay
  float*    f_hb      = (float*)alloc((size_t)N1 * F * 4);       // g1 h pong / binptr22 overlay
  float*    f_xr      = (float*)alloc((size_t)N1 * F * 4);       // reused for t2
  unsigned* u_key     = (unsigned*)alloc((size_t)N1 * 4);
  int*      i_partial = (int*)alloc((size_t)4096 * 4);
  int*      i_partptr = (int*)alloc((size_t)4097 * 4);
  int*      i_bidx    = (int*)alloc((size_t)N1 * 4);
  unsigned* u_bkey    = (unsigned*)alloc((size_t)N1 * 4);
  int*      i_supid   = (int*)alloc((size_t)N1 * 4);
  int*      i_rowptrS = (int*)alloc((size_t)(N1 + 1) * 4);
  int*      i_csrSc   = (int*)alloc((size_t)E1C * 4);
  int*      i_cluster = (int*)alloc((size_t)N1 * 4);
  float*    f_xpool   = (float*)alloc((size_t)NSUP * F * 4);
  float*    f_degc    = (float*)alloc((size_t)NSUP * 4);
  int*      i_rowptrC = (int*)alloc((size_t)(NSUP + 1) * 4);
  int2*     e_gC      = (int2*)alloc((size_t)E1C * 8);           // coarse CSR / g2 overlay
  int*      i_rowptrM = (int*)alloc((size_t)(NSUP + 1) * 4);
  int*      i_memb    = (int*)alloc((size_t)N1 * 4);
  float*    f_h2      = (float*)alloc((size_t)NSUP * F * 4);
  float*    f_h2p     = (float*)alloc((size_t)NSUP * F * 4);     // t1
  float*    f_wt      = (float*)alloc((size_t)6 * F * F * 4);

  // overlays (non-overlapping lifetimes):
  int* i_cnt22    = (int*)f_ha;       // rank bins live after props
  int* i_binptr22 = (int*)f_hb;
  int2* e_g2      = e_gC;             // g2 CSR lives before coarse CSR
  unsigned short* h16a = (unsigned short*)f_xpool;   // g2 bf16 h lives before coarsen
  unsigned short* h16b = (unsigned short*)f_h2;

  const int* src1 = ei,  * dst1 = ei + E1C;
  const int* srcy = eiy, * dsty = eiy + E2C;
  const int* a1 = anc, * a2 = anc + AC;

  int gE = cdiv(E1C, 256);
  int gN = cdiv(N1, 256);
  int gC8 = cdiv(NSUP, 8);
  int gD = 2 * cdiv(N1, 8);

  // --- single upfront counter memset (counters self-restore via atomicSub fills) ---
  hipMemsetAsync(i_cnt3, 0, (size_t)3 * NB * 4, stream);
  k_transpose6<<<cdiv(6 * F * F, 256), 256, 0, stream>>>(W_gcn, W_c1, W_m1, W_l1, W_l2,
                                                         W_m2, f_wt);
  float* wt_gcn = f_wt, *wt_c1 = f_wt + 16384, *wt_m1 = f_wt + 2 * 16384,
       * wt_l1 = f_wt + 3 * 16384, *wt_l2 = f_wt + 4 * 16384, *wt_m2 = f_wt + 5 * 16384;

  // --- all three big CSRs (g1-by-dst, g2, g1-by-src) in 3 fused launches ---
  k_count3<<<cdiv(3 * E1C, 256), 256, 0, stream>>>(dst1, dsty, src1, i_cnt3);
  k_scan3<<<3, 1024, 0, stream>>>(i_cnt3, i_rowptr1, i_rowptr2, i_rowptrS, N1, N2, N1);
  k_fill3<<<cdiv(3 * E1C, 256), 256, 0, stream>>>(dst1, src1, w1, dsty, srcy, wy,
                                                  i_rowptr1, i_rowptr2, i_rowptrS, i_cnt3,
                                                  e_g1, e_g2, i_csrSc);
  k_rowsum2<<<cdiv(N1 + N2, 8), 256, 0, stream>>>(e_g1, i_rowptr1, f_deg, N1,
                                                  e_g2, i_rowptr2, f_deg2, N2);
  k_csrnorm2<<<cdiv(N1 + N2, 8), 256, 0, stream>>>(e_g1, i_rowptr1, f_deg, N1,
                                                   e_g2, i_rowptr2, f_deg2, N2);

  // --- h0 for both graphs ---
  k_mm128<<<cdiv(N1, 16), 256, 0, stream>>>(x, wt_gcn, b_gcn, f_ha, N1, 0);
  k_mm128_bf16<<<cdiv(N2, 16), 256, 0, stream>>>(y, wt_gcn, b_gcn, h16a, N2);

  // --- FUSED 10 hops: g1 fp32 + g2 bf16 co-scheduled per dispatch ---
  {
    const float* cur1 = f_ha;
    const unsigned short* cur2 = h16a;
    for (int i = 0; i < KHOPS; ++i) {
      int last = (i == KHOPS - 1);
      float* dst1b = last ? out_x : ((i & 1) ? f_ha : f_hb);
      unsigned short* dst2b = (i & 1) ? h16a : h16b;
      k_prop_dual<<<gD, 256, 0, stream>>>(
          (const float4*)cur1, (float4*)dst1b, last ? (float4*)f_xr : nullptr,
          i_rowptr1, e_g1,
          (const ushort4*)cur2, (ushort4*)dst2b, last ? (float4*)out_y : nullptr,
          i_rowptr2, e_g2, N1);
      cur1 = dst1b; cur2 = dst2b;
    }
  }

  // --- scores + top-k ranks (22-bit bins; overlays on f_ha/f_hb, now free) ---
  k_score_key<<<cdiv(N1, 4), 256, 0, stream>>>(f_xr, p_sc, u_key, N1);
  hipMemsetAsync(i_cnt22, 0, (size_t)NBINS22 * 4, stream);
  k_count_bins22<<<gN, 256, 0, stream>>>(u_key, i_cnt22, N1);
  k_hist_blocksum<<<NBINS22 / 1024, 256, 0, stream>>>(i_cnt22, i_partial);
  k_scan<<<1, 1024, 0, stream>>>(i_partial, i_partptr, 4096);
  k_hist_apply<<<NBINS22 / 1024, 256, 0, stream>>>(i_cnt22, i_partptr, i_binptr22);
  k_fill_bins22<<<gN, 256, 0, stream>>>(u_key, i_binptr22, i_cnt22, i_bidx, u_bkey, N1);
  k_rank22<<<gN, 256, 0, stream>>>(u_key, i_binptr22, i_bidx, u_bkey, i_supid, N1);

  // --- fused attention: online softmax + exact argmax, one pass ---
  k_att<<<cdiv(N1, 4), 256, 0, stream>>>(f_xr, i_rowptrS, i_csrSc, i_supid, tmp,
                                         i_cluster, a_out, N1);

  // --- coarsen: cluster->member CSR + pull pooling (cnt3 region 0, self-restored) ---
  k_count<<<gN, 256, 0, stream>>>(i_cluster, i_cnt3, N1);
  k_scan<<<1, 1024, 0, stream>>>(i_cnt3, i_rowptrM, NSUP);
  k_fill_iota<<<gN, 256, 0, stream>>>(i_cluster, i_rowptrM, i_cnt3, i_memb, N1);
  k_xpool_pull<<<gC8, 256, 0, stream>>>((const float4*)f_xr, a_out, i_rowptrM,
                                        i_memb, (float4*)f_xpool, NSUP);

  // --- coarse CSR with cw values (cnt3 region 0 again; int2-interleaved) ---
  k_count_coarse<<<gE, 256, 0, stream>>>(dst1, i_cluster, i_cnt3, E1C);
  k_scan<<<1, 1024, 0, stream>>>(i_cnt3, i_rowptrC, NSUP);
  k_fill_coarse<<<gE, 256, 0, stream>>>(src1, dst1, i_cluster, w1, a_out, i_rowptrC,
                                        i_cnt3, e_gC, E1C);
  k_rowsum<<<gC8, 256, 0, stream>>>(e_gC, i_rowptrC, f_degc, NSUP);
  k_csrnorm<<<gC8, 256, 0, stream>>>(e_gC, i_rowptrC, f_degc, NSUP);

  // --- coarse conv (prop + add + relu fused) + MLP1 ---
  k_mm128<<<cdiv(NSUP, 16), 256, 0, stream>>>(f_xpool, wt_c1, b_c1, f_h2, NSUP, 0);
  k_prop<<<gC8, 256, 0, stream>>>((const float4*)f_h2, (float4*)sup1, (const float4*)f_h2,
                                  i_rowptrC, e_gC, NSUP);
  k_mm128<<<cdiv(NSUP, 16), 256, 0, stream>>>(sup1, wt_m1, b_m1, sup2, NSUP, 1);

  // --- LastLayer: both mms, then one fused scatter ---
  float* f_t1 = f_h2p;
  float* f_t2 = f_xr;
  k_mm128<<<cdiv(NSUP, 16), 256, 0, stream>>>(sup2, wt_l1, (const float*)nullptr, f_t1,
                                              NSUP, 0);
  k_mm128<<<cdiv(N1, 16), 256, 0, stream>>>(out_x, wt_l2, (const float*)nullptr, f_t2,
                                            N1, 0);
  k_scatter2<<<cdiv(AC * F, 256), 256, 0, stream>>>(a1, a2, i_cluster, a_out, f_t1, f_t2,
                                                    out_y, AC);

  // --- recon ---
  k_mm128<<<cdiv(N2, 16), 256, 0, stream>>>(out_y, wt_m2, b_m2, recon, N2, 0);
}